// Round 12
// baseline (1383.385 us; speedup 1.0000x reference)
//
#include <hip/hip_runtime.h>
#include <hip/hip_bf16.h>
#include <math.h>

#define HWsz 4096
#define Csz  256
#define BZsz 4
#define Msz  1024
#define Ksz  3072
#define KSPL 4
#define KPER 768      // Ksz / KSPL
#define NKT  6        // KPER / 128
#define LDP  132      // padded LDS row (floats)

typedef float f32x2 __attribute__((ext_vector_type(2)));

// ---------------------------------------------------------------------------
// K0: transpose input [b][c][p] -> inpT [b][p][c]
// ---------------------------------------------------------------------------
__global__ void transpose_kernel(const float* __restrict__ in, float* __restrict__ outT) {
    __shared__ float tile[32][33];
    int b  = blockIdx.z;
    int p0 = blockIdx.x * 32;
    int c0 = blockIdx.y * 32;
    int tx = threadIdx.x;  // 32
    int ty = threadIdx.y;  // 8
#pragma unroll
    for (int i = 0; i < 4; i++) {
        int c = c0 + ty + i * 8;
        tile[ty + i * 8][tx] = in[((size_t)b * Csz + c) * HWsz + p0 + tx];
    }
    __syncthreads();
#pragma unroll
    for (int i = 0; i < 4; i++) {
        int p = p0 + ty + i * 8;
        outT[((size_t)b * HWsz + p) * Csz + c0 + tx] = tile[tx][ty + i * 8];
    }
}

// ---------------------------------------------------------------------------
// K1: norm replica: f32 square (rounded mult), STRICTLY SEQUENTIAL f32 sum
// over c ascending, IEEE f32 sqrt, + 1e-8f.  (unchanged numerics)
// ---------------------------------------------------------------------------
__global__ void colnorm_kernel(const float* __restrict__ inp, float* __restrict__ dnorm) {
#pragma clang fp contract(off)
    int p = blockIdx.x * 256 + threadIdx.x;   // 0..HW-1
    int b = blockIdx.y;
    const float* col = inp + (size_t)b * Csz * HWsz + p;
    float acc = 0.f;
    for (int c = 0; c < Csz; c++) {
        float x  = col[(size_t)c * HWsz];
        float sq = x * x;
        acc = acc + sq;
    }
    dnorm[b * HWsz + p] = sqrtf(acc) + 1e-8f;
}

// ---------------------------------------------------------------------------
// K1b: knT[b][kk][c] = inpT[b][kidx[kk]][c] / dn  (IEEE f32 div, once)
// grid (Ksz/4, BZ), 256 thr (4 rows/block)
// ---------------------------------------------------------------------------
__global__ void knprep_kernel(const float* __restrict__ inpT, const float* __restrict__ dnorm,
                              const int* __restrict__ kidx, float* __restrict__ knT) {
    int row  = blockIdx.x * 4 + (threadIdx.x >> 6);
    int lane = threadIdx.x & 63;
    int b    = blockIdx.y;
    int kid  = kidx[row];
    float dn = dnorm[b * HWsz + kid];
    const float* src = inpT + ((size_t)b * HWsz + kid) * Csz + lane * 4;
    float4 v = *(const float4*)src;
    float4 w = {v.x / dn, v.y / dn, v.z / dn, v.w / dn};
    *(float4*)(knT + ((size_t)b * Ksz + row) * Csz + lane * 4) = w;
}

// ---------------------------------------------------------------------------
// K2 v3: sim einsum replica with packed-f32 VALU.
// Per (p,k): single f32 accumulator, mul then add (NO fma), c ascending.
// v_pk_mul_f32 / v_pk_add_f32 do two independent IEEE f32 ops -> bit-exact.
// grid (BZ, HW/128, KSPL), 256 thr, 2 blocks/CU.
// ---------------------------------------------------------------------------
#define PK_MUL(dst, s0, s1) asm("v_pk_mul_f32 %0, %1, %2" : "=v"(dst) : "v"(s0), "v"(s1))
#define PK_ADD(dst, s1)     asm("v_pk_add_f32 %0, %0, %1" : "+v"(dst) : "v"(s1))

__launch_bounds__(256, 2)
__global__ void sim_argmax_kernel(const float* __restrict__ knT,
                                  const float* __restrict__ refm,
                                  float* __restrict__ pvmax, int* __restrict__ pind) {
#pragma clang fp contract(off)
    __shared__ float rf[64][LDP];   // [c][p]
    __shared__ float kn[64][LDP];   // [c][k]

    int b   = blockIdx.x;
    int p0  = blockIdx.y * 128;
    int ks  = blockIdx.z;
    int k0  = ks * KPER;
    int tid = threadIdx.x;

    int tr = tid >> 4;          // 0..15 -> p = p0 + tr*8 + i
    int tc = tid & 15;          // 0..15 -> k = tile_k0 + tc*8 + j

    int spp = tid & 127;        // rf: pixel col
    int sch = tid >> 7;         // rf: row parity
    int skk = tid >> 1;         // kn: k row (0..127)
    int sc4 = (tid & 1) * 32;   // kn: c offset (0 or 32)

    float best[8];
    int   bidx[8];
#pragma unroll
    for (int i = 0; i < 8; i++) { best[i] = -INFINITY; bidx[i] = 0x7fffffff; }

    for (int kt = 0; kt < NKT; kt++) {
        int ktbase = k0 + kt * 128;
        const float* nrow = knT + ((size_t)b * Ksz + ktbase + skk) * Csz;

        f32x2 acc[8][4];   // [i][jj] -> j = 2*jj (lo), 2*jj+1 (hi)
#pragma unroll
        for (int i = 0; i < 8; i++)
#pragma unroll
            for (int jj = 0; jj < 4; jj++) acc[i][jj] = (f32x2){0.f, 0.f};

        for (int cc = 0; cc < 4; cc++) {
            __syncthreads();
#pragma unroll 8
            for (int i = 0; i < 32; i++) {
                int c = i * 2 + sch;
                rf[c][spp] = refm[((size_t)b * Csz + cc * 64 + c) * HWsz + p0 + spp];
            }
            const float* src = nrow + cc * 64 + sc4;
#pragma unroll
            for (int i = 0; i < 8; i++) {
                float4 v = *(const float4*)(src + i * 4);
                int c = sc4 + i * 4;
                kn[c + 0][skk] = v.x;
                kn[c + 1][skk] = v.y;
                kn[c + 2][skk] = v.z;
                kn[c + 3][skk] = v.w;
            }
            __syncthreads();

#pragma unroll 2
            for (int c = 0; c < 64; c++) {
                float4 a0 = *(const float4*)&rf[c][tr * 8];
                float4 a1 = *(const float4*)&rf[c][tr * 8 + 4];
                float4 b0 = *(const float4*)&kn[c][tc * 8];
                float4 b1 = *(const float4*)&kn[c][tc * 8 + 4];
                float av[8] = {a0.x, a0.y, a0.z, a0.w, a1.x, a1.y, a1.z, a1.w};
                f32x2 B[4] = {{b0.x, b0.y}, {b0.z, b0.w}, {b1.x, b1.y}, {b1.z, b1.w}};
#pragma unroll
                for (int i = 0; i < 8; i++) {
                    f32x2 av2 = {av[i], av[i]};
#pragma unroll
                    for (int jj = 0; jj < 4; jj++) {
                        f32x2 pr;
                        PK_MUL(pr, av2, B[jj]);       // two IEEE f32 muls
                        PK_ADD(acc[i][jj], pr);       // two IEEE f32 adds
                    }
                }
            }
        }
        // argmax update, k ascending (kt asc, j asc)
#pragma unroll
        for (int j = 0; j < 8; j++) {
            int k = ktbase + tc * 8 + j;
#pragma unroll
            for (int i = 0; i < 8; i++) {
                float v = (j & 1) ? acc[i][j >> 1].y : acc[i][j >> 1].x;
                if (v > best[i] || (v == best[i] && k < bidx[i])) { best[i] = v; bidx[i] = k; }
            }
        }
    }

    // reduce across tc groups (reuse LDS)
    __syncthreads();
    float* sv = &rf[0][0];          // 128p x 16tc
    int*   si = (int*)&kn[0][0];
#pragma unroll
    for (int i = 0; i < 8; i++) {
        int p = tr * 8 + i;
        sv[p * 16 + tc] = best[i];
        si[p * 16 + tc] = bidx[i];
    }
    __syncthreads();
    if (tid < 128) {
        float bv = -INFINITY; int bi = 0x7fffffff;
        for (int t = 0; t < 16; t++) {
            float v = sv[tid * 16 + t];
            int   k = si[tid * 16 + t];
            if (v > bv || (v == bv && k < bi)) { bv = v; bi = k; }
        }
        pvmax[((size_t)ks * BZsz + b) * HWsz + p0 + tid] = bv;
        pind [((size_t)ks * BZsz + b) * HWsz + p0 + tid] = bi;
    }
}

// ---------------------------------------------------------------------------
// K2b: combine K-splits (ascending ks => global first-max)
// ---------------------------------------------------------------------------
__global__ void combine_kernel(const float* __restrict__ pvmax, const int* __restrict__ pind,
                               float* __restrict__ vmax, int* __restrict__ ind) {
    int p = blockIdx.x * 256 + threadIdx.x;
    int b = blockIdx.y;
    float bv = -INFINITY; int bi = 0x7fffffff;
    for (int ks = 0; ks < KSPL; ks++) {
        float v = pvmax[((size_t)ks * BZsz + b) * HWsz + p];
        int   k = pind [((size_t)ks * BZsz + b) * HWsz + p];
        if (v > bv || (v == bv && k < bi)) { bv = v; bi = k; }
    }
    vmax[b * HWsz + p] = bv;
    ind [b * HWsz + p] = bi;
}

// ---------------------------------------------------------------------------
// K2c: scanprep: uT[b][t][c] = inpT[b][midx[t]][c] / dn (IEEE f32 div, same
// bits as before), bkT[b][t][c] = inpT[b][kidx[ind[..]]][c] (raw copy).
// ---------------------------------------------------------------------------
__global__ void scanprep_kernel(const float* __restrict__ inpT, const float* __restrict__ dnorm,
                                const int* __restrict__ ind, const int* __restrict__ midx,
                                const int* __restrict__ kidx,
                                float* __restrict__ uT, float* __restrict__ bkT) {
    int t    = blockIdx.x * 4 + (threadIdx.x >> 6);
    int lane = threadIdx.x & 63;
    int b    = blockIdx.y;
    int pp   = midx[t];
    float dn = dnorm[b * HWsz + pp];
    int bkid = kidx[ind[b * HWsz + pp]];
    const float* us = inpT + ((size_t)b * HWsz + pp) * Csz + lane * 4;
    const float* bs = inpT + ((size_t)b * HWsz + bkid) * Csz + lane * 4;
    float4 v = *(const float4*)us;
    float4 w = {v.x / dn, v.y / dn, v.z / dn, v.w / dn};
    *(float4*)(uT  + ((size_t)b * Msz + t) * Csz + lane * 4) = w;
    *(float4*)(bkT + ((size_t)b * Msz + t) * Csz + lane * 4) = *(const float4*)bs;
}

// ---------------------------------------------------------------------------
// K3 v4: serial scan, one wave per image. Numerics IDENTICAL to R7/R8/R10:
//   pair terms r = fmaf(u_even, o_even, f32(u_odd*o_odd)); dot = strictly
//   sequential f32 adds over 128 pair terms ascending; denom = at+vm;
//   IEEE f32 divs; update mul,mul,add (contract off).
// Scheduling change only: single-wave block => NO __syncthreads in the loop
// (s_waitcnt lgkmcnt(0) orders ds_write->ds_read within the wave; global
// stores/prefetch loads are never drained -> HBM latency off critical path).
// Chain reads software-pipelined in 4xb128 chunks against the add chain.
// ---------------------------------------------------------------------------
__launch_bounds__(64, 1)
__global__ void scan_kernel(const float* __restrict__ uT, const float* __restrict__ bkT,
                            const float* __restrict__ vmax, const int* __restrict__ midx,
                            float* __restrict__ outT) {
#pragma clang fp contract(off)
    __shared__ float L_vm[Msz];
    __shared__ float rbuf[2][128];
    int b    = blockIdx.x;
    int lane = threadIdx.x;

    for (int t0 = 0; t0 < Msz; t0 += 64) {
        int t = t0 + lane;
        L_vm[t] = vmax[b * HWsz + midx[t]];
    }
    __syncthreads();

    const float* ub = uT  + (size_t)b * Msz * Csz + lane * 4;
    const float* bb = bkT + (size_t)b * Msz * Csz + lane * 4;
    float o0 = 0.f, o1 = 0.f, o2 = 0.f, o3 = 0.f;
    float4 U[4], Bk[4];
#pragma unroll
    for (int s = 0; s < 4; s++) {
        U[s]  = *(const float4*)(ub + (size_t)s * Csz);
        Bk[s] = *(const float4*)(bb + (size_t)s * Csz);
    }

    for (int t = 0; t < Msz; t += 4) {
#pragma unroll
        for (int s = 0; s < 4; s++) {
            int tt = t + s;
            float4 u = U[s];
            // sdot strided pair terms: r = fmaf(y0,x0, fl(y1*x1)); 2 pairs/lane
            float pA = u.y * o1;
            float rA = __builtin_fmaf(u.x, o0, pA);
            float pB = u.w * o3;
            float rB = __builtin_fmaf(u.z, o2, pB);
            float2 w2; w2.x = rA; w2.y = rB;
            *(float2*)&rbuf[tt & 1][2 * lane] = w2;
            // single wave: ds_write -> ds_read ordering via lgkmcnt only
            asm volatile("s_waitcnt lgkmcnt(0)" ::: "memory");
            const float4* rb = (const float4*)&rbuf[tt & 1][0];
            // software-pipelined chunked reads + strictly sequential adds
            float4 A0 = rb[0], A1 = rb[1], A2 = rb[2], A3 = rb[3];
            float dot = 0.f;
#pragma unroll
            for (int ch = 0; ch < 8; ch++) {
                float4 B0, B1, B2, B3;
                if (ch < 7) {
                    B0 = rb[ch * 4 + 4]; B1 = rb[ch * 4 + 5];
                    B2 = rb[ch * 4 + 6]; B3 = rb[ch * 4 + 7];
                }
                dot = dot + A0.x; dot = dot + A0.y; dot = dot + A0.z; dot = dot + A0.w;
                dot = dot + A1.x; dot = dot + A1.y; dot = dot + A1.z; dot = dot + A1.w;
                dot = dot + A2.x; dot = dot + A2.y; dot = dot + A2.z; dot = dot + A2.w;
                dot = dot + A3.x; dot = dot + A3.y; dot = dot + A3.z; dot = dot + A3.w;
                A0 = B0; A1 = B1; A2 = B2; A3 = B3;
            }
            float at    = dot;
            float vm    = L_vm[tt];
            float denom = at + vm;      // f32 add
            float anew  = at / denom;   // IEEE f32 div
            float aori  = vm / denom;   // IEEE f32 div
            float m0 = anew * o0, n0 = aori * Bk[s].x;
            float m1 = anew * o1, n1 = aori * Bk[s].y;
            float m2 = anew * o2, n2 = aori * Bk[s].z;
            float m3 = anew * o3, n3 = aori * Bk[s].w;
            o0 = m0 + n0; o1 = m1 + n1; o2 = m2 + n2; o3 = m3 + n3;
            float4 w = {o0, o1, o2, o3};
            *(float4*)&outT[((size_t)b * Msz + tt) * Csz + lane * 4] = w;
            if (tt + 4 < Msz) {
                U[s]  = *(const float4*)(ub + (size_t)(tt + 4) * Csz);
                Bk[s] = *(const float4*)(bb + (size_t)(tt + 4) * Csz);
            }
        }
    }
}

// ---------------------------------------------------------------------------
// K4: mask position map
// ---------------------------------------------------------------------------
__global__ void maskpos_init(int* mp) { mp[blockIdx.x * 256 + threadIdx.x] = -1; }
__global__ void maskpos_set(const int* __restrict__ midx, int* mp) {
    int t = blockIdx.x * 256 + threadIdx.x;
    if (t < Msz) mp[midx[t]] = t;
}

// ---------------------------------------------------------------------------
// K5: assemble output [b][c][p]: masked -> scan carry row, known -> gathered col
// ---------------------------------------------------------------------------
#define FSTR 261
__launch_bounds__(256)
__global__ void finalize_kernel(const float* __restrict__ inpT, const float* __restrict__ outT,
                                const int* __restrict__ ind, const int* __restrict__ kidx,
                                const int* __restrict__ mp, float* __restrict__ out) {
    __shared__ float tile[64 * FSTR];
    int b   = blockIdx.x;
    int p0  = blockIdx.y * 64;
    int tid = threadIdx.x;
    int rl  = tid >> 6;          // 0..3
    int cc  = (tid & 63) * 4;    // float4 col offset
    for (int i = 0; i < 16; i++) {
        int r = rl + i * 4;
        int p = p0 + r;
        int m = mp[p];
        const float* src = (m >= 0) ? (outT + ((size_t)b * Msz + m) * Csz)
                                    : (inpT + ((size_t)b * HWsz + kidx[ind[b * HWsz + p]]) * Csz);
        float4 v = *(const float4*)(src + cc);
        tile[r * FSTR + cc + 0] = v.x;
        tile[r * FSTR + cc + 1] = v.y;
        tile[r * FSTR + cc + 2] = v.z;
        tile[r * FSTR + cc + 3] = v.w;
    }
    __syncthreads();
    int pp = tid & 63;
    int c0 = tid >> 6;
    for (int i = 0; i < 64; i++) {
        int c = c0 + i * 4;
        out[((size_t)b * Csz + c) * HWsz + p0 + pp] = tile[pp * FSTR + c];
    }
}

// ---------------------------------------------------------------------------
extern "C" void kernel_launch(void* const* d_in, const int* in_sizes, int n_in,
                              void* d_out, int out_size, void* d_ws, size_t ws_size,
                              hipStream_t stream) {
    const float* inp  = (const float*)d_in[0];
    const float* refm = (const float*)d_in[1];
    const int*   midx = (const int*)d_in[2];
    const int*   kidx = (const int*)d_in[3];
    float* out = (float*)d_out;

    char* ws = (char*)d_ws;
    float* inpT  = (float*)(ws);                  // 16 MB   (ends 16777216)
    float* outT  = (float*)(ws + 16777216);       // 4 MB    (ends 20971520)
    float* knT   = (float*)(ws + 20971520);       // 12 MB   (ends 33554432)
    float* uT    = (float*)(ws + 33554432);       // 4 MB    (ends 37748736)
    float* bkT   = (float*)(ws + 37748736);       // 4 MB    (ends 41943040)
    float* dnorm = (float*)(ws + 41943040);       // 64 KB   (ends 42008576)
    float* vmax  = (float*)(ws + 42008576);       // 64 KB   (ends 42074112)
    int*   ind   = (int*)  (ws + 42074112);       // 64 KB   (ends 42139648)
    int*   mp    = (int*)  (ws + 42139648);       // 16 KB   (ends 42156032)
    float* pvmax = (float*)(ws + 42156032);       // 256 KB  (ends 42418176)
    int*   pind  = (int*)  (ws + 42418176);       // 256 KB  (ends 42680320)

    hipLaunchKernelGGL(transpose_kernel, dim3(HWsz / 32, Csz / 32, BZsz), dim3(32, 8), 0, stream,
                       inp, inpT);
    hipLaunchKernelGGL(maskpos_init, dim3(HWsz / 256), dim3(256), 0, stream, mp);
    hipLaunchKernelGGL(maskpos_set, dim3((Msz + 255) / 256), dim3(256), 0, stream, midx, mp);
    hipLaunchKernelGGL(colnorm_kernel, dim3(HWsz / 256, BZsz), dim3(256), 0, stream, inp, dnorm);
    hipLaunchKernelGGL(knprep_kernel, dim3(Ksz / 4, BZsz), dim3(256), 0, stream,
                       inpT, dnorm, kidx, knT);
    hipLaunchKernelGGL(sim_argmax_kernel, dim3(BZsz, HWsz / 128, KSPL), dim3(256), 0, stream,
                       knT, refm, pvmax, pind);
    hipLaunchKernelGGL(combine_kernel, dim3(HWsz / 256, BZsz), dim3(256), 0, stream,
                       pvmax, pind, vmax, ind);
    hipLaunchKernelGGL(scanprep_kernel, dim3(Msz / 4, BZsz), dim3(256), 0, stream,
                       inpT, dnorm, ind, midx, kidx, uT, bkT);
    hipLaunchKernelGGL(scan_kernel, dim3(BZsz), dim3(64), 0, stream,
                       uT, bkT, vmax, midx, outT);
    hipLaunchKernelGGL(finalize_kernel, dim3(BZsz, HWsz / 64), dim3(256), 0, stream,
                       inpT, outT, ind, kidx, mp, out);
}

// Round 13
// 1334.484 us; speedup vs baseline: 1.0366x; 1.0366x over previous
//
#include <hip/hip_runtime.h>
#include <hip/hip_bf16.h>
#include <math.h>

#define HWsz 4096
#define Csz  256
#define BZsz 4
#define Msz  1024
#define Ksz  3072
#define KSPL 4
#define KPER 768      // Ksz / KSPL
#define NKT  6        // KPER / 128
#define LDP  132      // padded LDS row (floats)

typedef float f32x2 __attribute__((ext_vector_type(2)));

// ---------------------------------------------------------------------------
// K0: transpose input [b][c][p] -> inpT [b][p][c]
// ---------------------------------------------------------------------------
__global__ void transpose_kernel(const float* __restrict__ in, float* __restrict__ outT) {
    __shared__ float tile[32][33];
    int b  = blockIdx.z;
    int p0 = blockIdx.x * 32;
    int c0 = blockIdx.y * 32;
    int tx = threadIdx.x;  // 32
    int ty = threadIdx.y;  // 8
#pragma unroll
    for (int i = 0; i < 4; i++) {
        int c = c0 + ty + i * 8;
        tile[ty + i * 8][tx] = in[((size_t)b * Csz + c) * HWsz + p0 + tx];
    }
    __syncthreads();
#pragma unroll
    for (int i = 0; i < 4; i++) {
        int p = p0 + ty + i * 8;
        outT[((size_t)b * HWsz + p) * Csz + c0 + tx] = tile[tx][ty + i * 8];
    }
}

// ---------------------------------------------------------------------------
// K1: norm replica: f32 square (rounded mult), STRICTLY SEQUENTIAL f32 sum
// over c ascending, IEEE f32 sqrt, + 1e-8f.  (unchanged numerics)
// ---------------------------------------------------------------------------
__global__ void colnorm_kernel(const float* __restrict__ inp, float* __restrict__ dnorm) {
#pragma clang fp contract(off)
    int p = blockIdx.x * 256 + threadIdx.x;   // 0..HW-1
    int b = blockIdx.y;
    const float* col = inp + (size_t)b * Csz * HWsz + p;
    float acc = 0.f;
    for (int c = 0; c < Csz; c++) {
        float x  = col[(size_t)c * HWsz];
        float sq = x * x;
        acc = acc + sq;
    }
    dnorm[b * HWsz + p] = sqrtf(acc) + 1e-8f;
}

// ---------------------------------------------------------------------------
// K1b: knT[b][kk][c] = inpT[b][kidx[kk]][c] / dn  (IEEE f32 div, once)
// ---------------------------------------------------------------------------
__global__ void knprep_kernel(const float* __restrict__ inpT, const float* __restrict__ dnorm,
                              const int* __restrict__ kidx, float* __restrict__ knT) {
    int row  = blockIdx.x * 4 + (threadIdx.x >> 6);
    int lane = threadIdx.x & 63;
    int b    = blockIdx.y;
    int kid  = kidx[row];
    float dn = dnorm[b * HWsz + kid];
    const float* src = inpT + ((size_t)b * HWsz + kid) * Csz + lane * 4;
    float4 v = *(const float4*)src;
    float4 w = {v.x / dn, v.y / dn, v.z / dn, v.w / dn};
    *(float4*)(knT + ((size_t)b * Ksz + row) * Csz + lane * 4) = w;
}

// ---------------------------------------------------------------------------
// K2 v3: sim einsum replica with packed-f32 VALU (unchanged from R10/R12).
// ---------------------------------------------------------------------------
#define PK_MUL(dst, s0, s1) asm("v_pk_mul_f32 %0, %1, %2" : "=v"(dst) : "v"(s0), "v"(s1))
#define PK_ADD(dst, s1)     asm("v_pk_add_f32 %0, %0, %1" : "+v"(dst) : "v"(s1))

__launch_bounds__(256, 2)
__global__ void sim_argmax_kernel(const float* __restrict__ knT,
                                  const float* __restrict__ refm,
                                  float* __restrict__ pvmax, int* __restrict__ pind) {
#pragma clang fp contract(off)
    __shared__ float rf[64][LDP];   // [c][p]
    __shared__ float kn[64][LDP];   // [c][k]

    int b   = blockIdx.x;
    int p0  = blockIdx.y * 128;
    int ks  = blockIdx.z;
    int k0  = ks * KPER;
    int tid = threadIdx.x;

    int tr = tid >> 4;          // 0..15 -> p = p0 + tr*8 + i
    int tc = tid & 15;          // 0..15 -> k = tile_k0 + tc*8 + j

    int spp = tid & 127;        // rf: pixel col
    int sch = tid >> 7;         // rf: row parity
    int skk = tid >> 1;         // kn: k row (0..127)
    int sc4 = (tid & 1) * 32;   // kn: c offset (0 or 32)

    float best[8];
    int   bidx[8];
#pragma unroll
    for (int i = 0; i < 8; i++) { best[i] = -INFINITY; bidx[i] = 0x7fffffff; }

    for (int kt = 0; kt < NKT; kt++) {
        int ktbase = k0 + kt * 128;
        const float* nrow = knT + ((size_t)b * Ksz + ktbase + skk) * Csz;

        f32x2 acc[8][4];   // [i][jj] -> j = 2*jj (lo), 2*jj+1 (hi)
#pragma unroll
        for (int i = 0; i < 8; i++)
#pragma unroll
            for (int jj = 0; jj < 4; jj++) acc[i][jj] = (f32x2){0.f, 0.f};

        for (int cc = 0; cc < 4; cc++) {
            __syncthreads();
#pragma unroll 8
            for (int i = 0; i < 32; i++) {
                int c = i * 2 + sch;
                rf[c][spp] = refm[((size_t)b * Csz + cc * 64 + c) * HWsz + p0 + spp];
            }
            const float* src = nrow + cc * 64 + sc4;
#pragma unroll
            for (int i = 0; i < 8; i++) {
                float4 v = *(const float4*)(src + i * 4);
                int c = sc4 + i * 4;
                kn[c + 0][skk] = v.x;
                kn[c + 1][skk] = v.y;
                kn[c + 2][skk] = v.z;
                kn[c + 3][skk] = v.w;
            }
            __syncthreads();

#pragma unroll 2
            for (int c = 0; c < 64; c++) {
                float4 a0 = *(const float4*)&rf[c][tr * 8];
                float4 a1 = *(const float4*)&rf[c][tr * 8 + 4];
                float4 b0 = *(const float4*)&kn[c][tc * 8];
                float4 b1 = *(const float4*)&kn[c][tc * 8 + 4];
                float av[8] = {a0.x, a0.y, a0.z, a0.w, a1.x, a1.y, a1.z, a1.w};
                f32x2 B[4] = {{b0.x, b0.y}, {b0.z, b0.w}, {b1.x, b1.y}, {b1.z, b1.w}};
#pragma unroll
                for (int i = 0; i < 8; i++) {
                    f32x2 av2 = {av[i], av[i]};
#pragma unroll
                    for (int jj = 0; jj < 4; jj++) {
                        f32x2 pr;
                        PK_MUL(pr, av2, B[jj]);       // two IEEE f32 muls
                        PK_ADD(acc[i][jj], pr);       // two IEEE f32 adds
                    }
                }
            }
        }
        // argmax update, k ascending (kt asc, j asc)
#pragma unroll
        for (int j = 0; j < 8; j++) {
            int k = ktbase + tc * 8 + j;
#pragma unroll
            for (int i = 0; i < 8; i++) {
                float v = (j & 1) ? acc[i][j >> 1].y : acc[i][j >> 1].x;
                if (v > best[i] || (v == best[i] && k < bidx[i])) { best[i] = v; bidx[i] = k; }
            }
        }
    }

    // reduce across tc groups (reuse LDS)
    __syncthreads();
    float* sv = &rf[0][0];          // 128p x 16tc
    int*   si = (int*)&kn[0][0];
#pragma unroll
    for (int i = 0; i < 8; i++) {
        int p = tr * 8 + i;
        sv[p * 16 + tc] = best[i];
        si[p * 16 + tc] = bidx[i];
    }
    __syncthreads();
    if (tid < 128) {
        float bv = -INFINITY; int bi = 0x7fffffff;
        for (int t = 0; t < 16; t++) {
            float v = sv[tid * 16 + t];
            int   k = si[tid * 16 + t];
            if (v > bv || (v == bv && k < bi)) { bv = v; bi = k; }
        }
        pvmax[((size_t)ks * BZsz + b) * HWsz + p0 + tid] = bv;
        pind [((size_t)ks * BZsz + b) * HWsz + p0 + tid] = bi;
    }
}

// ---------------------------------------------------------------------------
// K2b: combine K-splits (ascending ks => global first-max)
// ---------------------------------------------------------------------------
__global__ void combine_kernel(const float* __restrict__ pvmax, const int* __restrict__ pind,
                               float* __restrict__ vmax, int* __restrict__ ind) {
    int p = blockIdx.x * 256 + threadIdx.x;
    int b = blockIdx.y;
    float bv = -INFINITY; int bi = 0x7fffffff;
    for (int ks = 0; ks < KSPL; ks++) {
        float v = pvmax[((size_t)ks * BZsz + b) * HWsz + p];
        int   k = pind [((size_t)ks * BZsz + b) * HWsz + p];
        if (v > bv || (v == bv && k < bi)) { bv = v; bi = k; }
    }
    vmax[b * HWsz + p] = bv;
    ind [b * HWsz + p] = bi;
}

// ---------------------------------------------------------------------------
// K2c: scanprep: uT[b][t][c] = inpT[b][midx[t]][c] / dn (IEEE f32 div),
// bkT[b][t][c] = inpT[b][kidx[ind[..]]][c] (raw copy).
// ---------------------------------------------------------------------------
__global__ void scanprep_kernel(const float* __restrict__ inpT, const float* __restrict__ dnorm,
                                const int* __restrict__ ind, const int* __restrict__ midx,
                                const int* __restrict__ kidx,
                                float* __restrict__ uT, float* __restrict__ bkT) {
    int t    = blockIdx.x * 4 + (threadIdx.x >> 6);
    int lane = threadIdx.x & 63;
    int b    = blockIdx.y;
    int pp   = midx[t];
    float dn = dnorm[b * HWsz + pp];
    int bkid = kidx[ind[b * HWsz + pp]];
    const float* us = inpT + ((size_t)b * HWsz + pp) * Csz + lane * 4;
    const float* bs = inpT + ((size_t)b * HWsz + bkid) * Csz + lane * 4;
    float4 v = *(const float4*)us;
    float4 w = {v.x / dn, v.y / dn, v.z / dn, v.w / dn};
    *(float4*)(uT  + ((size_t)b * Msz + t) * Csz + lane * 4) = w;
    *(float4*)(bkT + ((size_t)b * Msz + t) * Csz + lane * 4) = *(const float4*)bs;
}

// ---------------------------------------------------------------------------
// K3 v5: serial scan, one wave per image. Numerics IDENTICAL to R7..R12:
//   pair terms r = fmaf(u_even, o_even, f32(u_odd*o_odd)); dot = strictly
//   sequential f32 adds over the 128 pair terms ascending (rA(l),rB(l) at
//   positions 2l, 2l+1); denom = at+vm; IEEE f32 divs; update mul,mul,add.
// Cross-lane broadcast via v_readlane -> SGPR (no LDS, no barrier, no lgkm
// stalls): 128 independent readlanes overlap the serial add chain; every
// lane redundantly computes the identical chain from the same SGPR values.
// ---------------------------------------------------------------------------
__launch_bounds__(64, 1)
__global__ void scan_kernel(const float* __restrict__ uT, const float* __restrict__ bkT,
                            const float* __restrict__ vmax, const int* __restrict__ midx,
                            float* __restrict__ outT) {
#pragma clang fp contract(off)
    __shared__ float L_vm[Msz];
    int b    = blockIdx.x;
    int lane = threadIdx.x;

    for (int t0 = 0; t0 < Msz; t0 += 64) {
        int t = t0 + lane;
        L_vm[t] = vmax[b * HWsz + midx[t]];
    }
    __syncthreads();

    const float* ub = uT  + (size_t)b * Msz * Csz + lane * 4;
    const float* bb = bkT + (size_t)b * Msz * Csz + lane * 4;
    float o0 = 0.f, o1 = 0.f, o2 = 0.f, o3 = 0.f;
    float4 U[4], Bk[4];
#pragma unroll
    for (int s = 0; s < 4; s++) {
        U[s]  = *(const float4*)(ub + (size_t)s * Csz);
        Bk[s] = *(const float4*)(bb + (size_t)s * Csz);
    }

    for (int t = 0; t < Msz; t += 4) {
#pragma unroll
        for (int s = 0; s < 4; s++) {
            int tt = t + s;
            float4 u = U[s];
            // sdot strided pair terms: r = fmaf(y0,x0, fl(y1*x1)); 2 pairs/lane
            float pA = u.y * o1;
            float rA = __builtin_fmaf(u.x, o0, pA);
            float pB = u.w * o3;
            float rB = __builtin_fmaf(u.z, o2, pB);
            // strictly sequential 128-add chain; terms broadcast via readlane
            // (order: rA(0), rB(0), rA(1), rB(1), ... == rbuf order of R7)
            unsigned uA = __float_as_uint(rA);
            unsigned uB = __float_as_uint(rB);
            float dot = 0.f;
#pragma unroll
            for (int q = 0; q < 64; q++) {
                float sa = __uint_as_float(__builtin_amdgcn_readlane(uA, q));
                float sb = __uint_as_float(__builtin_amdgcn_readlane(uB, q));
                dot = dot + sa;
                dot = dot + sb;
            }
            float at    = dot;
            float vm    = L_vm[tt];
            float denom = at + vm;      // f32 add
            float anew  = at / denom;   // IEEE f32 div
            float aori  = vm / denom;   // IEEE f32 div
            float m0 = anew * o0, n0 = aori * Bk[s].x;
            float m1 = anew * o1, n1 = aori * Bk[s].y;
            float m2 = anew * o2, n2 = aori * Bk[s].z;
            float m3 = anew * o3, n3 = aori * Bk[s].w;
            o0 = m0 + n0; o1 = m1 + n1; o2 = m2 + n2; o3 = m3 + n3;
            float4 w = {o0, o1, o2, o3};
            *(float4*)&outT[((size_t)b * Msz + tt) * Csz + lane * 4] = w;
            if (tt + 4 < Msz) {
                U[s]  = *(const float4*)(ub + (size_t)(tt + 4) * Csz);
                Bk[s] = *(const float4*)(bb + (size_t)(tt + 4) * Csz);
            }
        }
    }
}

// ---------------------------------------------------------------------------
// K4: mask position map
// ---------------------------------------------------------------------------
__global__ void maskpos_init(int* mp) { mp[blockIdx.x * 256 + threadIdx.x] = -1; }
__global__ void maskpos_set(const int* __restrict__ midx, int* mp) {
    int t = blockIdx.x * 256 + threadIdx.x;
    if (t < Msz) mp[midx[t]] = t;
}

// ---------------------------------------------------------------------------
// K5: assemble output [b][c][p]: masked -> scan carry row, known -> gathered col
// ---------------------------------------------------------------------------
#define FSTR 261
__launch_bounds__(256)
__global__ void finalize_kernel(const float* __restrict__ inpT, const float* __restrict__ outT,
                                const int* __restrict__ ind, const int* __restrict__ kidx,
                                const int* __restrict__ mp, float* __restrict__ out) {
    __shared__ float tile[64 * FSTR];
    int b   = blockIdx.x;
    int p0  = blockIdx.y * 64;
    int tid = threadIdx.x;
    int rl  = tid >> 6;          // 0..3
    int cc  = (tid & 63) * 4;    // float4 col offset
    for (int i = 0; i < 16; i++) {
        int r = rl + i * 4;
        int p = p0 + r;
        int m = mp[p];
        const float* src = (m >= 0) ? (outT + ((size_t)b * Msz + m) * Csz)
                                    : (inpT + ((size_t)b * HWsz + kidx[ind[b * HWsz + p]]) * Csz);
        float4 v = *(const float4*)(src + cc);
        tile[r * FSTR + cc + 0] = v.x;
        tile[r * FSTR + cc + 1] = v.y;
        tile[r * FSTR + cc + 2] = v.z;
        tile[r * FSTR + cc + 3] = v.w;
    }
    __syncthreads();
    int pp = tid & 63;
    int c0 = tid >> 6;
    for (int i = 0; i < 64; i++) {
        int c = c0 + i * 4;
        out[((size_t)b * Csz + c) * HWsz + p0 + pp] = tile[pp * FSTR + c];
    }
}

// ---------------------------------------------------------------------------
extern "C" void kernel_launch(void* const* d_in, const int* in_sizes, int n_in,
                              void* d_out, int out_size, void* d_ws, size_t ws_size,
                              hipStream_t stream) {
    const float* inp  = (const float*)d_in[0];
    const float* refm = (const float*)d_in[1];
    const int*   midx = (const int*)d_in[2];
    const int*   kidx = (const int*)d_in[3];
    float* out = (float*)d_out;

    char* ws = (char*)d_ws;
    float* inpT  = (float*)(ws);                  // 16 MB   (ends 16777216)
    float* outT  = (float*)(ws + 16777216);       // 4 MB    (ends 20971520)
    float* knT   = (float*)(ws + 20971520);       // 12 MB   (ends 33554432)
    float* uT    = (float*)(ws + 33554432);       // 4 MB    (ends 37748736)
    float* bkT   = (float*)(ws + 37748736);       // 4 MB    (ends 41943040)
    float* dnorm = (float*)(ws + 41943040);       // 64 KB   (ends 42008576)
    float* vmax  = (float*)(ws + 42008576);       // 64 KB   (ends 42074112)
    int*   ind   = (int*)  (ws + 42074112);       // 64 KB   (ends 42139648)
    int*   mp    = (int*)  (ws + 42139648);       // 16 KB   (ends 42156032)
    float* pvmax = (float*)(ws + 42156032);       // 256 KB  (ends 42418176)
    int*   pind  = (int*)  (ws + 42418176);       // 256 KB  (ends 42680320)

    hipLaunchKernelGGL(transpose_kernel, dim3(HWsz / 32, Csz / 32, BZsz), dim3(32, 8), 0, stream,
                       inp, inpT);
    hipLaunchKernelGGL(maskpos_init, dim3(HWsz / 256), dim3(256), 0, stream, mp);
    hipLaunchKernelGGL(maskpos_set, dim3((Msz + 255) / 256), dim3(256), 0, stream, midx, mp);
    hipLaunchKernelGGL(colnorm_kernel, dim3(HWsz / 256, BZsz), dim3(256), 0, stream, inp, dnorm);
    hipLaunchKernelGGL(knprep_kernel, dim3(Ksz / 4, BZsz), dim3(256), 0, stream,
                       inpT, dnorm, kidx, knT);
    hipLaunchKernelGGL(sim_argmax_kernel, dim3(BZsz, HWsz / 128, KSPL), dim3(256), 0, stream,
                       knT, refm, pvmax, pind);
    hipLaunchKernelGGL(combine_kernel, dim3(HWsz / 256, BZsz), dim3(256), 0, stream,
                       pvmax, pind, vmax, ind);
    hipLaunchKernelGGL(scanprep_kernel, dim3(Msz / 4, BZsz), dim3(256), 0, stream,
                       inpT, dnorm, ind, midx, kidx, uT, bkT);
    hipLaunchKernelGGL(scan_kernel, dim3(BZsz), dim3(64), 0, stream,
                       uT, bkT, vmax, midx, outT);
    hipLaunchKernelGGL(finalize_kernel, dim3(BZsz, HWsz / 64), dim3(256), 0, stream,
                       inpT, outT, ind, kidx, mp, out);
}

// Round 14
// 1237.756 us; speedup vs baseline: 1.1177x; 1.0781x over previous
//
#include <hip/hip_runtime.h>
#include <hip/hip_bf16.h>
#include <math.h>

#define HWsz 4096
#define Csz  256
#define BZsz 4
#define Msz  1024
#define Ksz  3072
#define KSPL 4
#define KPER 768      // Ksz / KSPL
#define NKT  6        // KPER / 128
#define LDP  132      // padded LDS row (floats)

typedef float f32x2 __attribute__((ext_vector_type(2)));

// ---------------------------------------------------------------------------
// K0: transpose input [b][c][p] -> inpT [b][p][c]
// ---------------------------------------------------------------------------
__global__ void transpose_kernel(const float* __restrict__ in, float* __restrict__ outT) {
    __shared__ float tile[32][33];
    int b  = blockIdx.z;
    int p0 = blockIdx.x * 32;
    int c0 = blockIdx.y * 32;
    int tx = threadIdx.x;  // 32
    int ty = threadIdx.y;  // 8
#pragma unroll
    for (int i = 0; i < 4; i++) {
        int c = c0 + ty + i * 8;
        tile[ty + i * 8][tx] = in[((size_t)b * Csz + c) * HWsz + p0 + tx];
    }
    __syncthreads();
#pragma unroll
    for (int i = 0; i < 4; i++) {
        int p = p0 + ty + i * 8;
        outT[((size_t)b * HWsz + p) * Csz + c0 + tx] = tile[tx][ty + i * 8];
    }
}

// ---------------------------------------------------------------------------
// K1: norm replica: f32 square (rounded mult), STRICTLY SEQUENTIAL f32 sum
// over c ascending, IEEE f32 sqrt, + 1e-8f.  (unchanged numerics)
// ---------------------------------------------------------------------------
__global__ void colnorm_kernel(const float* __restrict__ inp, float* __restrict__ dnorm) {
#pragma clang fp contract(off)
    int p = blockIdx.x * 256 + threadIdx.x;   // 0..HW-1
    int b = blockIdx.y;
    const float* col = inp + (size_t)b * Csz * HWsz + p;
    float acc = 0.f;
    for (int c = 0; c < Csz; c++) {
        float x  = col[(size_t)c * HWsz];
        float sq = x * x;
        acc = acc + sq;
    }
    dnorm[b * HWsz + p] = sqrtf(acc) + 1e-8f;
}

// ---------------------------------------------------------------------------
// K1b: knT[b][kk][c] = inpT[b][kidx[kk]][c] / dn  (IEEE f32 div, once)
// ---------------------------------------------------------------------------
__global__ void knprep_kernel(const float* __restrict__ inpT, const float* __restrict__ dnorm,
                              const int* __restrict__ kidx, float* __restrict__ knT) {
    int row  = blockIdx.x * 4 + (threadIdx.x >> 6);
    int lane = threadIdx.x & 63;
    int b    = blockIdx.y;
    int kid  = kidx[row];
    float dn = dnorm[b * HWsz + kid];
    const float* src = inpT + ((size_t)b * HWsz + kid) * Csz + lane * 4;
    float4 v = *(const float4*)src;
    float4 w = {v.x / dn, v.y / dn, v.z / dn, v.w / dn};
    *(float4*)(knT + ((size_t)b * Ksz + row) * Csz + lane * 4) = w;
}

// ---------------------------------------------------------------------------
// K2 v3: sim einsum replica with packed-f32 VALU (unchanged from R10..R13).
// ---------------------------------------------------------------------------
#define PK_MUL(dst, s0, s1) asm("v_pk_mul_f32 %0, %1, %2" : "=v"(dst) : "v"(s0), "v"(s1))
#define PK_ADD(dst, s1)     asm("v_pk_add_f32 %0, %0, %1" : "+v"(dst) : "v"(s1))

__launch_bounds__(256, 2)
__global__ void sim_argmax_kernel(const float* __restrict__ knT,
                                  const float* __restrict__ refm,
                                  float* __restrict__ pvmax, int* __restrict__ pind) {
#pragma clang fp contract(off)
    __shared__ float rf[64][LDP];   // [c][p]
    __shared__ float kn[64][LDP];   // [c][k]

    int b   = blockIdx.x;
    int p0  = blockIdx.y * 128;
    int ks  = blockIdx.z;
    int k0  = ks * KPER;
    int tid = threadIdx.x;

    int tr = tid >> 4;          // 0..15 -> p = p0 + tr*8 + i
    int tc = tid & 15;          // 0..15 -> k = tile_k0 + tc*8 + j

    int spp = tid & 127;        // rf: pixel col
    int sch = tid >> 7;         // rf: row parity
    int skk = tid >> 1;         // kn: k row (0..127)
    int sc4 = (tid & 1) * 32;   // kn: c offset (0 or 32)

    float best[8];
    int   bidx[8];
#pragma unroll
    for (int i = 0; i < 8; i++) { best[i] = -INFINITY; bidx[i] = 0x7fffffff; }

    for (int kt = 0; kt < NKT; kt++) {
        int ktbase = k0 + kt * 128;
        const float* nrow = knT + ((size_t)b * Ksz + ktbase + skk) * Csz;

        f32x2 acc[8][4];   // [i][jj] -> j = 2*jj (lo), 2*jj+1 (hi)
#pragma unroll
        for (int i = 0; i < 8; i++)
#pragma unroll
            for (int jj = 0; jj < 4; jj++) acc[i][jj] = (f32x2){0.f, 0.f};

        for (int cc = 0; cc < 4; cc++) {
            __syncthreads();
#pragma unroll 8
            for (int i = 0; i < 32; i++) {
                int c = i * 2 + sch;
                rf[c][spp] = refm[((size_t)b * Csz + cc * 64 + c) * HWsz + p0 + spp];
            }
            const float* src = nrow + cc * 64 + sc4;
#pragma unroll
            for (int i = 0; i < 8; i++) {
                float4 v = *(const float4*)(src + i * 4);
                int c = sc4 + i * 4;
                kn[c + 0][skk] = v.x;
                kn[c + 1][skk] = v.y;
                kn[c + 2][skk] = v.z;
                kn[c + 3][skk] = v.w;
            }
            __syncthreads();

#pragma unroll 2
            for (int c = 0; c < 64; c++) {
                float4 a0 = *(const float4*)&rf[c][tr * 8];
                float4 a1 = *(const float4*)&rf[c][tr * 8 + 4];
                float4 b0 = *(const float4*)&kn[c][tc * 8];
                float4 b1 = *(const float4*)&kn[c][tc * 8 + 4];
                float av[8] = {a0.x, a0.y, a0.z, a0.w, a1.x, a1.y, a1.z, a1.w};
                f32x2 B[4] = {{b0.x, b0.y}, {b0.z, b0.w}, {b1.x, b1.y}, {b1.z, b1.w}};
#pragma unroll
                for (int i = 0; i < 8; i++) {
                    f32x2 av2 = {av[i], av[i]};
#pragma unroll
                    for (int jj = 0; jj < 4; jj++) {
                        f32x2 pr;
                        PK_MUL(pr, av2, B[jj]);       // two IEEE f32 muls
                        PK_ADD(acc[i][jj], pr);       // two IEEE f32 adds
                    }
                }
            }
        }
        // argmax update, k ascending (kt asc, j asc)
#pragma unroll
        for (int j = 0; j < 8; j++) {
            int k = ktbase + tc * 8 + j;
#pragma unroll
            for (int i = 0; i < 8; i++) {
                float v = (j & 1) ? acc[i][j >> 1].y : acc[i][j >> 1].x;
                if (v > best[i] || (v == best[i] && k < bidx[i])) { best[i] = v; bidx[i] = k; }
            }
        }
    }

    // reduce across tc groups (reuse LDS)
    __syncthreads();
    float* sv = &rf[0][0];          // 128p x 16tc
    int*   si = (int*)&kn[0][0];
#pragma unroll
    for (int i = 0; i < 8; i++) {
        int p = tr * 8 + i;
        sv[p * 16 + tc] = best[i];
        si[p * 16 + tc] = bidx[i];
    }
    __syncthreads();
    if (tid < 128) {
        float bv = -INFINITY; int bi = 0x7fffffff;
        for (int t = 0; t < 16; t++) {
            float v = sv[tid * 16 + t];
            int   k = si[tid * 16 + t];
            if (v > bv || (v == bv && k < bi)) { bv = v; bi = k; }
        }
        pvmax[((size_t)ks * BZsz + b) * HWsz + p0 + tid] = bv;
        pind [((size_t)ks * BZsz + b) * HWsz + p0 + tid] = bi;
    }
}

// ---------------------------------------------------------------------------
// K2b: combine K-splits (ascending ks => global first-max)
// ---------------------------------------------------------------------------
__global__ void combine_kernel(const float* __restrict__ pvmax, const int* __restrict__ pind,
                               float* __restrict__ vmax, int* __restrict__ ind) {
    int p = blockIdx.x * 256 + threadIdx.x;
    int b = blockIdx.y;
    float bv = -INFINITY; int bi = 0x7fffffff;
    for (int ks = 0; ks < KSPL; ks++) {
        float v = pvmax[((size_t)ks * BZsz + b) * HWsz + p];
        int   k = pind [((size_t)ks * BZsz + b) * HWsz + p];
        if (v > bv || (v == bv && k < bi)) { bv = v; bi = k; }
    }
    vmax[b * HWsz + p] = bv;
    ind [b * HWsz + p] = bi;
}

// ---------------------------------------------------------------------------
// K2c: scanprep: uT[b][t][c] = inpT[b][midx[t]][c] / dn (IEEE f32 div),
// bkT[b][t][c] = inpT[b][kidx[ind[..]]][c] (raw copy).
// ---------------------------------------------------------------------------
__global__ void scanprep_kernel(const float* __restrict__ inpT, const float* __restrict__ dnorm,
                                const int* __restrict__ ind, const int* __restrict__ midx,
                                const int* __restrict__ kidx,
                                float* __restrict__ uT, float* __restrict__ bkT) {
    int t    = blockIdx.x * 4 + (threadIdx.x >> 6);
    int lane = threadIdx.x & 63;
    int b    = blockIdx.y;
    int pp   = midx[t];
    float dn = dnorm[b * HWsz + pp];
    int bkid = kidx[ind[b * HWsz + pp]];
    const float* us = inpT + ((size_t)b * HWsz + pp) * Csz + lane * 4;
    const float* bs = inpT + ((size_t)b * HWsz + bkid) * Csz + lane * 4;
    float4 v = *(const float4*)us;
    float4 w = {v.x / dn, v.y / dn, v.z / dn, v.w / dn};
    *(float4*)(uT  + ((size_t)b * Msz + t) * Csz + lane * 4) = w;
    *(float4*)(bkT + ((size_t)b * Msz + t) * Csz + lane * 4) = *(const float4*)bs;
}

// ---------------------------------------------------------------------------
// K3 v6: serial scan, one wave per image. Numerics IDENTICAL to R7..R13:
//   pair terms r = fmaf(u_even, o_even, f32(u_odd*o_odd)); dot = strictly
//   sequential f32 adds over the 128 pair terms ascending (rA(l),rB(l) at
//   positions 2l, 2l+1); denom = at+vm; IEEE f32 divs; update mul,mul,add.
// Chain is now a HAND-SCHEDULED inline-asm pipeline: ring of 16 SGPRs
// (s40-55), readlanes for lane q+4 issued between the dependent adds of
// lane q -> readlane issue hides under add latency. Same adds, same order,
// same accumulator => identical bits.
// ---------------------------------------------------------------------------

// CH(q4, next A-slot, next B-slot, cur A-slot, cur B-slot)
#define CH(LQ4, RA_N, RB_N, RA_C, RB_C) \
    "v_readlane_b32 " #RA_N ", %[va], " #LQ4 "\n\t" \
    "v_add_f32 %[dot], " #RA_C ", %[dot]\n\t" \
    "v_readlane_b32 " #RB_N ", %[vb], " #LQ4 "\n\t" \
    "v_add_f32 %[dot], " #RB_C ", %[dot]\n\t"

#define CH_BLOCK8(L0, L1, L2, L3, L4, L5, L6, L7) \
    CH(L0, s44, s52, s40, s48) \
    CH(L1, s45, s53, s41, s49) \
    CH(L2, s46, s54, s42, s50) \
    CH(L3, s47, s55, s43, s51) \
    CH(L4, s40, s48, s44, s52) \
    CH(L5, s41, s49, s45, s53) \
    CH(L6, s42, s50, s46, s54) \
    CH(L7, s43, s51, s47, s55)

__launch_bounds__(64, 1)
__global__ void scan_kernel(const float* __restrict__ uT, const float* __restrict__ bkT,
                            const float* __restrict__ vmax, const int* __restrict__ midx,
                            float* __restrict__ outT) {
#pragma clang fp contract(off)
    __shared__ float L_vm[Msz];
    int b    = blockIdx.x;
    int lane = threadIdx.x;

    for (int t0 = 0; t0 < Msz; t0 += 64) {
        int t = t0 + lane;
        L_vm[t] = vmax[b * HWsz + midx[t]];
    }
    __syncthreads();

    const float* ub = uT  + (size_t)b * Msz * Csz + lane * 4;
    const float* bb = bkT + (size_t)b * Msz * Csz + lane * 4;
    float o0 = 0.f, o1 = 0.f, o2 = 0.f, o3 = 0.f;
    float4 U[4], Bk[4];
#pragma unroll
    for (int s = 0; s < 4; s++) {
        U[s]  = *(const float4*)(ub + (size_t)s * Csz);
        Bk[s] = *(const float4*)(bb + (size_t)s * Csz);
    }

    for (int t = 0; t < Msz; t += 4) {
#pragma unroll
        for (int s = 0; s < 4; s++) {
            int tt = t + s;
            float4 u = U[s];
            // sdot strided pair terms: r = fmaf(y0,x0, fl(y1*x1)); 2 pairs/lane
            float pA = u.y * o1;
            float rA = __builtin_fmaf(u.x, o0, pA);
            float pB = u.w * o3;
            float rB = __builtin_fmaf(u.z, o2, pB);
            // strictly sequential 128-add chain (order rA(0),rB(0),rA(1),...)
            // hand-scheduled: readlane(q+4) interleaved with adds(q)
            float dot = 0.f;
            asm volatile(
                "v_readlane_b32 s40, %[va], 0\n\t"
                "v_readlane_b32 s48, %[vb], 0\n\t"
                "v_readlane_b32 s41, %[va], 1\n\t"
                "v_readlane_b32 s49, %[vb], 1\n\t"
                "v_readlane_b32 s42, %[va], 2\n\t"
                "v_readlane_b32 s50, %[vb], 2\n\t"
                "v_readlane_b32 s43, %[va], 3\n\t"
                "v_readlane_b32 s51, %[vb], 3\n\t"
                CH_BLOCK8( 4,  5,  6,  7,  8,  9, 10, 11)
                CH_BLOCK8(12, 13, 14, 15, 16, 17, 18, 19)
                CH_BLOCK8(20, 21, 22, 23, 24, 25, 26, 27)
                CH_BLOCK8(28, 29, 30, 31, 32, 33, 34, 35)
                CH_BLOCK8(36, 37, 38, 39, 40, 41, 42, 43)
                CH_BLOCK8(44, 45, 46, 47, 48, 49, 50, 51)
                CH_BLOCK8(52, 53, 54, 55, 56, 57, 58, 59)
                CH(60, s44, s52, s40, s48)
                CH(61, s45, s53, s41, s49)
                CH(62, s46, s54, s42, s50)
                CH(63, s47, s55, s43, s51)
                "v_add_f32 %[dot], s44, %[dot]\n\t"
                "v_add_f32 %[dot], s52, %[dot]\n\t"
                "v_add_f32 %[dot], s45, %[dot]\n\t"
                "v_add_f32 %[dot], s53, %[dot]\n\t"
                "v_add_f32 %[dot], s46, %[dot]\n\t"
                "v_add_f32 %[dot], s54, %[dot]\n\t"
                "v_add_f32 %[dot], s47, %[dot]\n\t"
                "v_add_f32 %[dot], s55, %[dot]\n\t"
                : [dot] "+v"(dot)
                : [va] "v"(rA), [vb] "v"(rB)
                : "s40","s41","s42","s43","s44","s45","s46","s47",
                  "s48","s49","s50","s51","s52","s53","s54","s55");
            float at    = dot;
            float vm    = L_vm[tt];
            float denom = at + vm;      // f32 add
            float anew  = at / denom;   // IEEE f32 div
            float aori  = vm / denom;   // IEEE f32 div
            float m0 = anew * o0, n0 = aori * Bk[s].x;
            float m1 = anew * o1, n1 = aori * Bk[s].y;
            float m2 = anew * o2, n2 = aori * Bk[s].z;
            float m3 = anew * o3, n3 = aori * Bk[s].w;
            o0 = m0 + n0; o1 = m1 + n1; o2 = m2 + n2; o3 = m3 + n3;
            float4 w = {o0, o1, o2, o3};
            *(float4*)&outT[((size_t)b * Msz + tt) * Csz + lane * 4] = w;
            if (tt + 4 < Msz) {
                U[s]  = *(const float4*)(ub + (size_t)(tt + 4) * Csz);
                Bk[s] = *(const float4*)(bb + (size_t)(tt + 4) * Csz);
            }
        }
    }
}

// ---------------------------------------------------------------------------
// K4: mask position map
// ---------------------------------------------------------------------------
__global__ void maskpos_init(int* mp) { mp[blockIdx.x * 256 + threadIdx.x] = -1; }
__global__ void maskpos_set(const int* __restrict__ midx, int* mp) {
    int t = blockIdx.x * 256 + threadIdx.x;
    if (t < Msz) mp[midx[t]] = t;
}

// ---------------------------------------------------------------------------
// K5: assemble output [b][c][p]: masked -> scan carry row, known -> gathered col
// ---------------------------------------------------------------------------
#define FSTR 261
__launch_bounds__(256)
__global__ void finalize_kernel(const float* __restrict__ inpT, const float* __restrict__ outT,
                                const int* __restrict__ ind, const int* __restrict__ kidx,
                                const int* __restrict__ mp, float* __restrict__ out) {
    __shared__ float tile[64 * FSTR];
    int b   = blockIdx.x;
    int p0  = blockIdx.y * 64;
    int tid = threadIdx.x;
    int rl  = tid >> 6;          // 0..3
    int cc  = (tid & 63) * 4;    // float4 col offset
    for (int i = 0; i < 16; i++) {
        int r = rl + i * 4;
        int p = p0 + r;
        int m = mp[p];
        const float* src = (m >= 0) ? (outT + ((size_t)b * Msz + m) * Csz)
                                    : (inpT + ((size_t)b * HWsz + kidx[ind[b * HWsz + p]]) * Csz);
        float4 v = *(const float4*)(src + cc);
        tile[r * FSTR + cc + 0] = v.x;
        tile[r * FSTR + cc + 1] = v.y;
        tile[r * FSTR + cc + 2] = v.z;
        tile[r * FSTR + cc + 3] = v.w;
    }
    __syncthreads();
    int pp = tid & 63;
    int c0 = tid >> 6;
    for (int i = 0; i < 64; i++) {
        int c = c0 + i * 4;
        out[((size_t)b * Csz + c) * HWsz + p0 + pp] = tile[pp * FSTR + c];
    }
}

// ---------------------------------------------------------------------------
extern "C" void kernel_launch(void* const* d_in, const int* in_sizes, int n_in,
                              void* d_out, int out_size, void* d_ws, size_t ws_size,
                              hipStream_t stream) {
    const float* inp  = (const float*)d_in[0];
    const float* refm = (const float*)d_in[1];
    const int*   midx = (const int*)d_in[2];
    const int*   kidx = (const int*)d_in[3];
    float* out = (float*)d_out;

    char* ws = (char*)d_ws;
    float* inpT  = (float*)(ws);                  // 16 MB   (ends 16777216)
    float* outT  = (float*)(ws + 16777216);       // 4 MB    (ends 20971520)
    float* knT   = (float*)(ws + 20971520);       // 12 MB   (ends 33554432)
    float* uT    = (float*)(ws + 33554432);       // 4 MB    (ends 37748736)
    float* bkT   = (float*)(ws + 37748736);       // 4 MB    (ends 41943040)
    float* dnorm = (float*)(ws + 41943040);       // 64 KB   (ends 42008576)
    float* vmax  = (float*)(ws + 42008576);       // 64 KB   (ends 42074112)
    int*   ind   = (int*)  (ws + 42074112);       // 64 KB   (ends 42139648)
    int*   mp    = (int*)  (ws + 42139648);       // 16 KB   (ends 42156032)
    float* pvmax = (float*)(ws + 42156032);       // 256 KB  (ends 42418176)
    int*   pind  = (int*)  (ws + 42418176);       // 256 KB  (ends 42680320)

    hipLaunchKernelGGL(transpose_kernel, dim3(HWsz / 32, Csz / 32, BZsz), dim3(32, 8), 0, stream,
                       inp, inpT);
    hipLaunchKernelGGL(maskpos_init, dim3(HWsz / 256), dim3(256), 0, stream, mp);
    hipLaunchKernelGGL(maskpos_set, dim3((Msz + 255) / 256), dim3(256), 0, stream, midx, mp);
    hipLaunchKernelGGL(colnorm_kernel, dim3(HWsz / 256, BZsz), dim3(256), 0, stream, inp, dnorm);
    hipLaunchKernelGGL(knprep_kernel, dim3(Ksz / 4, BZsz), dim3(256), 0, stream,
                       inpT, dnorm, kidx, knT);
    hipLaunchKernelGGL(sim_argmax_kernel, dim3(BZsz, HWsz / 128, KSPL), dim3(256), 0, stream,
                       knT, refm, pvmax, pind);
    hipLaunchKernelGGL(combine_kernel, dim3(HWsz / 256, BZsz), dim3(256), 0, stream,
                       pvmax, pind, vmax, ind);
    hipLaunchKernelGGL(scanprep_kernel, dim3(Msz / 4, BZsz), dim3(256), 0, stream,
                       inpT, dnorm, ind, midx, kidx, uT, bkT);
    hipLaunchKernelGGL(scan_kernel, dim3(BZsz), dim3(64), 0, stream,
                       uT, bkT, vmax, midx, outT);
    hipLaunchKernelGGL(finalize_kernel, dim3(BZsz, HWsz / 64), dim3(256), 0, stream,
                       inpT, outT, ind, kidx, mp, out);
}

// Round 15
// 1200.233 us; speedup vs baseline: 1.1526x; 1.0313x over previous
//
#include <hip/hip_runtime.h>
#include <hip/hip_bf16.h>
#include <math.h>

#define HWsz 4096
#define Csz  256
#define BZsz 4
#define Msz  1024
#define Ksz  3072
#define KSPL 4
#define KPER 768      // Ksz / KSPL
#define NKT  6        // KPER / 128
#define LDP  132      // rf padded row (floats), 132*4=528B = 33*16 (b128-aligned rows)
#define KLD  140      // kn padded row: 128 + 4-float pad per 32 (bank depad)

typedef float f32x2 __attribute__((ext_vector_type(2)));

// ---------------------------------------------------------------------------
// K0: transpose input [b][c][p] -> inpT [b][p][c]
// ---------------------------------------------------------------------------
__global__ void transpose_kernel(const float* __restrict__ in, float* __restrict__ outT) {
    __shared__ float tile[32][33];
    int b  = blockIdx.z;
    int p0 = blockIdx.x * 32;
    int c0 = blockIdx.y * 32;
    int tx = threadIdx.x;  // 32
    int ty = threadIdx.y;  // 8
#pragma unroll
    for (int i = 0; i < 4; i++) {
        int c = c0 + ty + i * 8;
        tile[ty + i * 8][tx] = in[((size_t)b * Csz + c) * HWsz + p0 + tx];
    }
    __syncthreads();
#pragma unroll
    for (int i = 0; i < 4; i++) {
        int p = p0 + ty + i * 8;
        outT[((size_t)b * HWsz + p) * Csz + c0 + tx] = tile[tx][ty + i * 8];
    }
}

// ---------------------------------------------------------------------------
// K1: norm replica: f32 square (rounded mult), STRICTLY SEQUENTIAL f32 sum
// over c ascending, IEEE f32 sqrt, + 1e-8f.  (unchanged numerics)
// ---------------------------------------------------------------------------
__global__ void colnorm_kernel(const float* __restrict__ inp, float* __restrict__ dnorm) {
#pragma clang fp contract(off)
    int p = blockIdx.x * 256 + threadIdx.x;   // 0..HW-1
    int b = blockIdx.y;
    const float* col = inp + (size_t)b * Csz * HWsz + p;
    float acc = 0.f;
    for (int c = 0; c < Csz; c++) {
        float x  = col[(size_t)c * HWsz];
        float sq = x * x;
        acc = acc + sq;
    }
    dnorm[b * HWsz + p] = sqrtf(acc) + 1e-8f;
}

// ---------------------------------------------------------------------------
// K1b: knT[b][kk][c] = inpT[b][kidx[kk]][c] / dn  (IEEE f32 div, once)
// ---------------------------------------------------------------------------
__global__ void knprep_kernel(const float* __restrict__ inpT, const float* __restrict__ dnorm,
                              const int* __restrict__ kidx, float* __restrict__ knT) {
    int row  = blockIdx.x * 4 + (threadIdx.x >> 6);
    int lane = threadIdx.x & 63;
    int b    = blockIdx.y;
    int kid  = kidx[row];
    float dn = dnorm[b * HWsz + kid];
    const float* src = inpT + ((size_t)b * HWsz + kid) * Csz + lane * 4;
    float4 v = *(const float4*)src;
    float4 w = {v.x / dn, v.y / dn, v.z / dn, v.w / dn};
    *(float4*)(knT + ((size_t)b * Ksz + row) * Csz + lane * 4) = w;
}

// ---------------------------------------------------------------------------
// K2 v4: sim einsum replica with packed-f32 VALU.
// Numerics unchanged (per (p,k): single f32 accumulator, mul then add, NO
// fma, c ascending). v_pk ops = two independent IEEE f32 ops, bit-exact.
// LDS changes only: kn bank-depad (kcol = k + (k>>5)*4 -> 2-way aliasing,
// free) and b128-vectorized rf staging.
// grid (BZ, HW/128, KSPL), 256 thr, 2 blocks/CU (69.6KB LDS).
// ---------------------------------------------------------------------------
#define PK_MUL(dst, s0, s1) asm("v_pk_mul_f32 %0, %1, %2" : "=v"(dst) : "v"(s0), "v"(s1))
#define PK_ADD(dst, s1)     asm("v_pk_add_f32 %0, %0, %1" : "+v"(dst) : "v"(s1))

__launch_bounds__(256, 2)
__global__ void sim_argmax_kernel(const float* __restrict__ knT,
                                  const float* __restrict__ refm,
                                  float* __restrict__ pvmax, int* __restrict__ pind) {
#pragma clang fp contract(off)
    __shared__ float rf[64][LDP];   // [c][p]
    __shared__ float kn[64][KLD];   // [c][kcol]

    int b   = blockIdx.x;
    int p0  = blockIdx.y * 128;
    int ks  = blockIdx.z;
    int k0  = ks * KPER;
    int tid = threadIdx.x;

    int tr = tid >> 4;          // 0..15 -> p = p0 + tr*8 + i
    int tc = tid & 15;          // 0..15 -> k = tile_k0 + tc*8 + j
    int kc = tc * 8 + ((tc >> 2) << 2);   // depadded base col for this k-group

    // rf staging roles (vectorized)
    int rowgrp = tid >> 5;          // 0..7
    int px4    = (tid & 31) * 4;    // float4 col offset
    // kn staging roles
    int skk  = tid >> 1;            // k row (0..127)
    int sc4  = (tid & 1) * 32;      // c offset (0 or 32)
    int kcol = skk + ((skk >> 5) << 2);

    float best[8];
    int   bidx[8];
#pragma unroll
    for (int i = 0; i < 8; i++) { best[i] = -INFINITY; bidx[i] = 0x7fffffff; }

    for (int kt = 0; kt < NKT; kt++) {
        int ktbase = k0 + kt * 128;
        const float* nrow = knT + ((size_t)b * Ksz + ktbase + skk) * Csz;

        f32x2 acc[8][4];   // [i][jj] -> j = 2*jj (lo), 2*jj+1 (hi)
#pragma unroll
        for (int i = 0; i < 8; i++)
#pragma unroll
            for (int jj = 0; jj < 4; jj++) acc[i][jj] = (f32x2){0.f, 0.f};

        for (int cc = 0; cc < 4; cc++) {
            __syncthreads();
            // stage rf[c][p] via float4 loads + b128 writes (contiguous)
#pragma unroll
            for (int i = 0; i < 8; i++) {
                int c = i * 8 + rowgrp;
                float4 v = *(const float4*)&refm[((size_t)b * Csz + cc * 64 + c) * HWsz + p0 + px4];
                *(float4*)&rf[c][px4] = v;
            }
            // stage kn[c][kcol] (values identical to R10..R14; layout depadded)
            const float* src = nrow + cc * 64 + sc4;
#pragma unroll
            for (int i = 0; i < 8; i++) {
                float4 v = *(const float4*)(src + i * 4);
                int c = sc4 + i * 4;
                kn[c + 0][kcol] = v.x;
                kn[c + 1][kcol] = v.y;
                kn[c + 2][kcol] = v.z;
                kn[c + 3][kcol] = v.w;
            }
            __syncthreads();

#pragma unroll 2
            for (int c = 0; c < 64; c++) {
                float4 a0 = *(const float4*)&rf[c][tr * 8];
                float4 a1 = *(const float4*)&rf[c][tr * 8 + 4];
                float4 b0 = *(const float4*)&kn[c][kc];
                float4 b1 = *(const float4*)&kn[c][kc + 4];
                float av[8] = {a0.x, a0.y, a0.z, a0.w, a1.x, a1.y, a1.z, a1.w};
                f32x2 B[4] = {{b0.x, b0.y}, {b0.z, b0.w}, {b1.x, b1.y}, {b1.z, b1.w}};
#pragma unroll
                for (int i = 0; i < 8; i++) {
                    f32x2 av2 = {av[i], av[i]};
#pragma unroll
                    for (int jj = 0; jj < 4; jj++) {
                        f32x2 pr;
                        PK_MUL(pr, av2, B[jj]);       // two IEEE f32 muls
                        PK_ADD(acc[i][jj], pr);       // two IEEE f32 adds
                    }
                }
            }
        }
        // argmax update, k ascending (kt asc, j asc)
#pragma unroll
        for (int j = 0; j < 8; j++) {
            int k = ktbase + tc * 8 + j;
#pragma unroll
            for (int i = 0; i < 8; i++) {
                float v = (j & 1) ? acc[i][j >> 1].y : acc[i][j >> 1].x;
                if (v > best[i] || (v == best[i] && k < bidx[i])) { best[i] = v; bidx[i] = k; }
            }
        }
    }

    // reduce across tc groups (reuse LDS)
    __syncthreads();
    float* sv = &rf[0][0];          // 128p x 16tc
    int*   si = (int*)&kn[0][0];
#pragma unroll
    for (int i = 0; i < 8; i++) {
        int p = tr * 8 + i;
        sv[p * 16 + tc] = best[i];
        si[p * 16 + tc] = bidx[i];
    }
    __syncthreads();
    if (tid < 128) {
        float bv = -INFINITY; int bi = 0x7fffffff;
        for (int t = 0; t < 16; t++) {
            float v = sv[tid * 16 + t];
            int   k = si[tid * 16 + t];
            if (v > bv || (v == bv && k < bi)) { bv = v; bi = k; }
        }
        pvmax[((size_t)ks * BZsz + b) * HWsz + p0 + tid] = bv;
        pind [((size_t)ks * BZsz + b) * HWsz + p0 + tid] = bi;
    }
}

// ---------------------------------------------------------------------------
// K2b: combine K-splits (ascending ks => global first-max)
// ---------------------------------------------------------------------------
__global__ void combine_kernel(const float* __restrict__ pvmax, const int* __restrict__ pind,
                               float* __restrict__ vmax, int* __restrict__ ind) {
    int p = blockIdx.x * 256 + threadIdx.x;
    int b = blockIdx.y;
    float bv = -INFINITY; int bi = 0x7fffffff;
    for (int ks = 0; ks < KSPL; ks++) {
        float v = pvmax[((size_t)ks * BZsz + b) * HWsz + p];
        int   k = pind [((size_t)ks * BZsz + b) * HWsz + p];
        if (v > bv || (v == bv && k < bi)) { bv = v; bi = k; }
    }
    vmax[b * HWsz + p] = bv;
    ind [b * HWsz + p] = bi;
}

// ---------------------------------------------------------------------------
// K2c: scanprep: uT[b][t][c] = inpT[b][midx[t]][c] / dn (IEEE f32 div),
// bkT[b][t][c] = inpT[b][kidx[ind[..]]][c] (raw copy).
// ---------------------------------------------------------------------------
__global__ void scanprep_kernel(const float* __restrict__ inpT, const float* __restrict__ dnorm,
                                const int* __restrict__ ind, const int* __restrict__ midx,
                                const int* __restrict__ kidx,
                                float* __restrict__ uT, float* __restrict__ bkT) {
    int t    = blockIdx.x * 4 + (threadIdx.x >> 6);
    int lane = threadIdx.x & 63;
    int b    = blockIdx.y;
    int pp   = midx[t];
    float dn = dnorm[b * HWsz + pp];
    int bkid = kidx[ind[b * HWsz + pp]];
    const float* us = inpT + ((size_t)b * HWsz + pp) * Csz + lane * 4;
    const float* bs = inpT + ((size_t)b * HWsz + bkid) * Csz + lane * 4;
    float4 v = *(const float4*)us;
    float4 w = {v.x / dn, v.y / dn, v.z / dn, v.w / dn};
    *(float4*)(uT  + ((size_t)b * Msz + t) * Csz + lane * 4) = w;
    *(float4*)(bkT + ((size_t)b * Msz + t) * Csz + lane * 4) = *(const float4*)bs;
}

// ---------------------------------------------------------------------------
// K3 v6: serial scan, one wave per image. Numerics IDENTICAL to R7..R14:
//   pair terms r = fmaf(u_even, o_even, f32(u_odd*o_odd)); dot = strictly
//   sequential f32 adds over the 128 pair terms ascending (rA(l),rB(l) at
//   positions 2l, 2l+1); denom = at+vm; IEEE f32 divs; update mul,mul,add.
// Hand-scheduled inline-asm chain: ring of 16 SGPRs, readlane(q+4)
// interleaved with the dependent adds of lane q.
// ---------------------------------------------------------------------------

// CH(q4, next A-slot, next B-slot, cur A-slot, cur B-slot)
#define CH(LQ4, RA_N, RB_N, RA_C, RB_C) \
    "v_readlane_b32 " #RA_N ", %[va], " #LQ4 "\n\t" \
    "v_add_f32 %[dot], " #RA_C ", %[dot]\n\t" \
    "v_readlane_b32 " #RB_N ", %[vb], " #LQ4 "\n\t" \
    "v_add_f32 %[dot], " #RB_C ", %[dot]\n\t"

#define CH_BLOCK8(L0, L1, L2, L3, L4, L5, L6, L7) \
    CH(L0, s44, s52, s40, s48) \
    CH(L1, s45, s53, s41, s49) \
    CH(L2, s46, s54, s42, s50) \
    CH(L3, s47, s55, s43, s51) \
    CH(L4, s40, s48, s44, s52) \
    CH(L5, s41, s49, s45, s53) \
    CH(L6, s42, s50, s46, s54) \
    CH(L7, s43, s51, s47, s55)

__launch_bounds__(64, 1)
__global__ void scan_kernel(const float* __restrict__ uT, const float* __restrict__ bkT,
                            const float* __restrict__ vmax, const int* __restrict__ midx,
                            float* __restrict__ outT) {
#pragma clang fp contract(off)
    __shared__ float L_vm[Msz];
    int b    = blockIdx.x;
    int lane = threadIdx.x;

    for (int t0 = 0; t0 < Msz; t0 += 64) {
        int t = t0 + lane;
        L_vm[t] = vmax[b * HWsz + midx[t]];
    }
    __syncthreads();

    const float* ub = uT  + (size_t)b * Msz * Csz + lane * 4;
    const float* bb = bkT + (size_t)b * Msz * Csz + lane * 4;
    float o0 = 0.f, o1 = 0.f, o2 = 0.f, o3 = 0.f;
    float4 U[4], Bk[4];
#pragma unroll
    for (int s = 0; s < 4; s++) {
        U[s]  = *(const float4*)(ub + (size_t)s * Csz);
        Bk[s] = *(const float4*)(bb + (size_t)s * Csz);
    }

    for (int t = 0; t < Msz; t += 4) {
#pragma unroll
        for (int s = 0; s < 4; s++) {
            int tt = t + s;
            float4 u = U[s];
            // sdot strided pair terms: r = fmaf(y0,x0, fl(y1*x1)); 2 pairs/lane
            float pA = u.y * o1;
            float rA = __builtin_fmaf(u.x, o0, pA);
            float pB = u.w * o3;
            float rB = __builtin_fmaf(u.z, o2, pB);
            // strictly sequential 128-add chain (order rA(0),rB(0),rA(1),...)
            float dot = 0.f;
            asm volatile(
                "v_readlane_b32 s40, %[va], 0\n\t"
                "v_readlane_b32 s48, %[vb], 0\n\t"
                "v_readlane_b32 s41, %[va], 1\n\t"
                "v_readlane_b32 s49, %[vb], 1\n\t"
                "v_readlane_b32 s42, %[va], 2\n\t"
                "v_readlane_b32 s50, %[vb], 2\n\t"
                "v_readlane_b32 s43, %[va], 3\n\t"
                "v_readlane_b32 s51, %[vb], 3\n\t"
                CH_BLOCK8( 4,  5,  6,  7,  8,  9, 10, 11)
                CH_BLOCK8(12, 13, 14, 15, 16, 17, 18, 19)
                CH_BLOCK8(20, 21, 22, 23, 24, 25, 26, 27)
                CH_BLOCK8(28, 29, 30, 31, 32, 33, 34, 35)
                CH_BLOCK8(36, 37, 38, 39, 40, 41, 42, 43)
                CH_BLOCK8(44, 45, 46, 47, 48, 49, 50, 51)
                CH_BLOCK8(52, 53, 54, 55, 56, 57, 58, 59)
                CH(60, s44, s52, s40, s48)
                CH(61, s45, s53, s41, s49)
                CH(62, s46, s54, s42, s50)
                CH(63, s47, s55, s43, s51)
                "v_add_f32 %[dot], s44, %[dot]\n\t"
                "v_add_f32 %[dot], s52, %[dot]\n\t"
                "v_add_f32 %[dot], s45, %[dot]\n\t"
                "v_add_f32 %[dot], s53, %[dot]\n\t"
                "v_add_f32 %[dot], s46, %[dot]\n\t"
                "v_add_f32 %[dot], s54, %[dot]\n\t"
                "v_add_f32 %[dot], s47, %[dot]\n\t"
                "v_add_f32 %[dot], s55, %[dot]\n\t"
                : [dot] "+v"(dot)
                : [va] "v"(rA), [vb] "v"(rB)
                : "s40","s41","s42","s43","s44","s45","s46","s47",
                  "s48","s49","s50","s51","s52","s53","s54","s55");
            float at    = dot;
            float vm    = L_vm[tt];
            float denom = at + vm;      // f32 add
            float anew  = at / denom;   // IEEE f32 div
            float aori  = vm / denom;   // IEEE f32 div
            float m0 = anew * o0, n0 = aori * Bk[s].x;
            float m1 = anew * o1, n1 = aori * Bk[s].y;
            float m2 = anew * o2, n2 = aori * Bk[s].z;
            float m3 = anew * o3, n3 = aori * Bk[s].w;
            o0 = m0 + n0; o1 = m1 + n1; o2 = m2 + n2; o3 = m3 + n3;
            float4 w = {o0, o1, o2, o3};
            *(float4*)&outT[((size_t)b * Msz + tt) * Csz + lane * 4] = w;
            if (tt + 4 < Msz) {
                U[s]  = *(const float4*)(ub + (size_t)(tt + 4) * Csz);
                Bk[s] = *(const float4*)(bb + (size_t)(tt + 4) * Csz);
            }
        }
    }
}

// ---------------------------------------------------------------------------
// K4: mask position map
// ---------------------------------------------------------------------------
__global__ void maskpos_init(int* mp) { mp[blockIdx.x * 256 + threadIdx.x] = -1; }
__global__ void maskpos_set(const int* __restrict__ midx, int* mp) {
    int t = blockIdx.x * 256 + threadIdx.x;
    if (t < Msz) mp[midx[t]] = t;
}

// ---------------------------------------------------------------------------
// K5: assemble output [b][c][p]: masked -> scan carry row, known -> gathered col
// ---------------------------------------------------------------------------
#define FSTR 261
__launch_bounds__(256)
__global__ void finalize_kernel(const float* __restrict__ inpT, const float* __restrict__ outT,
                                const int* __restrict__ ind, const int* __restrict__ kidx,
                                const int* __restrict__ mp, float* __restrict__ out) {
    __shared__ float tile[64 * FSTR];
    int b   = blockIdx.x;
    int p0  = blockIdx.y * 64;
    int tid = threadIdx.x;
    int rl  = tid >> 6;          // 0..3
    int cc  = (tid & 63) * 4;    // float4 col offset
    for (int i = 0; i < 16; i++) {
        int r = rl + i * 4;
        int p = p0 + r;
        int m = mp[p];
        const float* src = (m >= 0) ? (outT + ((size_t)b * Msz + m) * Csz)
                                    : (inpT + ((size_t)b * HWsz + kidx[ind[b * HWsz + p]]) * Csz);
        float4 v = *(const float4*)(src + cc);
        tile[r * FSTR + cc + 0] = v.x;
        tile[r * FSTR + cc + 1] = v.y;
        tile[r * FSTR + cc + 2] = v.z;
        tile[r * FSTR + cc + 3] = v.w;
    }
    __syncthreads();
    int pp = tid & 63;
    int c0 = tid >> 6;
    for (int i = 0; i < 64; i++) {
        int c = c0 + i * 4;
        out[((size_t)b * Csz + c) * HWsz + p0 + pp] = tile[pp * FSTR + c];
    }
}

// ---------------------------------------------------------------------------
extern "C" void kernel_launch(void* const* d_in, const int* in_sizes, int n_in,
                              void* d_out, int out_size, void* d_ws, size_t ws_size,
                              hipStream_t stream) {
    const float* inp  = (const float*)d_in[0];
    const float* refm = (const float*)d_in[1];
    const int*   midx = (const int*)d_in[2];
    const int*   kidx = (const int*)d_in[3];
    float* out = (float*)d_out;

    char* ws = (char*)d_ws;
    float* inpT  = (float*)(ws);                  // 16 MB   (ends 16777216)
    float* outT  = (float*)(ws + 16777216);       // 4 MB    (ends 20971520)
    float* knT   = (float*)(ws + 20971520);       // 12 MB   (ends 33554432)
    float* uT    = (float*)(ws + 33554432);       // 4 MB    (ends 37748736)
    float* bkT   = (float*)(ws + 37748736);       // 4 MB    (ends 41943040)
    float* dnorm = (float*)(ws + 41943040);       // 64 KB   (ends 42008576)
    float* vmax  = (float*)(ws + 42008576);       // 64 KB   (ends 42074112)
    int*   ind   = (int*)  (ws + 42074112);       // 64 KB   (ends 42139648)
    int*   mp    = (int*)  (ws + 42139648);       // 16 KB   (ends 42156032)
    float* pvmax = (float*)(ws + 42156032);       // 256 KB  (ends 42418176)
    int*   pind  = (int*)  (ws + 42418176);       // 256 KB  (ends 42680320)

    hipLaunchKernelGGL(transpose_kernel, dim3(HWsz / 32, Csz / 32, BZsz), dim3(32, 8), 0, stream,
                       inp, inpT);
    hipLaunchKernelGGL(maskpos_init, dim3(HWsz / 256), dim3(256), 0, stream, mp);
    hipLaunchKernelGGL(maskpos_set, dim3((Msz + 255) / 256), dim3(256), 0, stream, midx, mp);
    hipLaunchKernelGGL(colnorm_kernel, dim3(HWsz / 256, BZsz), dim3(256), 0, stream, inp, dnorm);
    hipLaunchKernelGGL(knprep_kernel, dim3(Ksz / 4, BZsz), dim3(256), 0, stream,
                       inpT, dnorm, kidx, knT);
    hipLaunchKernelGGL(sim_argmax_kernel, dim3(BZsz, HWsz / 128, KSPL), dim3(256), 0, stream,
                       knT, refm, pvmax, pind);
    hipLaunchKernelGGL(combine_kernel, dim3(HWsz / 256, BZsz), dim3(256), 0, stream,
                       pvmax, pind, vmax, ind);
    hipLaunchKernelGGL(scanprep_kernel, dim3(Msz / 4, BZsz), dim3(256), 0, stream,
                       inpT, dnorm, ind, midx, kidx, uT, bkT);
    hipLaunchKernelGGL(scan_kernel, dim3(BZsz), dim3(64), 0, stream,
                       uT, bkT, vmax, midx, outT);
    hipLaunchKernelGGL(finalize_kernel, dim3(BZsz, HWsz / 64), dim3(256), 0, stream,
                       inpT, outT, ind, kidx, mp, out);
}

// Round 16
// 1123.241 us; speedup vs baseline: 1.2316x; 1.0685x over previous
//
#include <hip/hip_runtime.h>
#include <hip/hip_bf16.h>
#include <math.h>

#define HWsz 4096
#define Csz  256
#define BZsz 4
#define Msz  1024
#define Ksz  3072
#define KSPL 4
#define KPER 768      // Ksz / KSPL
#define NKT  6        // KPER / 128
#define LDP  132      // rf padded row (floats)
#define KLD  140      // kn padded row: 128 + 4-float pad per 32 (bank depad)

typedef float f32x2 __attribute__((ext_vector_type(2)));

// ---------------------------------------------------------------------------
// K0: transpose input [b][c][p] -> inpT [b][p][c]
// ---------------------------------------------------------------------------
__global__ void transpose_kernel(const float* __restrict__ in, float* __restrict__ outT) {
    __shared__ float tile[32][33];
    int b  = blockIdx.z;
    int p0 = blockIdx.x * 32;
    int c0 = blockIdx.y * 32;
    int tx = threadIdx.x;  // 32
    int ty = threadIdx.y;  // 8
#pragma unroll
    for (int i = 0; i < 4; i++) {
        int c = c0 + ty + i * 8;
        tile[ty + i * 8][tx] = in[((size_t)b * Csz + c) * HWsz + p0 + tx];
    }
    __syncthreads();
#pragma unroll
    for (int i = 0; i < 4; i++) {
        int p = p0 + ty + i * 8;
        outT[((size_t)b * HWsz + p) * Csz + c0 + tx] = tile[tx][ty + i * 8];
    }
}

// ---------------------------------------------------------------------------
// K1: norm replica: f32 square (rounded mult), STRICTLY SEQUENTIAL f32 sum
// over c ascending, IEEE f32 sqrt, + 1e-8f.  (unchanged numerics)
// ---------------------------------------------------------------------------
__global__ void colnorm_kernel(const float* __restrict__ inp, float* __restrict__ dnorm) {
#pragma clang fp contract(off)
    int p = blockIdx.x * 256 + threadIdx.x;   // 0..HW-1
    int b = blockIdx.y;
    const float* col = inp + (size_t)b * Csz * HWsz + p;
    float acc = 0.f;
    for (int c = 0; c < Csz; c++) {
        float x  = col[(size_t)c * HWsz];
        float sq = x * x;
        acc = acc + sq;
    }
    dnorm[b * HWsz + p] = sqrtf(acc) + 1e-8f;
}

// ---------------------------------------------------------------------------
// K1b: knT[b][kk][c] = inpT[b][kidx[kk]][c] / dn  (IEEE f32 div, once)
// ---------------------------------------------------------------------------
__global__ void knprep_kernel(const float* __restrict__ inpT, const float* __restrict__ dnorm,
                              const int* __restrict__ kidx, float* __restrict__ knT) {
    int row  = blockIdx.x * 4 + (threadIdx.x >> 6);
    int lane = threadIdx.x & 63;
    int b    = blockIdx.y;
    int kid  = kidx[row];
    float dn = dnorm[b * HWsz + kid];
    const float* src = inpT + ((size_t)b * HWsz + kid) * Csz + lane * 4;
    float4 v = *(const float4*)src;
    float4 w = {v.x / dn, v.y / dn, v.z / dn, v.w / dn};
    *(float4*)(knT + ((size_t)b * Ksz + row) * Csz + lane * 4) = w;
}

// ---------------------------------------------------------------------------
// K2 v4: sim einsum replica with packed-f32 VALU (unchanged from R15).
// ---------------------------------------------------------------------------
#define PK_MUL(dst, s0, s1) asm("v_pk_mul_f32 %0, %1, %2" : "=v"(dst) : "v"(s0), "v"(s1))
#define PK_ADD(dst, s1)     asm("v_pk_add_f32 %0, %0, %1" : "+v"(dst) : "v"(s1))

__launch_bounds__(256, 2)
__global__ void sim_argmax_kernel(const float* __restrict__ knT,
                                  const float* __restrict__ refm,
                                  float* __restrict__ pvmax, int* __restrict__ pind) {
#pragma clang fp contract(off)
    __shared__ float rf[64][LDP];   // [c][p]
    __shared__ float kn[64][KLD];   // [c][kcol]

    int b   = blockIdx.x;
    int p0  = blockIdx.y * 128;
    int ks  = blockIdx.z;
    int k0  = ks * KPER;
    int tid = threadIdx.x;

    int tr = tid >> 4;          // 0..15 -> p = p0 + tr*8 + i
    int tc = tid & 15;          // 0..15 -> k = tile_k0 + tc*8 + j
    int kc = tc * 8 + ((tc >> 2) << 2);   // depadded base col for this k-group

    int rowgrp = tid >> 5;          // 0..7
    int px4    = (tid & 31) * 4;    // float4 col offset
    int skk  = tid >> 1;            // k row (0..127)
    int sc4  = (tid & 1) * 32;      // c offset (0 or 32)
    int kcol = skk + ((skk >> 5) << 2);

    float best[8];
    int   bidx[8];
#pragma unroll
    for (int i = 0; i < 8; i++) { best[i] = -INFINITY; bidx[i] = 0x7fffffff; }

    for (int kt = 0; kt < NKT; kt++) {
        int ktbase = k0 + kt * 128;
        const float* nrow = knT + ((size_t)b * Ksz + ktbase + skk) * Csz;

        f32x2 acc[8][4];
#pragma unroll
        for (int i = 0; i < 8; i++)
#pragma unroll
            for (int jj = 0; jj < 4; jj++) acc[i][jj] = (f32x2){0.f, 0.f};

        for (int cc = 0; cc < 4; cc++) {
            __syncthreads();
#pragma unroll
            for (int i = 0; i < 8; i++) {
                int c = i * 8 + rowgrp;
                float4 v = *(const float4*)&refm[((size_t)b * Csz + cc * 64 + c) * HWsz + p0 + px4];
                *(float4*)&rf[c][px4] = v;
            }
            const float* src = nrow + cc * 64 + sc4;
#pragma unroll
            for (int i = 0; i < 8; i++) {
                float4 v = *(const float4*)(src + i * 4);
                int c = sc4 + i * 4;
                kn[c + 0][kcol] = v.x;
                kn[c + 1][kcol] = v.y;
                kn[c + 2][kcol] = v.z;
                kn[c + 3][kcol] = v.w;
            }
            __syncthreads();

#pragma unroll 2
            for (int c = 0; c < 64; c++) {
                float4 a0 = *(const float4*)&rf[c][tr * 8];
                float4 a1 = *(const float4*)&rf[c][tr * 8 + 4];
                float4 b0 = *(const float4*)&kn[c][kc];
                float4 b1 = *(const float4*)&kn[c][kc + 4];
                float av[8] = {a0.x, a0.y, a0.z, a0.w, a1.x, a1.y, a1.z, a1.w};
                f32x2 B[4] = {{b0.x, b0.y}, {b0.z, b0.w}, {b1.x, b1.y}, {b1.z, b1.w}};
#pragma unroll
                for (int i = 0; i < 8; i++) {
                    f32x2 av2 = {av[i], av[i]};
#pragma unroll
                    for (int jj = 0; jj < 4; jj++) {
                        f32x2 pr;
                        PK_MUL(pr, av2, B[jj]);       // two IEEE f32 muls
                        PK_ADD(acc[i][jj], pr);       // two IEEE f32 adds
                    }
                }
            }
        }
#pragma unroll
        for (int j = 0; j < 8; j++) {
            int k = ktbase + tc * 8 + j;
#pragma unroll
            for (int i = 0; i < 8; i++) {
                float v = (j & 1) ? acc[i][j >> 1].y : acc[i][j >> 1].x;
                if (v > best[i] || (v == best[i] && k < bidx[i])) { best[i] = v; bidx[i] = k; }
            }
        }
    }

    __syncthreads();
    float* sv = &rf[0][0];
    int*   si = (int*)&kn[0][0];
#pragma unroll
    for (int i = 0; i < 8; i++) {
        int p = tr * 8 + i;
        sv[p * 16 + tc] = best[i];
        si[p * 16 + tc] = bidx[i];
    }
    __syncthreads();
    if (tid < 128) {
        float bv = -INFINITY; int bi = 0x7fffffff;
        for (int t = 0; t < 16; t++) {
            float v = sv[tid * 16 + t];
            int   k = si[tid * 16 + t];
            if (v > bv || (v == bv && k < bi)) { bv = v; bi = k; }
        }
        pvmax[((size_t)ks * BZsz + b) * HWsz + p0 + tid] = bv;
        pind [((size_t)ks * BZsz + b) * HWsz + p0 + tid] = bi;
    }
}

// ---------------------------------------------------------------------------
// K2b: combine K-splits (ascending ks => global first-max)
// ---------------------------------------------------------------------------
__global__ void combine_kernel(const float* __restrict__ pvmax, const int* __restrict__ pind,
                               float* __restrict__ vmax, int* __restrict__ ind) {
    int p = blockIdx.x * 256 + threadIdx.x;
    int b = blockIdx.y;
    float bv = -INFINITY; int bi = 0x7fffffff;
    for (int ks = 0; ks < KSPL; ks++) {
        float v = pvmax[((size_t)ks * BZsz + b) * HWsz + p];
        int   k = pind [((size_t)ks * BZsz + b) * HWsz + p];
        if (v > bv || (v == bv && k < bi)) { bv = v; bi = k; }
    }
    vmax[b * HWsz + p] = bv;
    ind [b * HWsz + p] = bi;
}

// ---------------------------------------------------------------------------
// K2c: scanprep: uT[b][t][c] = inpT[b][midx[t]][c] / dn (IEEE f32 div),
// bkT[b][t][c] = inpT[b][kidx[ind[..]]][c] (raw copy).
// ---------------------------------------------------------------------------
__global__ void scanprep_kernel(const float* __restrict__ inpT, const float* __restrict__ dnorm,
                                const int* __restrict__ ind, const int* __restrict__ midx,
                                const int* __restrict__ kidx,
                                float* __restrict__ uT, float* __restrict__ bkT) {
    int t    = blockIdx.x * 4 + (threadIdx.x >> 6);
    int lane = threadIdx.x & 63;
    int b    = blockIdx.y;
    int pp   = midx[t];
    float dn = dnorm[b * HWsz + pp];
    int bkid = kidx[ind[b * HWsz + pp]];
    const float* us = inpT + ((size_t)b * HWsz + pp) * Csz + lane * 4;
    const float* bs = inpT + ((size_t)b * HWsz + bkid) * Csz + lane * 4;
    float4 v = *(const float4*)us;
    float4 w = {v.x / dn, v.y / dn, v.z / dn, v.w / dn};
    *(float4*)(uT  + ((size_t)b * Msz + t) * Csz + lane * 4) = w;
    *(float4*)(bkT + ((size_t)b * Msz + t) * Csz + lane * 4) = *(const float4*)bs;
}

// ---------------------------------------------------------------------------
// K3 v7: serial scan, one wave per image. Numerics IDENTICAL to R7..R15.
// Change: explicit distance-1 rolling double-buffer in NAMED float4 regs
// (Uc/Bc current, Un/Bn next) -> ~36 live VGPRs, compiler keeps them
// resident; next-row load latency hides under the ~1200-cyc chain instead
// of sitting on the critical path (R15's VGPR=28 demotion).
// ---------------------------------------------------------------------------

// CH(q4, next A-slot, next B-slot, cur A-slot, cur B-slot)
#define CH(LQ4, RA_N, RB_N, RA_C, RB_C) \
    "v_readlane_b32 " #RA_N ", %[va], " #LQ4 "\n\t" \
    "v_add_f32 %[dot], " #RA_C ", %[dot]\n\t" \
    "v_readlane_b32 " #RB_N ", %[vb], " #LQ4 "\n\t" \
    "v_add_f32 %[dot], " #RB_C ", %[dot]\n\t"

#define CH_BLOCK8(L0, L1, L2, L3, L4, L5, L6, L7) \
    CH(L0, s44, s52, s40, s48) \
    CH(L1, s45, s53, s41, s49) \
    CH(L2, s46, s54, s42, s50) \
    CH(L3, s47, s55, s43, s51) \
    CH(L4, s40, s48, s44, s52) \
    CH(L5, s41, s49, s45, s53) \
    CH(L6, s42, s50, s46, s54) \
    CH(L7, s43, s51, s47, s55)

__launch_bounds__(64, 1)
__global__ void scan_kernel(const float* __restrict__ uT, const float* __restrict__ bkT,
                            const float* __restrict__ vmax, const int* __restrict__ midx,
                            float* __restrict__ outT) {
#pragma clang fp contract(off)
    __shared__ float L_vm[Msz];
    int b    = blockIdx.x;
    int lane = threadIdx.x;

    for (int t0 = 0; t0 < Msz; t0 += 64) {
        int t = t0 + lane;
        L_vm[t] = vmax[b * HWsz + midx[t]];
    }
    __syncthreads();

    const float* ub = uT  + (size_t)b * Msz * Csz + lane * 4;
    const float* bb = bkT + (size_t)b * Msz * Csz + lane * 4;
    float o0 = 0.f, o1 = 0.f, o2 = 0.f, o3 = 0.f;

    float4 Uc = *(const float4*)ub;
    float4 Bc = *(const float4*)bb;

    for (int t = 0; t < Msz; t++) {
        // issue next-row loads NOW; waitcnt lands after the chain (hidden)
        int tn = (t + 1) & (Msz - 1);          // branchless wrap (row 0 tail reload, unused)
        float4 Un = *(const float4*)(ub + (size_t)tn * Csz);
        float4 Bn = *(const float4*)(bb + (size_t)tn * Csz);

        // sdot strided pair terms: r = fmaf(y0,x0, fl(y1*x1)); 2 pairs/lane
        float pA = Uc.y * o1;
        float rA = __builtin_fmaf(Uc.x, o0, pA);
        float pB = Uc.w * o3;
        float rB = __builtin_fmaf(Uc.z, o2, pB);
        // strictly sequential 128-add chain (order rA(0),rB(0),rA(1),...)
        float dot = 0.f;
        asm volatile(
            "v_readlane_b32 s40, %[va], 0\n\t"
            "v_readlane_b32 s48, %[vb], 0\n\t"
            "v_readlane_b32 s41, %[va], 1\n\t"
            "v_readlane_b32 s49, %[vb], 1\n\t"
            "v_readlane_b32 s42, %[va], 2\n\t"
            "v_readlane_b32 s50, %[vb], 2\n\t"
            "v_readlane_b32 s43, %[va], 3\n\t"
            "v_readlane_b32 s51, %[vb], 3\n\t"
            CH_BLOCK8( 4,  5,  6,  7,  8,  9, 10, 11)
            CH_BLOCK8(12, 13, 14, 15, 16, 17, 18, 19)
            CH_BLOCK8(20, 21, 22, 23, 24, 25, 26, 27)
            CH_BLOCK8(28, 29, 30, 31, 32, 33, 34, 35)
            CH_BLOCK8(36, 37, 38, 39, 40, 41, 42, 43)
            CH_BLOCK8(44, 45, 46, 47, 48, 49, 50, 51)
            CH_BLOCK8(52, 53, 54, 55, 56, 57, 58, 59)
            CH(60, s44, s52, s40, s48)
            CH(61, s45, s53, s41, s49)
            CH(62, s46, s54, s42, s50)
            CH(63, s47, s55, s43, s51)
            "v_add_f32 %[dot], s44, %[dot]\n\t"
            "v_add_f32 %[dot], s52, %[dot]\n\t"
            "v_add_f32 %[dot], s45, %[dot]\n\t"
            "v_add_f32 %[dot], s53, %[dot]\n\t"
            "v_add_f32 %[dot], s46, %[dot]\n\t"
            "v_add_f32 %[dot], s54, %[dot]\n\t"
            "v_add_f32 %[dot], s47, %[dot]\n\t"
            "v_add_f32 %[dot], s55, %[dot]\n\t"
            : [dot] "+v"(dot)
            : [va] "v"(rA), [vb] "v"(rB)
            : "s40","s41","s42","s43","s44","s45","s46","s47",
              "s48","s49","s50","s51","s52","s53","s54","s55");
        float at    = dot;
        float vm    = L_vm[t];
        float denom = at + vm;      // f32 add
        float anew  = at / denom;   // IEEE f32 div
        float aori  = vm / denom;   // IEEE f32 div
        float m0 = anew * o0, n0 = aori * Bc.x;
        float m1 = anew * o1, n1 = aori * Bc.y;
        float m2 = anew * o2, n2 = aori * Bc.z;
        float m3 = anew * o3, n3 = aori * Bc.w;
        o0 = m0 + n0; o1 = m1 + n1; o2 = m2 + n2; o3 = m3 + n3;
        float4 w = {o0, o1, o2, o3};
        *(float4*)&outT[((size_t)b * Msz + t) * Csz + lane * 4] = w;

        Uc = Un; Bc = Bn;   // waitcnt for Un/Bn lands here, post-chain
    }
}

// ---------------------------------------------------------------------------
// K4: mask position map
// ---------------------------------------------------------------------------
__global__ void maskpos_init(int* mp) { mp[blockIdx.x * 256 + threadIdx.x] = -1; }
__global__ void maskpos_set(const int* __restrict__ midx, int* mp) {
    int t = blockIdx.x * 256 + threadIdx.x;
    if (t < Msz) mp[midx[t]] = t;
}

// ---------------------------------------------------------------------------
// K5: assemble output [b][c][p]: masked -> scan carry row, known -> gathered col
// ---------------------------------------------------------------------------
#define FSTR 261
__launch_bounds__(256)
__global__ void finalize_kernel(const float* __restrict__ inpT, const float* __restrict__ outT,
                                const int* __restrict__ ind, const int* __restrict__ kidx,
                                const int* __restrict__ mp, float* __restrict__ out) {
    __shared__ float tile[64 * FSTR];
    int b   = blockIdx.x;
    int p0  = blockIdx.y * 64;
    int tid = threadIdx.x;
    int rl  = tid >> 6;          // 0..3
    int cc  = (tid & 63) * 4;    // float4 col offset
    for (int i = 0; i < 16; i++) {
        int r = rl + i * 4;
        int p = p0 + r;
        int m = mp[p];
        const float* src = (m >= 0) ? (outT + ((size_t)b * Msz + m) * Csz)
                                    : (inpT + ((size_t)b * HWsz + kidx[ind[b * HWsz + p]]) * Csz);
        float4 v = *(const float4*)(src + cc);
        tile[r * FSTR + cc + 0] = v.x;
        tile[r * FSTR + cc + 1] = v.y;
        tile[r * FSTR + cc + 2] = v.z;
        tile[r * FSTR + cc + 3] = v.w;
    }
    __syncthreads();
    int pp = tid & 63;
    int c0 = tid >> 6;
    for (int i = 0; i < 64; i++) {
        int c = c0 + i * 4;
        out[((size_t)b * Csz + c) * HWsz + p0 + pp] = tile[pp * FSTR + c];
    }
}

// ---------------------------------------------------------------------------
extern "C" void kernel_launch(void* const* d_in, const int* in_sizes, int n_in,
                              void* d_out, int out_size, void* d_ws, size_t ws_size,
                              hipStream_t stream) {
    const float* inp  = (const float*)d_in[0];
    const float* refm = (const float*)d_in[1];
    const int*   midx = (const int*)d_in[2];
    const int*   kidx = (const int*)d_in[3];
    float* out = (float*)d_out;

    char* ws = (char*)d_ws;
    float* inpT  = (float*)(ws);                  // 16 MB   (ends 16777216)
    float* outT  = (float*)(ws + 16777216);       // 4 MB    (ends 20971520)
    float* knT   = (float*)(ws + 20971520);       // 12 MB   (ends 33554432)
    float* uT    = (float*)(ws + 33554432);       // 4 MB    (ends 37748736)
    float* bkT   = (float*)(ws + 37748736);       // 4 MB    (ends 41943040)
    float* dnorm = (float*)(ws + 41943040);       // 64 KB   (ends 42008576)
    float* vmax  = (float*)(ws + 42008576);       // 64 KB   (ends 42074112)
    int*   ind   = (int*)  (ws + 42074112);       // 64 KB   (ends 42139648)
    int*   mp    = (int*)  (ws + 42139648);       // 16 KB   (ends 42156032)
    float* pvmax = (float*)(ws + 42156032);       // 256 KB  (ends 42418176)
    int*   pind  = (int*)  (ws + 42418176);       // 256 KB  (ends 42680320)

    hipLaunchKernelGGL(transpose_kernel, dim3(HWsz / 32, Csz / 32, BZsz), dim3(32, 8), 0, stream,
                       inp, inpT);
    hipLaunchKernelGGL(maskpos_init, dim3(HWsz / 256), dim3(256), 0, stream, mp);
    hipLaunchKernelGGL(maskpos_set, dim3((Msz + 255) / 256), dim3(256), 0, stream, midx, mp);
    hipLaunchKernelGGL(colnorm_kernel, dim3(HWsz / 256, BZsz), dim3(256), 0, stream, inp, dnorm);
    hipLaunchKernelGGL(knprep_kernel, dim3(Ksz / 4, BZsz), dim3(256), 0, stream,
                       inpT, dnorm, kidx, knT);
    hipLaunchKernelGGL(sim_argmax_kernel, dim3(BZsz, HWsz / 128, KSPL), dim3(256), 0, stream,
                       knT, refm, pvmax, pind);
    hipLaunchKernelGGL(combine_kernel, dim3(HWsz / 256, BZsz), dim3(256), 0, stream,
                       pvmax, pind, vmax, ind);
    hipLaunchKernelGGL(scanprep_kernel, dim3(Msz / 4, BZsz), dim3(256), 0, stream,
                       inpT, dnorm, ind, midx, kidx, uT, bkT);
    hipLaunchKernelGGL(scan_kernel, dim3(BZsz), dim3(64), 0, stream,
                       uT, bkT, vmax, midx, outT);
    hipLaunchKernelGGL(finalize_kernel, dim3(BZsz, HWsz / 64), dim3(256), 0, stream,
                       inpT, outT, ind, kidx, mp, out);
}

// Round 17
// 1064.242 us; speedup vs baseline: 1.2999x; 1.0554x over previous
//
#include <hip/hip_runtime.h>
#include <hip/hip_bf16.h>
#include <math.h>

#define HWsz 4096
#define Csz  256
#define BZsz 4
#define Msz  1024
#define Ksz  3072
// known-sim (128p tiles): 24 tiles, KSPL=4
#define KSPL 4
#define KPER 768
#define NKT  6
#define LDP  132
#define KLD  140
// masked-sim (64p tiles): 16 tiles, KSPL=8
#define MKSPL 8
#define MKPER 384
#define MNKT  3
#define MLDP  68

typedef float f32x2 __attribute__((ext_vector_type(2)));

#define PK_MUL(dst, s0, s1) asm("v_pk_mul_f32 %0, %1, %2" : "=v"(dst) : "v"(s0), "v"(s1))
#define PK_ADD(dst, s1)     asm("v_pk_add_f32 %0, %0, %1" : "+v"(dst) : "v"(s1))

// ---------------------------------------------------------------------------
// K0: transpose input [b][c][p] -> inpT [b][p][c]
// ---------------------------------------------------------------------------
__global__ void transpose_kernel(const float* __restrict__ in, float* __restrict__ outT) {
    __shared__ float tile[32][33];
    int b  = blockIdx.z;
    int p0 = blockIdx.x * 32;
    int c0 = blockIdx.y * 32;
    int tx = threadIdx.x;
    int ty = threadIdx.y;
#pragma unroll
    for (int i = 0; i < 4; i++) {
        int c = c0 + ty + i * 8;
        tile[ty + i * 8][tx] = in[((size_t)b * Csz + c) * HWsz + p0 + tx];
    }
    __syncthreads();
#pragma unroll
    for (int i = 0; i < 4; i++) {
        int p = p0 + ty + i * 8;
        outT[((size_t)b * HWsz + p) * Csz + c0 + tx] = tile[tx][ty + i * 8];
    }
}

// ---------------------------------------------------------------------------
// K1: norm replica (sequential f32 sum of f32 squares, sqrt, +1e-8f)
// ---------------------------------------------------------------------------
__global__ void colnorm_kernel(const float* __restrict__ inp, float* __restrict__ dnorm) {
#pragma clang fp contract(off)
    int p = blockIdx.x * 256 + threadIdx.x;
    int b = blockIdx.y;
    const float* col = inp + (size_t)b * Csz * HWsz + p;
    float acc = 0.f;
    for (int c = 0; c < Csz; c++) {
        float x  = col[(size_t)c * HWsz];
        float sq = x * x;
        acc = acc + sq;
    }
    dnorm[b * HWsz + p] = sqrtf(acc) + 1e-8f;
}

// ---------------------------------------------------------------------------
// K1b: knT[b][kk][c] = inpT[b][kidx[kk]][c] / dn  (IEEE f32 div, once)
// ---------------------------------------------------------------------------
__global__ void knprep_kernel(const float* __restrict__ inpT, const float* __restrict__ dnorm,
                              const int* __restrict__ kidx, float* __restrict__ knT) {
    int row  = blockIdx.x * 4 + (threadIdx.x >> 6);
    int lane = threadIdx.x & 63;
    int b    = blockIdx.y;
    int kid  = kidx[row];
    float dn = dnorm[b * HWsz + kid];
    const float* src = inpT + ((size_t)b * HWsz + kid) * Csz + lane * 4;
    float4 v = *(const float4*)src;
    float4 w = {v.x / dn, v.y / dn, v.z / dn, v.w / dn};
    *(float4*)(knT + ((size_t)b * Ksz + row) * Csz + lane * 4) = w;
}

// ---------------------------------------------------------------------------
// K2m: masked-pixel sim (64p x K tile, KSPL=8). Numerics identical: per (p,k)
// single f32 accumulator, mul then add (NO fma), c ascending. Pixel gather
// via midx (runs of 32, 4-aligned -> float4 gather valid). Scatter to
// original pixel index. grid (BZ, 16, 8), 512 blocks.
// ---------------------------------------------------------------------------
__launch_bounds__(256, 2)
__global__ void masked_sim_kernel(const float* __restrict__ knT,
                                  const float* __restrict__ refm,
                                  const int* __restrict__ midx,
                                  float* __restrict__ pvmax, int* __restrict__ pind) {
#pragma clang fp contract(off)
    __shared__ float rf[64][MLDP];  // [c][p]
    __shared__ float kn[64][KLD];   // [c][kcol]

    int b   = blockIdx.x;
    int p0  = blockIdx.y * 64;
    int ks  = blockIdx.z;
    int k0  = ks * MKPER;
    int tid = threadIdx.x;

    int tr = tid >> 4;          // 0..15 -> p = tr*4 + i
    int tc = tid & 15;          // 0..15 -> k = tc*8 + j
    int kc = tc * 8 + ((tc >> 2) << 2);

    int skk  = tid >> 1;
    int sc4  = (tid & 1) * 32;
    int kcol = skk + ((skk >> 5) << 2);

    float best[4];
    int   bidx[4];
#pragma unroll
    for (int i = 0; i < 4; i++) { best[i] = -INFINITY; bidx[i] = 0x7fffffff; }

    for (int kt = 0; kt < MNKT; kt++) {
        int ktbase = k0 + kt * 128;
        const float* nrow = knT + ((size_t)b * Ksz + ktbase + skk) * Csz;

        f32x2 acc[4][4];
#pragma unroll
        for (int i = 0; i < 4; i++)
#pragma unroll
            for (int jj = 0; jj < 4; jj++) acc[i][jj] = (f32x2){0.f, 0.f};

        for (int cc = 0; cc < 4; cc++) {
            __syncthreads();
            // rf gather: 4 float4 per thread (midx runs of 32, 4-aligned)
            {
                int pg  = (tid & 15) * 4;
                int pix = midx[p0 + pg];
#pragma unroll
                for (int i = 0; i < 4; i++) {
                    int c = i * 16 + (tid >> 4);
                    float4 v = *(const float4*)&refm[((size_t)b * Csz + cc * 64 + c) * HWsz + pix];
                    *(float4*)&rf[c][pg] = v;
                }
            }
            const float* src = nrow + cc * 64 + sc4;
#pragma unroll
            for (int i = 0; i < 8; i++) {
                float4 v = *(const float4*)(src + i * 4);
                int c = sc4 + i * 4;
                kn[c + 0][kcol] = v.x;
                kn[c + 1][kcol] = v.y;
                kn[c + 2][kcol] = v.z;
                kn[c + 3][kcol] = v.w;
            }
            __syncthreads();

#pragma unroll 2
            for (int c = 0; c < 64; c++) {
                float4 a0 = *(const float4*)&rf[c][tr * 4];
                float4 b0 = *(const float4*)&kn[c][kc];
                float4 b1 = *(const float4*)&kn[c][kc + 4];
                float av[4] = {a0.x, a0.y, a0.z, a0.w};
                f32x2 B[4] = {{b0.x, b0.y}, {b0.z, b0.w}, {b1.x, b1.y}, {b1.z, b1.w}};
#pragma unroll
                for (int i = 0; i < 4; i++) {
                    f32x2 av2 = {av[i], av[i]};
#pragma unroll
                    for (int jj = 0; jj < 4; jj++) {
                        f32x2 pr;
                        PK_MUL(pr, av2, B[jj]);
                        PK_ADD(acc[i][jj], pr);
                    }
                }
            }
        }
#pragma unroll
        for (int j = 0; j < 8; j++) {
            int k = ktbase + tc * 8 + j;
#pragma unroll
            for (int i = 0; i < 4; i++) {
                float v = (j & 1) ? acc[i][j >> 1].y : acc[i][j >> 1].x;
                if (v > best[i] || (v == best[i] && k < bidx[i])) { best[i] = v; bidx[i] = k; }
            }
        }
    }

    __syncthreads();
    float* sv = &rf[0][0];          // 64p x 16tc
    int*   si = (int*)&kn[0][0];
#pragma unroll
    for (int i = 0; i < 4; i++) {
        int p = tr * 4 + i;
        sv[p * 16 + tc] = best[i];
        si[p * 16 + tc] = bidx[i];
    }
    __syncthreads();
    if (tid < 64) {
        float bv = -INFINITY; int bi = 0x7fffffff;
        for (int t = 0; t < 16; t++) {
            float v = sv[tid * 16 + t];
            int   k = si[tid * 16 + t];
            if (v > bv || (v == bv && k < bi)) { bv = v; bi = k; }
        }
        int pix = midx[p0 + tid];
        pvmax[((size_t)ks * BZsz + b) * HWsz + pix] = bv;
        pind [((size_t)ks * BZsz + b) * HWsz + pix] = bi;
    }
}

// ---------------------------------------------------------------------------
// K2bm: combine masked splits (ks 0..7 ascending => global first-max)
// ---------------------------------------------------------------------------
__global__ void masked_combine_kernel(const float* __restrict__ pvmax, const int* __restrict__ pind,
                                      const int* __restrict__ midx,
                                      float* __restrict__ vmax, int* __restrict__ ind) {
    int i = blockIdx.x * 256 + threadIdx.x;   // 0..1023
    int b = blockIdx.y;
    int pix = midx[i];
    float bv = -INFINITY; int bi = 0x7fffffff;
    for (int ks = 0; ks < MKSPL; ks++) {
        float v = pvmax[((size_t)ks * BZsz + b) * HWsz + pix];
        int   k = pind [((size_t)ks * BZsz + b) * HWsz + pix];
        if (v > bv || (v == bv && k < bi)) { bv = v; bi = k; }
    }
    vmax[b * HWsz + pix] = bv;
    ind [b * HWsz + pix] = bi;
}

// ---------------------------------------------------------------------------
// K2b: combine known splits (ks 0..3)
// ---------------------------------------------------------------------------
__global__ void known_combine_kernel(const float* __restrict__ pvmax, const int* __restrict__ pind,
                                     const int* __restrict__ kidx,
                                     float* __restrict__ vmax, int* __restrict__ ind) {
    int i = blockIdx.x * 256 + threadIdx.x;   // 0..3071
    int b = blockIdx.y;
    int pix = kidx[i];
    float bv = -INFINITY; int bi = 0x7fffffff;
    for (int ks = 0; ks < KSPL; ks++) {
        float v = pvmax[((size_t)ks * BZsz + b) * HWsz + pix];
        int   k = pind [((size_t)ks * BZsz + b) * HWsz + pix];
        if (v > bv || (v == bv && k < bi)) { bv = v; bi = k; }
    }
    vmax[b * HWsz + pix] = bv;
    ind [b * HWsz + pix] = bi;
}

// ---------------------------------------------------------------------------
// K2c: scanprep: uT[b][t][c] = inpT[b][midx[t]][c] / dn (IEEE f32 div),
// bkT[b][t][c] = inpT[b][kidx[ind[..]]][c] (raw copy).
// ---------------------------------------------------------------------------
__global__ void scanprep_kernel(const float* __restrict__ inpT, const float* __restrict__ dnorm,
                                const int* __restrict__ ind, const int* __restrict__ midx,
                                const int* __restrict__ kidx,
                                float* __restrict__ uT, float* __restrict__ bkT) {
    int t    = blockIdx.x * 4 + (threadIdx.x >> 6);
    int lane = threadIdx.x & 63;
    int b    = blockIdx.y;
    int pp   = midx[t];
    float dn = dnorm[b * HWsz + pp];
    int bkid = kidx[ind[b * HWsz + pp]];
    const float* us = inpT + ((size_t)b * HWsz + pp) * Csz + lane * 4;
    const float* bs = inpT + ((size_t)b * HWsz + bkid) * Csz + lane * 4;
    float4 v = *(const float4*)us;
    float4 w = {v.x / dn, v.y / dn, v.z / dn, v.w / dn};
    *(float4*)(uT  + ((size_t)b * Msz + t) * Csz + lane * 4) = w;
    *(float4*)(bkT + ((size_t)b * Msz + t) * Csz + lane * 4) = *(const float4*)bs;
}

// ---------------------------------------------------------------------------
// K3h: HETEROGENEOUS kernel: blocks 0..3 = serial scan (R16 code, bit-exact);
// blocks 4..387 = known-pixel sim (128p tiles, gather via kidx).
// Both branches numerics identical to R16 versions.
// ---------------------------------------------------------------------------

#define CH(LQ4, RA_N, RB_N, RA_C, RB_C) \
    "v_readlane_b32 " #RA_N ", %[va], " #LQ4 "\n\t" \
    "v_add_f32 %[dot], " #RA_C ", %[dot]\n\t" \
    "v_readlane_b32 " #RB_N ", %[vb], " #LQ4 "\n\t" \
    "v_add_f32 %[dot], " #RB_C ", %[dot]\n\t"

#define CH_BLOCK8(L0, L1, L2, L3, L4, L5, L6, L7) \
    CH(L0, s44, s52, s40, s48) \
    CH(L1, s45, s53, s41, s49) \
    CH(L2, s46, s54, s42, s50) \
    CH(L3, s47, s55, s43, s51) \
    CH(L4, s40, s48, s44, s52) \
    CH(L5, s41, s49, s45, s53) \
    CH(L6, s42, s50, s46, s54) \
    CH(L7, s43, s51, s47, s55)

__launch_bounds__(256, 2)
__global__ void hetero_kernel(const float* __restrict__ knT, const float* __restrict__ refm,
                              const int* __restrict__ kidx,
                              float* __restrict__ pvmax, int* __restrict__ pind,
                              const float* __restrict__ uT, const float* __restrict__ bkT,
                              const float* __restrict__ vmax, const int* __restrict__ midx,
                              float* __restrict__ outT) {
#pragma clang fp contract(off)
    __shared__ float smem[64 * LDP + 64 * KLD];
    int gid = blockIdx.x;
    int tid = threadIdx.x;

    if (gid < BZsz) {
        // ------------------- scan branch (one wave does the work) ----------
        float* L_vm = smem;
        int b = gid;
        for (int t = tid; t < Msz; t += 256) L_vm[t] = vmax[b * HWsz + midx[t]];
        __syncthreads();
        if (tid >= 64) return;
        int lane = tid;

        const float* ub = uT  + (size_t)b * Msz * Csz + lane * 4;
        const float* bb = bkT + (size_t)b * Msz * Csz + lane * 4;
        float o0 = 0.f, o1 = 0.f, o2 = 0.f, o3 = 0.f;
        float4 Uc = *(const float4*)ub;
        float4 Bc = *(const float4*)bb;

        for (int t = 0; t < Msz; t++) {
            int tn = (t + 1) & (Msz - 1);
            float4 Un = *(const float4*)(ub + (size_t)tn * Csz);
            float4 Bn = *(const float4*)(bb + (size_t)tn * Csz);

            float pA = Uc.y * o1;
            float rA = __builtin_fmaf(Uc.x, o0, pA);
            float pB = Uc.w * o3;
            float rB = __builtin_fmaf(Uc.z, o2, pB);
            float dot = 0.f;
            asm volatile(
                "v_readlane_b32 s40, %[va], 0\n\t"
                "v_readlane_b32 s48, %[vb], 0\n\t"
                "v_readlane_b32 s41, %[va], 1\n\t"
                "v_readlane_b32 s49, %[vb], 1\n\t"
                "v_readlane_b32 s42, %[va], 2\n\t"
                "v_readlane_b32 s50, %[vb], 2\n\t"
                "v_readlane_b32 s43, %[va], 3\n\t"
                "v_readlane_b32 s51, %[vb], 3\n\t"
                CH_BLOCK8( 4,  5,  6,  7,  8,  9, 10, 11)
                CH_BLOCK8(12, 13, 14, 15, 16, 17, 18, 19)
                CH_BLOCK8(20, 21, 22, 23, 24, 25, 26, 27)
                CH_BLOCK8(28, 29, 30, 31, 32, 33, 34, 35)
                CH_BLOCK8(36, 37, 38, 39, 40, 41, 42, 43)
                CH_BLOCK8(44, 45, 46, 47, 48, 49, 50, 51)
                CH_BLOCK8(52, 53, 54, 55, 56, 57, 58, 59)
                CH(60, s44, s52, s40, s48)
                CH(61, s45, s53, s41, s49)
                CH(62, s46, s54, s42, s50)
                CH(63, s47, s55, s43, s51)
                "v_add_f32 %[dot], s44, %[dot]\n\t"
                "v_add_f32 %[dot], s52, %[dot]\n\t"
                "v_add_f32 %[dot], s45, %[dot]\n\t"
                "v_add_f32 %[dot], s53, %[dot]\n\t"
                "v_add_f32 %[dot], s46, %[dot]\n\t"
                "v_add_f32 %[dot], s54, %[dot]\n\t"
                "v_add_f32 %[dot], s47, %[dot]\n\t"
                "v_add_f32 %[dot], s55, %[dot]\n\t"
                : [dot] "+v"(dot)
                : [va] "v"(rA), [vb] "v"(rB)
                : "s40","s41","s42","s43","s44","s45","s46","s47",
                  "s48","s49","s50","s51","s52","s53","s54","s55");
            float at    = dot;
            float vm    = L_vm[t];
            float denom = at + vm;
            float anew  = at / denom;
            float aori  = vm / denom;
            float m0 = anew * o0, n0 = aori * Bc.x;
            float m1 = anew * o1, n1 = aori * Bc.y;
            float m2 = anew * o2, n2 = aori * Bc.z;
            float m3 = anew * o3, n3 = aori * Bc.w;
            o0 = m0 + n0; o1 = m1 + n1; o2 = m2 + n2; o3 = m3 + n3;
            float4 w = {o0, o1, o2, o3};
            *(float4*)&outT[((size_t)b * Msz + t) * Csz + lane * 4] = w;
            Uc = Un; Bc = Bn;
        }
        return;
    }

    // ------------------- known-pixel sim branch ---------------------------
    int g  = gid - BZsz;
    int ks = g & 3;
    int pt = (g >> 2) % 24;
    int b  = g / 96;
    int p0 = pt * 128;
    int k0 = ks * KPER;

    float (*rf)[LDP] = (float(*)[LDP])smem;
    float (*kn)[KLD] = (float(*)[KLD])(smem + 64 * LDP);

    int tr = tid >> 4;
    int tc = tid & 15;
    int kc = tc * 8 + ((tc >> 2) << 2);

    int rowgrp = tid >> 5;
    int px4    = (tid & 31) * 4;
    int skk  = tid >> 1;
    int sc4  = (tid & 1) * 32;
    int kcol = skk + ((skk >> 5) << 2);

    float best[8];
    int   bidx[8];
#pragma unroll
    for (int i = 0; i < 8; i++) { best[i] = -INFINITY; bidx[i] = 0x7fffffff; }

    for (int kt = 0; kt < NKT; kt++) {
        int ktbase = k0 + kt * 128;
        const float* nrow = knT + ((size_t)b * Ksz + ktbase + skk) * Csz;

        f32x2 acc[8][4];
#pragma unroll
        for (int i = 0; i < 8; i++)
#pragma unroll
            for (int jj = 0; jj < 4; jj++) acc[i][jj] = (f32x2){0.f, 0.f};

        for (int cc = 0; cc < 4; cc++) {
            __syncthreads();
            {
                int pix = kidx[p0 + px4];   // runs >=16, 4-aligned -> float4 ok
#pragma unroll
                for (int i = 0; i < 8; i++) {
                    int c = i * 8 + rowgrp;
                    float4 v = *(const float4*)&refm[((size_t)b * Csz + cc * 64 + c) * HWsz + pix];
                    *(float4*)&rf[c][px4] = v;
                }
            }
            const float* src = nrow + cc * 64 + sc4;
#pragma unroll
            for (int i = 0; i < 8; i++) {
                float4 v = *(const float4*)(src + i * 4);
                int c = sc4 + i * 4;
                kn[c + 0][kcol] = v.x;
                kn[c + 1][kcol] = v.y;
                kn[c + 2][kcol] = v.z;
                kn[c + 3][kcol] = v.w;
            }
            __syncthreads();

#pragma unroll 2
            for (int c = 0; c < 64; c++) {
                float4 a0 = *(const float4*)&rf[c][tr * 8];
                float4 a1 = *(const float4*)&rf[c][tr * 8 + 4];
                float4 b0 = *(const float4*)&kn[c][kc];
                float4 b1 = *(const float4*)&kn[c][kc + 4];
                float av[8] = {a0.x, a0.y, a0.z, a0.w, a1.x, a1.y, a1.z, a1.w};
                f32x2 B[4] = {{b0.x, b0.y}, {b0.z, b0.w}, {b1.x, b1.y}, {b1.z, b1.w}};
#pragma unroll
                for (int i = 0; i < 8; i++) {
                    f32x2 av2 = {av[i], av[i]};
#pragma unroll
                    for (int jj = 0; jj < 4; jj++) {
                        f32x2 pr;
                        PK_MUL(pr, av2, B[jj]);
                        PK_ADD(acc[i][jj], pr);
                    }
                }
            }
        }
#pragma unroll
        for (int j = 0; j < 8; j++) {
            int k = ktbase + tc * 8 + j;
#pragma unroll
            for (int i = 0; i < 8; i++) {
                float v = (j & 1) ? acc[i][j >> 1].y : acc[i][j >> 1].x;
                if (v > best[i] || (v == best[i] && k < bidx[i])) { best[i] = v; bidx[i] = k; }
            }
        }
    }

    __syncthreads();
    float* sv = &rf[0][0];
    int*   si = (int*)&kn[0][0];
#pragma unroll
    for (int i = 0; i < 8; i++) {
        int p = tr * 8 + i;
        sv[p * 16 + tc] = best[i];
        si[p * 16 + tc] = bidx[i];
    }
    __syncthreads();
    if (tid < 128) {
        float bv = -INFINITY; int bi = 0x7fffffff;
        for (int t = 0; t < 16; t++) {
            float v = sv[tid * 16 + t];
            int   k = si[tid * 16 + t];
            if (v > bv || (v == bv && k < bi)) { bv = v; bi = k; }
        }
        int pix = kidx[p0 + tid];
        pvmax[((size_t)ks * BZsz + b) * HWsz + pix] = bv;
        pind [((size_t)ks * BZsz + b) * HWsz + pix] = bi;
    }
}

// ---------------------------------------------------------------------------
// K4: mask position map
// ---------------------------------------------------------------------------
__global__ void maskpos_init(int* mp) { mp[blockIdx.x * 256 + threadIdx.x] = -1; }
__global__ void maskpos_set(const int* __restrict__ midx, int* mp) {
    int t = blockIdx.x * 256 + threadIdx.x;
    if (t < Msz) mp[midx[t]] = t;
}

// ---------------------------------------------------------------------------
// K5: assemble output [b][c][p]
// ---------------------------------------------------------------------------
#define FSTR 261
__launch_bounds__(256)
__global__ void finalize_kernel(const float* __restrict__ inpT, const float* __restrict__ outT,
                                const int* __restrict__ ind, const int* __restrict__ kidx,
                                const int* __restrict__ mp, float* __restrict__ out) {
    __shared__ float tile[64 * FSTR];
    int b   = blockIdx.x;
    int p0  = blockIdx.y * 64;
    int tid = threadIdx.x;
    int rl  = tid >> 6;
    int cc  = (tid & 63) * 4;
    for (int i = 0; i < 16; i++) {
        int r = rl + i * 4;
        int p = p0 + r;
        int m = mp[p];
        const float* src = (m >= 0) ? (outT + ((size_t)b * Msz + m) * Csz)
                                    : (inpT + ((size_t)b * HWsz + kidx[ind[b * HWsz + p]]) * Csz);
        float4 v = *(const float4*)(src + cc);
        tile[r * FSTR + cc + 0] = v.x;
        tile[r * FSTR + cc + 1] = v.y;
        tile[r * FSTR + cc + 2] = v.z;
        tile[r * FSTR + cc + 3] = v.w;
    }
    __syncthreads();
    int pp = tid & 63;
    int c0 = tid >> 6;
    for (int i = 0; i < 64; i++) {
        int c = c0 + i * 4;
        out[((size_t)b * Csz + c) * HWsz + p0 + pp] = tile[pp * FSTR + c];
    }
}

// ---------------------------------------------------------------------------
extern "C" void kernel_launch(void* const* d_in, const int* in_sizes, int n_in,
                              void* d_out, int out_size, void* d_ws, size_t ws_size,
                              hipStream_t stream) {
    const float* inp  = (const float*)d_in[0];
    const float* refm = (const float*)d_in[1];
    const int*   midx = (const int*)d_in[2];
    const int*   kidx = (const int*)d_in[3];
    float* out = (float*)d_out;

    char* ws = (char*)d_ws;
    float* inpT  = (float*)(ws);                  // 16 MB   (ends 16777216)
    float* outT  = (float*)(ws + 16777216);       // 4 MB    (ends 20971520)
    float* knT   = (float*)(ws + 20971520);       // 12 MB   (ends 33554432)
    float* uT    = (float*)(ws + 33554432);       // 4 MB    (ends 37748736)
    float* bkT   = (float*)(ws + 37748736);       // 4 MB    (ends 41943040)
    float* dnorm = (float*)(ws + 41943040);       // 64 KB   (ends 42008576)
    float* vmax  = (float*)(ws + 42008576);       // 64 KB   (ends 42074112)
    int*   ind   = (int*)  (ws + 42074112);       // 64 KB   (ends 42139648)
    int*   mp    = (int*)  (ws + 42139648);       // 16 KB   (ends 42156032)
    float* pvmax = (float*)(ws + 42156032);       // 8*BZ*HW = 512 KB (ends 42680320)
    int*   pind  = (int*)  (ws + 42680320);       // 512 KB  (ends 43204608)

    hipLaunchKernelGGL(transpose_kernel, dim3(HWsz / 32, Csz / 32, BZsz), dim3(32, 8), 0, stream,
                       inp, inpT);
    hipLaunchKernelGGL(maskpos_init, dim3(HWsz / 256), dim3(256), 0, stream, mp);
    hipLaunchKernelGGL(maskpos_set, dim3((Msz + 255) / 256), dim3(256), 0, stream, midx, mp);
    hipLaunchKernelGGL(colnorm_kernel, dim3(HWsz / 256, BZsz), dim3(256), 0, stream, inp, dnorm);
    hipLaunchKernelGGL(knprep_kernel, dim3(Ksz / 4, BZsz), dim3(256), 0, stream,
                       inpT, dnorm, kidx, knT);
    hipLaunchKernelGGL(masked_sim_kernel, dim3(BZsz, 16, MKSPL), dim3(256), 0, stream,
                       knT, refm, midx, pvmax, pind);
    hipLaunchKernelGGL(masked_combine_kernel, dim3(4, BZsz), dim3(256), 0, stream,
                       pvmax, pind, midx, vmax, ind);
    hipLaunchKernelGGL(scanprep_kernel, dim3(Msz / 4, BZsz), dim3(256), 0, stream,
                       inpT, dnorm, ind, midx, kidx, uT, bkT);
    hipLaunchKernelGGL(hetero_kernel, dim3(BZsz + BZsz * 24 * KSPL), dim3(256), 0, stream,
                       knT, refm, kidx, pvmax, pind, uT, bkT, vmax, midx, outT);
    hipLaunchKernelGGL(known_combine_kernel, dim3(Ksz / 256, BZsz), dim3(256), 0, stream,
                       pvmax, pind, kidx, vmax, ind);
    hipLaunchKernelGGL(finalize_kernel, dim3(BZsz, HWsz / 64), dim3(256), 0, stream,
                       inpT, outT, ind, kidx, mp, out);
}

// Round 18
// 1063.957 us; speedup vs baseline: 1.3002x; 1.0003x over previous
//
#include <hip/hip_runtime.h>
#include <hip/hip_bf16.h>
#include <math.h>

#define HWsz 4096
#define Csz  256
#define BZsz 4
#define Msz  1024
#define Ksz  3072
// known-sim (128p tiles): 24 tiles, KSPL=4
#define KSPL 4
#define KPER 768
#define NKT  6
#define LDP  132
#define KLD  140
// masked-sim (64p tiles): 16 tiles, KSPL=8
#define MKSPL 8
#define MKPER 384
#define MNKT  3
#define MLDP  68

typedef float f32x2 __attribute__((ext_vector_type(2)));

#define PK_MUL(dst, s0, s1) asm("v_pk_mul_f32 %0, %1, %2" : "=v"(dst) : "v"(s0), "v"(s1))
#define PK_ADD(dst, s1)     asm("v_pk_add_f32 %0, %0, %1" : "+v"(dst) : "v"(s1))

// ---------------------------------------------------------------------------
// K0: transpose input [b][c][p] -> inpT [b][p][c]
// ---------------------------------------------------------------------------
__global__ void transpose_kernel(const float* __restrict__ in, float* __restrict__ outT) {
    __shared__ float tile[32][33];
    int b  = blockIdx.z;
    int p0 = blockIdx.x * 32;
    int c0 = blockIdx.y * 32;
    int tx = threadIdx.x;
    int ty = threadIdx.y;
#pragma unroll
    for (int i = 0; i < 4; i++) {
        int c = c0 + ty + i * 8;
        tile[ty + i * 8][tx] = in[((size_t)b * Csz + c) * HWsz + p0 + tx];
    }
    __syncthreads();
#pragma unroll
    for (int i = 0; i < 4; i++) {
        int p = p0 + ty + i * 8;
        outT[((size_t)b * HWsz + p) * Csz + c0 + tx] = tile[tx][ty + i * 8];
    }
}

// ---------------------------------------------------------------------------
// K1: norm replica (sequential f32 sum of f32 squares, sqrt, +1e-8f)
// ---------------------------------------------------------------------------
__global__ void colnorm_kernel(const float* __restrict__ inp, float* __restrict__ dnorm) {
#pragma clang fp contract(off)
    int p = blockIdx.x * 256 + threadIdx.x;
    int b = blockIdx.y;
    const float* col = inp + (size_t)b * Csz * HWsz + p;
    float acc = 0.f;
    for (int c = 0; c < Csz; c++) {
        float x  = col[(size_t)c * HWsz];
        float sq = x * x;
        acc = acc + sq;
    }
    dnorm[b * HWsz + p] = sqrtf(acc) + 1e-8f;
}

// ---------------------------------------------------------------------------
// K1b: knT[b][kk][c] = inpT[b][kidx[kk]][c] / dn  (IEEE f32 div, once)
// ---------------------------------------------------------------------------
__global__ void knprep_kernel(const float* __restrict__ inpT, const float* __restrict__ dnorm,
                              const int* __restrict__ kidx, float* __restrict__ knT) {
    int row  = blockIdx.x * 4 + (threadIdx.x >> 6);
    int lane = threadIdx.x & 63;
    int b    = blockIdx.y;
    int kid  = kidx[row];
    float dn = dnorm[b * HWsz + kid];
    const float* src = inpT + ((size_t)b * HWsz + kid) * Csz + lane * 4;
    float4 v = *(const float4*)src;
    float4 w = {v.x / dn, v.y / dn, v.z / dn, v.w / dn};
    *(float4*)(knT + ((size_t)b * Ksz + row) * Csz + lane * 4) = w;
}

// ---------------------------------------------------------------------------
// K2m: masked-pixel sim (64p x K tile, KSPL=8). Numerics identical.
// ---------------------------------------------------------------------------
__launch_bounds__(256, 2)
__global__ void masked_sim_kernel(const float* __restrict__ knT,
                                  const float* __restrict__ refm,
                                  const int* __restrict__ midx,
                                  float* __restrict__ pvmax, int* __restrict__ pind) {
#pragma clang fp contract(off)
    __shared__ float rf[64][MLDP];  // [c][p]
    __shared__ float kn[64][KLD];   // [c][kcol]

    int b   = blockIdx.x;
    int p0  = blockIdx.y * 64;
    int ks  = blockIdx.z;
    int k0  = ks * MKPER;
    int tid = threadIdx.x;

    int tr = tid >> 4;
    int tc = tid & 15;
    int kc = tc * 8 + ((tc >> 2) << 2);

    int skk  = tid >> 1;
    int sc4  = (tid & 1) * 32;
    int kcol = skk + ((skk >> 5) << 2);

    float best[4];
    int   bidx[4];
#pragma unroll
    for (int i = 0; i < 4; i++) { best[i] = -INFINITY; bidx[i] = 0x7fffffff; }

    for (int kt = 0; kt < MNKT; kt++) {
        int ktbase = k0 + kt * 128;
        const float* nrow = knT + ((size_t)b * Ksz + ktbase + skk) * Csz;

        f32x2 acc[4][4];
#pragma unroll
        for (int i = 0; i < 4; i++)
#pragma unroll
            for (int jj = 0; jj < 4; jj++) acc[i][jj] = (f32x2){0.f, 0.f};

        for (int cc = 0; cc < 4; cc++) {
            __syncthreads();
            {
                int pg  = (tid & 15) * 4;
                int pix = midx[p0 + pg];
#pragma unroll
                for (int i = 0; i < 4; i++) {
                    int c = i * 16 + (tid >> 4);
                    float4 v = *(const float4*)&refm[((size_t)b * Csz + cc * 64 + c) * HWsz + pix];
                    *(float4*)&rf[c][pg] = v;
                }
            }
            const float* src = nrow + cc * 64 + sc4;
#pragma unroll
            for (int i = 0; i < 8; i++) {
                float4 v = *(const float4*)(src + i * 4);
                int c = sc4 + i * 4;
                kn[c + 0][kcol] = v.x;
                kn[c + 1][kcol] = v.y;
                kn[c + 2][kcol] = v.z;
                kn[c + 3][kcol] = v.w;
            }
            __syncthreads();

#pragma unroll 2
            for (int c = 0; c < 64; c++) {
                float4 a0 = *(const float4*)&rf[c][tr * 4];
                float4 b0 = *(const float4*)&kn[c][kc];
                float4 b1 = *(const float4*)&kn[c][kc + 4];
                float av[4] = {a0.x, a0.y, a0.z, a0.w};
                f32x2 B[4] = {{b0.x, b0.y}, {b0.z, b0.w}, {b1.x, b1.y}, {b1.z, b1.w}};
#pragma unroll
                for (int i = 0; i < 4; i++) {
                    f32x2 av2 = {av[i], av[i]};
#pragma unroll
                    for (int jj = 0; jj < 4; jj++) {
                        f32x2 pr;
                        PK_MUL(pr, av2, B[jj]);
                        PK_ADD(acc[i][jj], pr);
                    }
                }
            }
        }
#pragma unroll
        for (int j = 0; j < 8; j++) {
            int k = ktbase + tc * 8 + j;
#pragma unroll
            for (int i = 0; i < 4; i++) {
                float v = (j & 1) ? acc[i][j >> 1].y : acc[i][j >> 1].x;
                if (v > best[i] || (v == best[i] && k < bidx[i])) { best[i] = v; bidx[i] = k; }
            }
        }
    }

    __syncthreads();
    float* sv = &rf[0][0];
    int*   si = (int*)&kn[0][0];
#pragma unroll
    for (int i = 0; i < 4; i++) {
        int p = tr * 4 + i;
        sv[p * 16 + tc] = best[i];
        si[p * 16 + tc] = bidx[i];
    }
    __syncthreads();
    if (tid < 64) {
        float bv = -INFINITY; int bi = 0x7fffffff;
        for (int t = 0; t < 16; t++) {
            float v = sv[tid * 16 + t];
            int   k = si[tid * 16 + t];
            if (v > bv || (v == bv && k < bi)) { bv = v; bi = k; }
        }
        int pix = midx[p0 + tid];
        pvmax[((size_t)ks * BZsz + b) * HWsz + pix] = bv;
        pind [((size_t)ks * BZsz + b) * HWsz + pix] = bi;
    }
}

// ---------------------------------------------------------------------------
// K2bm: combine masked splits (ks 0..7 ascending => global first-max)
// ---------------------------------------------------------------------------
__global__ void masked_combine_kernel(const float* __restrict__ pvmax, const int* __restrict__ pind,
                                      const int* __restrict__ midx,
                                      float* __restrict__ vmax, int* __restrict__ ind) {
    int i = blockIdx.x * 256 + threadIdx.x;   // 0..1023
    int b = blockIdx.y;
    int pix = midx[i];
    float bv = -INFINITY; int bi = 0x7fffffff;
    for (int ks = 0; ks < MKSPL; ks++) {
        float v = pvmax[((size_t)ks * BZsz + b) * HWsz + pix];
        int   k = pind [((size_t)ks * BZsz + b) * HWsz + pix];
        if (v > bv || (v == bv && k < bi)) { bv = v; bi = k; }
    }
    vmax[b * HWsz + pix] = bv;
    ind [b * HWsz + pix] = bi;
}

// ---------------------------------------------------------------------------
// K2b: combine known splits (ks 0..3)
// ---------------------------------------------------------------------------
__global__ void known_combine_kernel(const float* __restrict__ pvmax, const int* __restrict__ pind,
                                     const int* __restrict__ kidx,
                                     float* __restrict__ vmax, int* __restrict__ ind) {
    int i = blockIdx.x * 256 + threadIdx.x;   // 0..3071
    int b = blockIdx.y;
    int pix = kidx[i];
    float bv = -INFINITY; int bi = 0x7fffffff;
    for (int ks = 0; ks < KSPL; ks++) {
        float v = pvmax[((size_t)ks * BZsz + b) * HWsz + pix];
        int   k = pind [((size_t)ks * BZsz + b) * HWsz + pix];
        if (v > bv || (v == bv && k < bi)) { bv = v; bi = k; }
    }
    vmax[b * HWsz + pix] = bv;
    ind [b * HWsz + pix] = bi;
}

// ---------------------------------------------------------------------------
// K2c: scanprep
// ---------------------------------------------------------------------------
__global__ void scanprep_kernel(const float* __restrict__ inpT, const float* __restrict__ dnorm,
                                const int* __restrict__ ind, const int* __restrict__ midx,
                                const int* __restrict__ kidx,
                                float* __restrict__ uT, float* __restrict__ bkT) {
    int t    = blockIdx.x * 4 + (threadIdx.x >> 6);
    int lane = threadIdx.x & 63;
    int b    = blockIdx.y;
    int pp   = midx[t];
    float dn = dnorm[b * HWsz + pp];
    int bkid = kidx[ind[b * HWsz + pp]];
    const float* us = inpT + ((size_t)b * HWsz + pp) * Csz + lane * 4;
    const float* bs = inpT + ((size_t)b * HWsz + bkid) * Csz + lane * 4;
    float4 v = *(const float4*)us;
    float4 w = {v.x / dn, v.y / dn, v.z / dn, v.w / dn};
    *(float4*)(uT  + ((size_t)b * Msz + t) * Csz + lane * 4) = w;
    *(float4*)(bkT + ((size_t)b * Msz + t) * Csz + lane * 4) = *(const float4*)bs;
}

// ---------------------------------------------------------------------------
// K3h: HETEROGENEOUS kernel: blocks 0..3 = serial scan at WAVE PRIORITY 3
// (T5: scan is dependency-bound, <=25% of SIMD issue BW; priority removes
// round-robin arbitration stalls vs co-resident sim waves). blocks 4..387 =
// known-pixel sim at default priority. Numerics identical to R17.
// ---------------------------------------------------------------------------

#define CH(LQ4, RA_N, RB_N, RA_C, RB_C) \
    "v_readlane_b32 " #RA_N ", %[va], " #LQ4 "\n\t" \
    "v_add_f32 %[dot], " #RA_C ", %[dot]\n\t" \
    "v_readlane_b32 " #RB_N ", %[vb], " #LQ4 "\n\t" \
    "v_add_f32 %[dot], " #RB_C ", %[dot]\n\t"

#define CH_BLOCK8(L0, L1, L2, L3, L4, L5, L6, L7) \
    CH(L0, s44, s52, s40, s48) \
    CH(L1, s45, s53, s41, s49) \
    CH(L2, s46, s54, s42, s50) \
    CH(L3, s47, s55, s43, s51) \
    CH(L4, s40, s48, s44, s52) \
    CH(L5, s41, s49, s45, s53) \
    CH(L6, s42, s50, s46, s54) \
    CH(L7, s43, s51, s47, s55)

__launch_bounds__(256, 2)
__global__ void hetero_kernel(const float* __restrict__ knT, const float* __restrict__ refm,
                              const int* __restrict__ kidx,
                              float* __restrict__ pvmax, int* __restrict__ pind,
                              const float* __restrict__ uT, const float* __restrict__ bkT,
                              const float* __restrict__ vmax, const int* __restrict__ midx,
                              float* __restrict__ outT) {
#pragma clang fp contract(off)
    __shared__ float smem[64 * LDP + 64 * KLD];
    int gid = blockIdx.x;
    int tid = threadIdx.x;

    if (gid < BZsz) {
        // ------------------- scan branch (one wave, priority 3) ------------
        float* L_vm = smem;
        int b = gid;
        for (int t = tid; t < Msz; t += 256) L_vm[t] = vmax[b * HWsz + midx[t]];
        __syncthreads();
        if (tid >= 64) return;
        __builtin_amdgcn_s_setprio(3);
        int lane = tid;

        const float* ub = uT  + (size_t)b * Msz * Csz + lane * 4;
        const float* bb = bkT + (size_t)b * Msz * Csz + lane * 4;
        float o0 = 0.f, o1 = 0.f, o2 = 0.f, o3 = 0.f;
        float4 Uc = *(const float4*)ub;
        float4 Bc = *(const float4*)bb;

        for (int t = 0; t < Msz; t++) {
            int tn = (t + 1) & (Msz - 1);
            float4 Un = *(const float4*)(ub + (size_t)tn * Csz);
            float4 Bn = *(const float4*)(bb + (size_t)tn * Csz);

            float pA = Uc.y * o1;
            float rA = __builtin_fmaf(Uc.x, o0, pA);
            float pB = Uc.w * o3;
            float rB = __builtin_fmaf(Uc.z, o2, pB);
            float dot = 0.f;
            asm volatile(
                "v_readlane_b32 s40, %[va], 0\n\t"
                "v_readlane_b32 s48, %[vb], 0\n\t"
                "v_readlane_b32 s41, %[va], 1\n\t"
                "v_readlane_b32 s49, %[vb], 1\n\t"
                "v_readlane_b32 s42, %[va], 2\n\t"
                "v_readlane_b32 s50, %[vb], 2\n\t"
                "v_readlane_b32 s43, %[va], 3\n\t"
                "v_readlane_b32 s51, %[vb], 3\n\t"
                CH_BLOCK8( 4,  5,  6,  7,  8,  9, 10, 11)
                CH_BLOCK8(12, 13, 14, 15, 16, 17, 18, 19)
                CH_BLOCK8(20, 21, 22, 23, 24, 25, 26, 27)
                CH_BLOCK8(28, 29, 30, 31, 32, 33, 34, 35)
                CH_BLOCK8(36, 37, 38, 39, 40, 41, 42, 43)
                CH_BLOCK8(44, 45, 46, 47, 48, 49, 50, 51)
                CH_BLOCK8(52, 53, 54, 55, 56, 57, 58, 59)
                CH(60, s44, s52, s40, s48)
                CH(61, s45, s53, s41, s49)
                CH(62, s46, s54, s42, s50)
                CH(63, s47, s55, s43, s51)
                "v_add_f32 %[dot], s44, %[dot]\n\t"
                "v_add_f32 %[dot], s52, %[dot]\n\t"
                "v_add_f32 %[dot], s45, %[dot]\n\t"
                "v_add_f32 %[dot], s53, %[dot]\n\t"
                "v_add_f32 %[dot], s46, %[dot]\n\t"
                "v_add_f32 %[dot], s54, %[dot]\n\t"
                "v_add_f32 %[dot], s47, %[dot]\n\t"
                "v_add_f32 %[dot], s55, %[dot]\n\t"
                : [dot] "+v"(dot)
                : [va] "v"(rA), [vb] "v"(rB)
                : "s40","s41","s42","s43","s44","s45","s46","s47",
                  "s48","s49","s50","s51","s52","s53","s54","s55");
            float at    = dot;
            float vm    = L_vm[t];
            float denom = at + vm;
            float anew  = at / denom;
            float aori  = vm / denom;
            float m0 = anew * o0, n0 = aori * Bc.x;
            float m1 = anew * o1, n1 = aori * Bc.y;
            float m2 = anew * o2, n2 = aori * Bc.z;
            float m3 = anew * o3, n3 = aori * Bc.w;
            o0 = m0 + n0; o1 = m1 + n1; o2 = m2 + n2; o3 = m3 + n3;
            float4 w = {o0, o1, o2, o3};
            *(float4*)&outT[((size_t)b * Msz + t) * Csz + lane * 4] = w;
            Uc = Un; Bc = Bn;
        }
        return;
    }

    // ------------------- known-pixel sim branch ---------------------------
    int g  = gid - BZsz;
    int ks = g & 3;
    int pt = (g >> 2) % 24;
    int b  = g / 96;
    int p0 = pt * 128;
    int k0 = ks * KPER;

    float (*rf)[LDP] = (float(*)[LDP])smem;
    float (*kn)[KLD] = (float(*)[KLD])(smem + 64 * LDP);

    int tr = tid >> 4;
    int tc = tid & 15;
    int kc = tc * 8 + ((tc >> 2) << 2);

    int rowgrp = tid >> 5;
    int px4    = (tid & 31) * 4;
    int skk  = tid >> 1;
    int sc4  = (tid & 1) * 32;
    int kcol = skk + ((skk >> 5) << 2);

    float best[8];
    int   bidx[8];
#pragma unroll
    for (int i = 0; i < 8; i++) { best[i] = -INFINITY; bidx[i] = 0x7fffffff; }

    for (int kt = 0; kt < NKT; kt++) {
        int ktbase = k0 + kt * 128;
        const float* nrow = knT + ((size_t)b * Ksz + ktbase + skk) * Csz;

        f32x2 acc[8][4];
#pragma unroll
        for (int i = 0; i < 8; i++)
#pragma unroll
            for (int jj = 0; jj < 4; jj++) acc[i][jj] = (f32x2){0.f, 0.f};

        for (int cc = 0; cc < 4; cc++) {
            __syncthreads();
            {
                int pix = kidx[p0 + px4];
#pragma unroll
                for (int i = 0; i < 8; i++) {
                    int c = i * 8 + rowgrp;
                    float4 v = *(const float4*)&refm[((size_t)b * Csz + cc * 64 + c) * HWsz + pix];
                    *(float4*)&rf[c][px4] = v;
                }
            }
            const float* src = nrow + cc * 64 + sc4;
#pragma unroll
            for (int i = 0; i < 8; i++) {
                float4 v = *(const float4*)(src + i * 4);
                int c = sc4 + i * 4;
                kn[c + 0][kcol] = v.x;
                kn[c + 1][kcol] = v.y;
                kn[c + 2][kcol] = v.z;
                kn[c + 3][kcol] = v.w;
            }
            __syncthreads();

#pragma unroll 2
            for (int c = 0; c < 64; c++) {
                float4 a0 = *(const float4*)&rf[c][tr * 8];
                float4 a1 = *(const float4*)&rf[c][tr * 8 + 4];
                float4 b0 = *(const float4*)&kn[c][kc];
                float4 b1 = *(const float4*)&kn[c][kc + 4];
                float av[8] = {a0.x, a0.y, a0.z, a0.w, a1.x, a1.y, a1.z, a1.w};
                f32x2 B[4] = {{b0.x, b0.y}, {b0.z, b0.w}, {b1.x, b1.y}, {b1.z, b1.w}};
#pragma unroll
                for (int i = 0; i < 8; i++) {
                    f32x2 av2 = {av[i], av[i]};
#pragma unroll
                    for (int jj = 0; jj < 4; jj++) {
                        f32x2 pr;
                        PK_MUL(pr, av2, B[jj]);
                        PK_ADD(acc[i][jj], pr);
                    }
                }
            }
        }
#pragma unroll
        for (int j = 0; j < 8; j++) {
            int k = ktbase + tc * 8 + j;
#pragma unroll
            for (int i = 0; i < 8; i++) {
                float v = (j & 1) ? acc[i][j >> 1].y : acc[i][j >> 1].x;
                if (v > best[i] || (v == best[i] && k < bidx[i])) { best[i] = v; bidx[i] = k; }
            }
        }
    }

    __syncthreads();
    float* sv = &rf[0][0];
    int*   si = (int*)&kn[0][0];
#pragma unroll
    for (int i = 0; i < 8; i++) {
        int p = tr * 8 + i;
        sv[p * 16 + tc] = best[i];
        si[p * 16 + tc] = bidx[i];
    }
    __syncthreads();
    if (tid < 128) {
        float bv = -INFINITY; int bi = 0x7fffffff;
        for (int t = 0; t < 16; t++) {
            float v = sv[tid * 16 + t];
            int   k = si[tid * 16 + t];
            if (v > bv || (v == bv && k < bi)) { bv = v; bi = k; }
        }
        int pix = kidx[p0 + tid];
        pvmax[((size_t)ks * BZsz + b) * HWsz + pix] = bv;
        pind [((size_t)ks * BZsz + b) * HWsz + pix] = bi;
    }
}

// ---------------------------------------------------------------------------
// K4: mask position map
// ---------------------------------------------------------------------------
__global__ void maskpos_init(int* mp) { mp[blockIdx.x * 256 + threadIdx.x] = -1; }
__global__ void maskpos_set(const int* __restrict__ midx, int* mp) {
    int t = blockIdx.x * 256 + threadIdx.x;
    if (t < Msz) mp[midx[t]] = t;
}

// ---------------------------------------------------------------------------
// K5: assemble output [b][c][p]
// ---------------------------------------------------------------------------
#define FSTR 261
__launch_bounds__(256)
__global__ void finalize_kernel(const float* __restrict__ inpT, const float* __restrict__ outT,
                                const int* __restrict__ ind, const int* __restrict__ kidx,
                                const int* __restrict__ mp, float* __restrict__ out) {
    __shared__ float tile[64 * FSTR];
    int b   = blockIdx.x;
    int p0  = blockIdx.y * 64;
    int tid = threadIdx.x;
    int rl  = tid >> 6;
    int cc  = (tid & 63) * 4;
    for (int i = 0; i < 16; i++) {
        int r = rl + i * 4;
        int p = p0 + r;
        int m = mp[p];
        const float* src = (m >= 0) ? (outT + ((size_t)b * Msz + m) * Csz)
                                    : (inpT + ((size_t)b * HWsz + kidx[ind[b * HWsz + p]]) * Csz);
        float4 v = *(const float4*)(src + cc);
        tile[r * FSTR + cc + 0] = v.x;
        tile[r * FSTR + cc + 1] = v.y;
        tile[r * FSTR + cc + 2] = v.z;
        tile[r * FSTR + cc + 3] = v.w;
    }
    __syncthreads();
    int pp = tid & 63;
    int c0 = tid >> 6;
    for (int i = 0; i < 64; i++) {
        int c = c0 + i * 4;
        out[((size_t)b * Csz + c) * HWsz + p0 + pp] = tile[pp * FSTR + c];
    }
}

// ---------------------------------------------------------------------------
extern "C" void kernel_launch(void* const* d_in, const int* in_sizes, int n_in,
                              void* d_out, int out_size, void* d_ws, size_t ws_size,
                              hipStream_t stream) {
    const float* inp  = (const float*)d_in[0];
    const float* refm = (const float*)d_in[1];
    const int*   midx = (const int*)d_in[2];
    const int*   kidx = (const int*)d_in[3];
    float* out = (float*)d_out;

    char* ws = (char*)d_ws;
    float* inpT  = (float*)(ws);                  // 16 MB   (ends 16777216)
    float* outT  = (float*)(ws + 16777216);       // 4 MB    (ends 20971520)
    float* knT   = (float*)(ws + 20971520);       // 12 MB   (ends 33554432)
    float* uT    = (float*)(ws + 33554432);       // 4 MB    (ends 37748736)
    float* bkT   = (float*)(ws + 37748736);       // 4 MB    (ends 41943040)
    float* dnorm = (float*)(ws + 41943040);       // 64 KB   (ends 42008576)
    float* vmax  = (float*)(ws + 42008576);       // 64 KB   (ends 42074112)
    int*   ind   = (int*)  (ws + 42074112);       // 64 KB   (ends 42139648)
    int*   mp    = (int*)  (ws + 42139648);       // 16 KB   (ends 42156032)
    float* pvmax = (float*)(ws + 42156032);       // 512 KB  (ends 42680320)
    int*   pind  = (int*)  (ws + 42680320);       // 512 KB  (ends 43204608)

    hipLaunchKernelGGL(transpose_kernel, dim3(HWsz / 32, Csz / 32, BZsz), dim3(32, 8), 0, stream,
                       inp, inpT);
    hipLaunchKernelGGL(maskpos_init, dim3(HWsz / 256), dim3(256), 0, stream, mp);
    hipLaunchKernelGGL(maskpos_set, dim3((Msz + 255) / 256), dim3(256), 0, stream, midx, mp);
    hipLaunchKernelGGL(colnorm_kernel, dim3(HWsz / 256, BZsz), dim3(256), 0, stream, inp, dnorm);
    hipLaunchKernelGGL(knprep_kernel, dim3(Ksz / 4, BZsz), dim3(256), 0, stream,
                       inpT, dnorm, kidx, knT);
    hipLaunchKernelGGL(masked_sim_kernel, dim3(BZsz, 16, MKSPL), dim3(256), 0, stream,
                       knT, refm, midx, pvmax, pind);
    hipLaunchKernelGGL(masked_combine_kernel, dim3(4, BZsz), dim3(256), 0, stream,
                       pvmax, pind, midx, vmax, ind);
    hipLaunchKernelGGL(scanprep_kernel, dim3(Msz / 4, BZsz), dim3(256), 0, stream,
                       inpT, dnorm, ind, midx, kidx, uT, bkT);
    hipLaunchKernelGGL(hetero_kernel, dim3(BZsz + BZsz * 24 * KSPL), dim3(256), 0, stream,
                       knT, refm, kidx, pvmax, pind, uT, bkT, vmax, midx, outT);
    hipLaunchKernelGGL(known_combine_kernel, dim3(Ksz / 256, BZsz), dim3(256), 0, stream,
                       pvmax, pind, kidx, vmax, ind);
    hipLaunchKernelGGL(finalize_kernel, dim3(BZsz, HWsz / 64), dim3(256), 0, stream,
                       inpT, outT, ind, kidx, mp, out);
}

// Round 19
// 943.508 us; speedup vs baseline: 1.4662x; 1.1277x over previous
//
#include <hip/hip_runtime.h>
#include <hip/hip_bf16.h>
#include <math.h>

#define HWsz 4096
#define Csz  256
#define BZsz 4
#define Msz  1024
#define Ksz  3072
// known-sim (128p tiles): 24 tiles, KSPL=6
#define KSPL 6
#define KPER 512
#define NKT  4
#define LDP  132
#define KLD  140
// masked-sim (64p tiles): 16 tiles, KSPL=8
#define MKSPL 8
#define MKPER 384
#define MNKT  3
#define MLDP  68

typedef float f32x2 __attribute__((ext_vector_type(2)));

#define PK_MUL(dst, s0, s1) asm("v_pk_mul_f32 %0, %1, %2" : "=v"(dst) : "v"(s0), "v"(s1))
#define PK_ADD(dst, s1)     asm("v_pk_add_f32 %0, %0, %1" : "+v"(dst) : "v"(s1))

// ---------------------------------------------------------------------------
// K0: transpose input [b][c][p] -> inpT [b][p][c]
// ---------------------------------------------------------------------------
__global__ void transpose_kernel(const float* __restrict__ in, float* __restrict__ outT) {
    __shared__ float tile[32][33];
    int b  = blockIdx.z;
    int p0 = blockIdx.x * 32;
    int c0 = blockIdx.y * 32;
    int tx = threadIdx.x;
    int ty = threadIdx.y;
#pragma unroll
    for (int i = 0; i < 4; i++) {
        int c = c0 + ty + i * 8;
        tile[ty + i * 8][tx] = in[((size_t)b * Csz + c) * HWsz + p0 + tx];
    }
    __syncthreads();
#pragma unroll
    for (int i = 0; i < 4; i++) {
        int p = p0 + ty + i * 8;
        outT[((size_t)b * HWsz + p) * Csz + c0 + tx] = tile[tx][ty + i * 8];
    }
}

// ---------------------------------------------------------------------------
// K1: norm replica (sequential f32 sum of f32 squares, sqrt, +1e-8f)
// ---------------------------------------------------------------------------
__global__ void colnorm_kernel(const float* __restrict__ inp, float* __restrict__ dnorm) {
#pragma clang fp contract(off)
    int p = blockIdx.x * 256 + threadIdx.x;
    int b = blockIdx.y;
    const float* col = inp + (size_t)b * Csz * HWsz + p;
    float acc = 0.f;
    for (int c = 0; c < Csz; c++) {
        float x  = col[(size_t)c * HWsz];
        float sq = x * x;
        acc = acc + sq;
    }
    dnorm[b * HWsz + p] = sqrtf(acc) + 1e-8f;
}

// ---------------------------------------------------------------------------
// K1b: knT[b][kk][c] = inpT[b][kidx[kk]][c] / dn  (IEEE f32 div, once)
// ---------------------------------------------------------------------------
__global__ void knprep_kernel(const float* __restrict__ inpT, const float* __restrict__ dnorm,
                              const int* __restrict__ kidx, float* __restrict__ knT) {
    int row  = blockIdx.x * 4 + (threadIdx.x >> 6);
    int lane = threadIdx.x & 63;
    int b    = blockIdx.y;
    int kid  = kidx[row];
    float dn = dnorm[b * HWsz + kid];
    const float* src = inpT + ((size_t)b * HWsz + kid) * Csz + lane * 4;
    float4 v = *(const float4*)src;
    float4 w = {v.x / dn, v.y / dn, v.z / dn, v.w / dn};
    *(float4*)(knT + ((size_t)b * Ksz + row) * Csz + lane * 4) = w;
}

// ---------------------------------------------------------------------------
// K2m: masked-pixel sim (64p x K tile, KSPL=8). Numerics identical.
// ---------------------------------------------------------------------------
__launch_bounds__(256, 2)
__global__ void masked_sim_kernel(const float* __restrict__ knT,
                                  const float* __restrict__ refm,
                                  const int* __restrict__ midx,
                                  float* __restrict__ pvmax, int* __restrict__ pind) {
#pragma clang fp contract(off)
    __shared__ float rf[64][MLDP];  // [c][p]
    __shared__ float kn[64][KLD];   // [c][kcol]

    int b   = blockIdx.x;
    int p0  = blockIdx.y * 64;
    int ks  = blockIdx.z;
    int k0  = ks * MKPER;
    int tid = threadIdx.x;

    int tr = tid >> 4;
    int tc = tid & 15;
    int kc = tc * 8 + ((tc >> 2) << 2);

    int skk  = tid >> 1;
    int sc4  = (tid & 1) * 32;
    int kcol = skk + ((skk >> 5) << 2);

    float best[4];
    int   bidx[4];
#pragma unroll
    for (int i = 0; i < 4; i++) { best[i] = -INFINITY; bidx[i] = 0x7fffffff; }

    for (int kt = 0; kt < MNKT; kt++) {
        int ktbase = k0 + kt * 128;
        const float* nrow = knT + ((size_t)b * Ksz + ktbase + skk) * Csz;

        f32x2 acc[4][4];
#pragma unroll
        for (int i = 0; i < 4; i++)
#pragma unroll
            for (int jj = 0; jj < 4; jj++) acc[i][jj] = (f32x2){0.f, 0.f};

        for (int cc = 0; cc < 4; cc++) {
            __syncthreads();
            {
                int pg  = (tid & 15) * 4;
                int pix = midx[p0 + pg];
#pragma unroll
                for (int i = 0; i < 4; i++) {
                    int c = i * 16 + (tid >> 4);
                    float4 v = *(const float4*)&refm[((size_t)b * Csz + cc * 64 + c) * HWsz + pix];
                    *(float4*)&rf[c][pg] = v;
                }
            }
            const float* src = nrow + cc * 64 + sc4;
#pragma unroll
            for (int i = 0; i < 8; i++) {
                float4 v = *(const float4*)(src + i * 4);
                int c = sc4 + i * 4;
                kn[c + 0][kcol] = v.x;
                kn[c + 1][kcol] = v.y;
                kn[c + 2][kcol] = v.z;
                kn[c + 3][kcol] = v.w;
            }
            __syncthreads();

#pragma unroll 2
            for (int c = 0; c < 64; c++) {
                float4 a0 = *(const float4*)&rf[c][tr * 4];
                float4 b0 = *(const float4*)&kn[c][kc];
                float4 b1 = *(const float4*)&kn[c][kc + 4];
                float av[4] = {a0.x, a0.y, a0.z, a0.w};
                f32x2 B[4] = {{b0.x, b0.y}, {b0.z, b0.w}, {b1.x, b1.y}, {b1.z, b1.w}};
#pragma unroll
                for (int i = 0; i < 4; i++) {
                    f32x2 av2 = {av[i], av[i]};
#pragma unroll
                    for (int jj = 0; jj < 4; jj++) {
                        f32x2 pr;
                        PK_MUL(pr, av2, B[jj]);
                        PK_ADD(acc[i][jj], pr);
                    }
                }
            }
        }
#pragma unroll
        for (int j = 0; j < 8; j++) {
            int k = ktbase + tc * 8 + j;
#pragma unroll
            for (int i = 0; i < 4; i++) {
                float v = (j & 1) ? acc[i][j >> 1].y : acc[i][j >> 1].x;
                if (v > best[i] || (v == best[i] && k < bidx[i])) { best[i] = v; bidx[i] = k; }
            }
        }
    }

    __syncthreads();
    float* sv = &rf[0][0];
    int*   si = (int*)&kn[0][0];
#pragma unroll
    for (int i = 0; i < 4; i++) {
        int p = tr * 4 + i;
        sv[p * 16 + tc] = best[i];
        si[p * 16 + tc] = bidx[i];
    }
    __syncthreads();
    if (tid < 64) {
        float bv = -INFINITY; int bi = 0x7fffffff;
        for (int t = 0; t < 16; t++) {
            float v = sv[tid * 16 + t];
            int   k = si[tid * 16 + t];
            if (v > bv || (v == bv && k < bi)) { bv = v; bi = k; }
        }
        int pix = midx[p0 + tid];
        pvmax[((size_t)ks * BZsz + b) * HWsz + pix] = bv;
        pind [((size_t)ks * BZsz + b) * HWsz + pix] = bi;
    }
}

// ---------------------------------------------------------------------------
// K2bm: combine masked splits (ks 0..7 ascending => global first-max)
// ---------------------------------------------------------------------------
__global__ void masked_combine_kernel(const float* __restrict__ pvmax, const int* __restrict__ pind,
                                      const int* __restrict__ midx,
                                      float* __restrict__ vmax, int* __restrict__ ind) {
    int i = blockIdx.x * 256 + threadIdx.x;   // 0..1023
    int b = blockIdx.y;
    int pix = midx[i];
    float bv = -INFINITY; int bi = 0x7fffffff;
    for (int ks = 0; ks < MKSPL; ks++) {
        float v = pvmax[((size_t)ks * BZsz + b) * HWsz + pix];
        int   k = pind [((size_t)ks * BZsz + b) * HWsz + pix];
        if (v > bv || (v == bv && k < bi)) { bv = v; bi = k; }
    }
    vmax[b * HWsz + pix] = bv;
    ind [b * HWsz + pix] = bi;
}

// ---------------------------------------------------------------------------
// K2b: combine known splits (ks 0..5)
// ---------------------------------------------------------------------------
__global__ void known_combine_kernel(const float* __restrict__ pvmax, const int* __restrict__ pind,
                                     const int* __restrict__ kidx,
                                     float* __restrict__ vmax, int* __restrict__ ind) {
    int i = blockIdx.x * 256 + threadIdx.x;   // 0..3071
    int b = blockIdx.y;
    int pix = kidx[i];
    float bv = -INFINITY; int bi = 0x7fffffff;
    for (int ks = 0; ks < KSPL; ks++) {
        float v = pvmax[((size_t)ks * BZsz + b) * HWsz + pix];
        int   k = pind [((size_t)ks * BZsz + b) * HWsz + pix];
        if (v > bv || (v == bv && k < bi)) { bv = v; bi = k; }
    }
    vmax[b * HWsz + pix] = bv;
    ind [b * HWsz + pix] = bi;
}

// ---------------------------------------------------------------------------
// K2c: scanprep
// ---------------------------------------------------------------------------
__global__ void scanprep_kernel(const float* __restrict__ inpT, const float* __restrict__ dnorm,
                                const int* __restrict__ ind, const int* __restrict__ midx,
                                const int* __restrict__ kidx,
                                float* __restrict__ uT, float* __restrict__ bkT) {
    int t    = blockIdx.x * 4 + (threadIdx.x >> 6);
    int lane = threadIdx.x & 63;
    int b    = blockIdx.y;
    int pp   = midx[t];
    float dn = dnorm[b * HWsz + pp];
    int bkid = kidx[ind[b * HWsz + pp]];
    const float* us = inpT + ((size_t)b * HWsz + pp) * Csz + lane * 4;
    const float* bs = inpT + ((size_t)b * HWsz + bkid) * Csz + lane * 4;
    float4 v = *(const float4*)us;
    float4 w = {v.x / dn, v.y / dn, v.z / dn, v.w / dn};
    *(float4*)(uT  + ((size_t)b * Msz + t) * Csz + lane * 4) = w;
    *(float4*)(bkT + ((size_t)b * Msz + t) * Csz + lane * 4) = *(const float4*)bs;
}

// ---------------------------------------------------------------------------
// K3h: HETEROGENEOUS kernel.
// blocks 0..3   = serial scan, producer-consumer: wave 0 consumes from an
//                 LDS double-buffer (16 steps/chunk, u+bk rows = 64KB);
//                 waves 1..3 prefetch the next chunk from HBM. Scan's loads
//                 leave the critical path and are immune to L2 thrash.
// blocks 4..579 = known-pixel sim (128p tiles, KSPL=6 -> 576 blocks fills
//                 the 512 resident slots; R18's 388 left half the CUs at
//                 1 wave/SIMD -> VALUBusy 35%).
// All numerics bit-identical.
// ---------------------------------------------------------------------------

#define CH(LQ4, RA_N, RB_N, RA_C, RB_C) \
    "v_readlane_b32 " #RA_N ", %[va], " #LQ4 "\n\t" \
    "v_add_f32 %[dot], " #RA_C ", %[dot]\n\t" \
    "v_readlane_b32 " #RB_N ", %[vb], " #LQ4 "\n\t" \
    "v_add_f32 %[dot], " #RB_C ", %[dot]\n\t"

#define CH_BLOCK8(L0, L1, L2, L3, L4, L5, L6, L7) \
    CH(L0, s44, s52, s40, s48) \
    CH(L1, s45, s53, s41, s49) \
    CH(L2, s46, s54, s42, s50) \
    CH(L3, s47, s55, s43, s51) \
    CH(L4, s40, s48, s44, s52) \
    CH(L5, s41, s49, s45, s53) \
    CH(L6, s42, s50, s46, s54) \
    CH(L7, s43, s51, s47, s55)

__launch_bounds__(256, 2)
__global__ void hetero_kernel(const float* __restrict__ knT, const float* __restrict__ refm,
                              const int* __restrict__ kidx,
                              float* __restrict__ pvmax, int* __restrict__ pind,
                              const float* __restrict__ uT, const float* __restrict__ bkT,
                              const float* __restrict__ vmax, const int* __restrict__ midx,
                              float* __restrict__ outT) {
#pragma clang fp contract(off)
    __shared__ float smem[17408];   // 69632 B
    int gid = blockIdx.x;
    int tid = threadIdx.x;

    if (gid < BZsz) {
        // ------------------- scan branch: producer-consumer ----------------
        // smem layout: [0..1023] L_vm; [1024..] 2 chunks x 16 steps x
        // (256 u + 256 bk) floats = 16384 floats.
        float* L_vm = smem;
        float* buf  = smem + 1024;
        int b = gid;
        for (int t = tid; t < Msz; t += 256) L_vm[t] = vmax[b * HWsz + midx[t]];
        // stage chunk 0 cooperatively (2048 float4s, 8 per thread)
        {
            const float* ubase = uT  + (size_t)b * Msz * Csz;
            const float* bbase = bkT + (size_t)b * Msz * Csz;
#pragma unroll
            for (int i = 0; i < 8; i++) {
                int j = tid + i * 256;          // 0..2047
                int s = j >> 7;
                int r = j & 127;
                int which = r >> 6;
                int l4 = r & 63;
                const float* src = (which ? bbase : ubase) + (size_t)s * Csz + l4 * 4;
                float4 v = *(const float4*)src;
                *(float4*)(buf + s * 512 + which * 256 + l4 * 4) = v;
            }
        }
        __syncthreads();

        if (tid < 64) {
            __builtin_amdgcn_s_setprio(3);
            int lane = tid;
            float o0 = 0.f, o1 = 0.f, o2 = 0.f, o3 = 0.f;
            for (int c = 0; c < Msz / 16; c++) {
                float* cb = buf + (c & 1) * 8192;
#pragma unroll 4
                for (int s = 0; s < 16; s++) {
                    int t = c * 16 + s;
                    float4 u  = *(const float4*)(cb + s * 512 + lane * 4);
                    float4 Bc = *(const float4*)(cb + s * 512 + 256 + lane * 4);
                    float pA = u.y * o1;
                    float rA = __builtin_fmaf(u.x, o0, pA);
                    float pB = u.w * o3;
                    float rB = __builtin_fmaf(u.z, o2, pB);
                    float dot = 0.f;
                    asm volatile(
                        "v_readlane_b32 s40, %[va], 0\n\t"
                        "v_readlane_b32 s48, %[vb], 0\n\t"
                        "v_readlane_b32 s41, %[va], 1\n\t"
                        "v_readlane_b32 s49, %[vb], 1\n\t"
                        "v_readlane_b32 s42, %[va], 2\n\t"
                        "v_readlane_b32 s50, %[vb], 2\n\t"
                        "v_readlane_b32 s43, %[va], 3\n\t"
                        "v_readlane_b32 s51, %[vb], 3\n\t"
                        CH_BLOCK8( 4,  5,  6,  7,  8,  9, 10, 11)
                        CH_BLOCK8(12, 13, 14, 15, 16, 17, 18, 19)
                        CH_BLOCK8(20, 21, 22, 23, 24, 25, 26, 27)
                        CH_BLOCK8(28, 29, 30, 31, 32, 33, 34, 35)
                        CH_BLOCK8(36, 37, 38, 39, 40, 41, 42, 43)
                        CH_BLOCK8(44, 45, 46, 47, 48, 49, 50, 51)
                        CH_BLOCK8(52, 53, 54, 55, 56, 57, 58, 59)
                        CH(60, s44, s52, s40, s48)
                        CH(61, s45, s53, s41, s49)
                        CH(62, s46, s54, s42, s50)
                        CH(63, s47, s55, s43, s51)
                        "v_add_f32 %[dot], s44, %[dot]\n\t"
                        "v_add_f32 %[dot], s52, %[dot]\n\t"
                        "v_add_f32 %[dot], s45, %[dot]\n\t"
                        "v_add_f32 %[dot], s53, %[dot]\n\t"
                        "v_add_f32 %[dot], s46, %[dot]\n\t"
                        "v_add_f32 %[dot], s54, %[dot]\n\t"
                        "v_add_f32 %[dot], s47, %[dot]\n\t"
                        "v_add_f32 %[dot], s55, %[dot]\n\t"
                        : [dot] "+v"(dot)
                        : [va] "v"(rA), [vb] "v"(rB)
                        : "s40","s41","s42","s43","s44","s45","s46","s47",
                          "s48","s49","s50","s51","s52","s53","s54","s55");
                    float at    = dot;
                    float vm    = L_vm[t];
                    float denom = at + vm;      // f32 add
                    float anew  = at / denom;   // IEEE f32 div
                    float aori  = vm / denom;   // IEEE f32 div
                    float m0 = anew * o0, n0 = aori * Bc.x;
                    float m1 = anew * o1, n1 = aori * Bc.y;
                    float m2 = anew * o2, n2 = aori * Bc.z;
                    float m3 = anew * o3, n3 = aori * Bc.w;
                    o0 = m0 + n0; o1 = m1 + n1; o2 = m2 + n2; o3 = m3 + n3;
                    float4 w = {o0, o1, o2, o3};
                    *(float4*)&outT[((size_t)b * Msz + t) * Csz + lane * 4] = w;
                }
                __syncthreads();
            }
        } else {
            // producers: stage chunk c+1 while consumer computes chunk c
            const float* ubase = uT  + (size_t)b * Msz * Csz;
            const float* bbase = bkT + (size_t)b * Msz * Csz;
            int pt_ = tid - 64;                 // 0..191
            for (int c = 0; c < Msz / 16; c++) {
                int cn = c + 1;
                if (cn < Msz / 16) {
                    float* db = buf + (cn & 1) * 8192;
#pragma unroll
                    for (int i = 0; i < 11; i++) {
                        int j = pt_ + i * 192;
                        if (j < 2048) {
                            int s = j >> 7;
                            int r = j & 127;
                            int which = r >> 6;
                            int l4 = r & 63;
                            const float* src = (which ? bbase : ubase) +
                                               ((size_t)(cn * 16 + s)) * Csz + l4 * 4;
                            float4 v = *(const float4*)src;
                            *(float4*)(db + s * 512 + which * 256 + l4 * 4) = v;
                        }
                    }
                }
                __syncthreads();
            }
        }
        return;
    }

    // ------------------- known-pixel sim branch ---------------------------
    int g  = gid - BZsz;
    int ks = g % KSPL;
    int pt = (g / KSPL) % 24;
    int b  = g / (24 * KSPL);
    int p0 = pt * 128;
    int k0 = ks * KPER;

    float (*rf)[LDP] = (float(*)[LDP])smem;
    float (*kn)[KLD] = (float(*)[KLD])(smem + 64 * LDP);

    int tr = tid >> 4;
    int tc = tid & 15;
    int kc = tc * 8 + ((tc >> 2) << 2);

    int rowgrp = tid >> 5;
    int px4    = (tid & 31) * 4;
    int skk  = tid >> 1;
    int sc4  = (tid & 1) * 32;
    int kcol = skk + ((skk >> 5) << 2);

    float best[8];
    int   bidx[8];
#pragma unroll
    for (int i = 0; i < 8; i++) { best[i] = -INFINITY; bidx[i] = 0x7fffffff; }

    for (int kt = 0; kt < NKT; kt++) {
        int ktbase = k0 + kt * 128;
        const float* nrow = knT + ((size_t)b * Ksz + ktbase + skk) * Csz;

        f32x2 acc[8][4];
#pragma unroll
        for (int i = 0; i < 8; i++)
#pragma unroll
            for (int jj = 0; jj < 4; jj++) acc[i][jj] = (f32x2){0.f, 0.f};

        for (int cc = 0; cc < 4; cc++) {
            __syncthreads();
            {
                int pix = kidx[p0 + px4];
#pragma unroll
                for (int i = 0; i < 8; i++) {
                    int c = i * 8 + rowgrp;
                    float4 v = *(const float4*)&refm[((size_t)b * Csz + cc * 64 + c) * HWsz + pix];
                    *(float4*)&rf[c][px4] = v;
                }
            }
            const float* src = nrow + cc * 64 + sc4;
#pragma unroll
            for (int i = 0; i < 8; i++) {
                float4 v = *(const float4*)(src + i * 4);
                int c = sc4 + i * 4;
                kn[c + 0][kcol] = v.x;
                kn[c + 1][kcol] = v.y;
                kn[c + 2][kcol] = v.z;
                kn[c + 3][kcol] = v.w;
            }
            __syncthreads();

#pragma unroll 2
            for (int c = 0; c < 64; c++) {
                float4 a0 = *(const float4*)&rf[c][tr * 8];
                float4 a1 = *(const float4*)&rf[c][tr * 8 + 4];
                float4 b0 = *(const float4*)&kn[c][kc];
                float4 b1 = *(const float4*)&kn[c][kc + 4];
                float av[8] = {a0.x, a0.y, a0.z, a0.w, a1.x, a1.y, a1.z, a1.w};
                f32x2 B[4] = {{b0.x, b0.y}, {b0.z, b0.w}, {b1.x, b1.y}, {b1.z, b1.w}};
#pragma unroll
                for (int i = 0; i < 8; i++) {
                    f32x2 av2 = {av[i], av[i]};
#pragma unroll
                    for (int jj = 0; jj < 4; jj++) {
                        f32x2 pr;
                        PK_MUL(pr, av2, B[jj]);
                        PK_ADD(acc[i][jj], pr);
                    }
                }
            }
        }
#pragma unroll
        for (int j = 0; j < 8; j++) {
            int k = ktbase + tc * 8 + j;
#pragma unroll
            for (int i = 0; i < 8; i++) {
                float v = (j & 1) ? acc[i][j >> 1].y : acc[i][j >> 1].x;
                if (v > best[i] || (v == best[i] && k < bidx[i])) { best[i] = v; bidx[i] = k; }
            }
        }
    }

    __syncthreads();
    float* sv = &rf[0][0];
    int*   si = (int*)&kn[0][0];
#pragma unroll
    for (int i = 0; i < 8; i++) {
        int p = tr * 8 + i;
        sv[p * 16 + tc] = best[i];
        si[p * 16 + tc] = bidx[i];
    }
    __syncthreads();
    if (tid < 128) {
        float bv = -INFINITY; int bi = 0x7fffffff;
        for (int t = 0; t < 16; t++) {
            float v = sv[tid * 16 + t];
            int   k = si[tid * 16 + t];
            if (v > bv || (v == bv && k < bi)) { bv = v; bi = k; }
        }
        int pix = kidx[p0 + tid];
        pvmax[((size_t)ks * BZsz + b) * HWsz + pix] = bv;
        pind [((size_t)ks * BZsz + b) * HWsz + pix] = bi;
    }
}

// ---------------------------------------------------------------------------
// K4: mask position map
// ---------------------------------------------------------------------------
__global__ void maskpos_init(int* mp) { mp[blockIdx.x * 256 + threadIdx.x] = -1; }
__global__ void maskpos_set(const int* __restrict__ midx, int* mp) {
    int t = blockIdx.x * 256 + threadIdx.x;
    if (t < Msz) mp[midx[t]] = t;
}

// ---------------------------------------------------------------------------
// K5: assemble output [b][c][p]
// ---------------------------------------------------------------------------
#define FSTR 261
__launch_bounds__(256)
__global__ void finalize_kernel(const float* __restrict__ inpT, const float* __restrict__ outT,
                                const int* __restrict__ ind, const int* __restrict__ kidx,
                                const int* __restrict__ mp, float* __restrict__ out) {
    __shared__ float tile[64 * FSTR];
    int b   = blockIdx.x;
    int p0  = blockIdx.y * 64;
    int tid = threadIdx.x;
    int rl  = tid >> 6;
    int cc  = (tid & 63) * 4;
    for (int i = 0; i < 16; i++) {
        int r = rl + i * 4;
        int p = p0 + r;
        int m = mp[p];
        const float* src = (m >= 0) ? (outT + ((size_t)b * Msz + m) * Csz)
                                    : (inpT + ((size_t)b * HWsz + kidx[ind[b * HWsz + p]]) * Csz);
        float4 v = *(const float4*)(src + cc);
        tile[r * FSTR + cc + 0] = v.x;
        tile[r * FSTR + cc + 1] = v.y;
        tile[r * FSTR + cc + 2] = v.z;
        tile[r * FSTR + cc + 3] = v.w;
    }
    __syncthreads();
    int pp = tid & 63;
    int c0 = tid >> 6;
    for (int i = 0; i < 64; i++) {
        int c = c0 + i * 4;
        out[((size_t)b * Csz + c) * HWsz + p0 + pp] = tile[pp * FSTR + c];
    }
}

// ---------------------------------------------------------------------------
extern "C" void kernel_launch(void* const* d_in, const int* in_sizes, int n_in,
                              void* d_out, int out_size, void* d_ws, size_t ws_size,
                              hipStream_t stream) {
    const float* inp  = (const float*)d_in[0];
    const float* refm = (const float*)d_in[1];
    const int*   midx = (const int*)d_in[2];
    const int*   kidx = (const int*)d_in[3];
    float* out = (float*)d_out;

    char* ws = (char*)d_ws;
    float* inpT  = (float*)(ws);                  // 16 MB   (ends 16777216)
    float* outT  = (float*)(ws + 16777216);       // 4 MB    (ends 20971520)
    float* knT   = (float*)(ws + 20971520);       // 12 MB   (ends 33554432)
    float* uT    = (float*)(ws + 33554432);       // 4 MB    (ends 37748736)
    float* bkT   = (float*)(ws + 37748736);       // 4 MB    (ends 41943040)
    float* dnorm = (float*)(ws + 41943040);       // 64 KB   (ends 42008576)
    float* vmax  = (float*)(ws + 42008576);       // 64 KB   (ends 42074112)
    int*   ind   = (int*)  (ws + 42074112);       // 64 KB   (ends 42139648)
    int*   mp    = (int*)  (ws + 42139648);       // 16 KB   (ends 42156032)
    float* pvmax = (float*)(ws + 42156032);       // 512 KB  (ends 42680320)
    int*   pind  = (int*)  (ws + 42680320);       // 512 KB  (ends 43204608)

    hipLaunchKernelGGL(transpose_kernel, dim3(HWsz / 32, Csz / 32, BZsz), dim3(32, 8), 0, stream,
                       inp, inpT);
    hipLaunchKernelGGL(maskpos_init, dim3(HWsz / 256), dim3(256), 0, stream, mp);
    hipLaunchKernelGGL(maskpos_set, dim3((Msz + 255) / 256), dim3(256), 0, stream, midx, mp);
    hipLaunchKernelGGL(colnorm_kernel, dim3(HWsz / 256, BZsz), dim3(256), 0, stream, inp, dnorm);
    hipLaunchKernelGGL(knprep_kernel, dim3(Ksz / 4, BZsz), dim3(256), 0, stream,
                       inpT, dnorm, kidx, knT);
    hipLaunchKernelGGL(masked_sim_kernel, dim3(BZsz, 16, MKSPL), dim3(256), 0, stream,
                       knT, refm, midx, pvmax, pind);
    hipLaunchKernelGGL(masked_combine_kernel, dim3(4, BZsz), dim3(256), 0, stream,
                       pvmax, pind, midx, vmax, ind);
    hipLaunchKernelGGL(scanprep_kernel, dim3(Msz / 4, BZsz), dim3(256), 0, stream,
                       inpT, dnorm, ind, midx, kidx, uT, bkT);
    hipLaunchKernelGGL(hetero_kernel, dim3(BZsz + BZsz * 24 * KSPL), dim3(256), 0, stream,
                       knT, refm, kidx, pvmax, pind, uT, bkT, vmax, midx, outT);
    hipLaunchKernelGGL(known_combine_kernel, dim3(Ksz / 256, BZsz), dim3(256), 0, stream,
                       pvmax, pind, kidx, vmax, ind);
    hipLaunchKernelGGL(finalize_kernel, dim3(BZsz, HWsz / 64), dim3(256), 0, stream,
                       inpT, outT, ind, kidx, mp, out);
}

// Round 20
// 942.119 us; speedup vs baseline: 1.4684x; 1.0015x over previous
//
#include <hip/hip_runtime.h>
#include <hip/hip_bf16.h>
#include <math.h>

#define HWsz 4096
#define Csz  256
#define BZsz 4
#define Msz  1024
#define Ksz  3072
// known-sim (128p tiles): 24 tiles, KSPL=6
#define KSPL 6
#define KPER 512
#define NKT  4
#define LDP  132
#define KLD  140
// masked-sim (64p tiles): 16 tiles, KSPL=8
#define MKSPL 8
#define MKPER 384
#define MNKT  3
#define MLDP  68

typedef float f32x2 __attribute__((ext_vector_type(2)));

#define PK_MUL(dst, s0, s1) asm("v_pk_mul_f32 %0, %1, %2" : "=v"(dst) : "v"(s0), "v"(s1))
#define PK_ADD(dst, s1)     asm("v_pk_add_f32 %0, %0, %1" : "+v"(dst) : "v"(s1))

// ---------------------------------------------------------------------------
// K0: transpose input [b][c][p] -> inpT [b][p][c]
// ---------------------------------------------------------------------------
__global__ void transpose_kernel(const float* __restrict__ in, float* __restrict__ outT) {
    __shared__ float tile[32][33];
    int b  = blockIdx.z;
    int p0 = blockIdx.x * 32;
    int c0 = blockIdx.y * 32;
    int tx = threadIdx.x;
    int ty = threadIdx.y;
#pragma unroll
    for (int i = 0; i < 4; i++) {
        int c = c0 + ty + i * 8;
        tile[ty + i * 8][tx] = in[((size_t)b * Csz + c) * HWsz + p0 + tx];
    }
    __syncthreads();
#pragma unroll
    for (int i = 0; i < 4; i++) {
        int p = p0 + ty + i * 8;
        outT[((size_t)b * HWsz + p) * Csz + c0 + tx] = tile[tx][ty + i * 8];
    }
}

// ---------------------------------------------------------------------------
// K1: norm replica (sequential f32 sum of f32 squares, sqrt, +1e-8f)
// ---------------------------------------------------------------------------
__global__ void colnorm_kernel(const float* __restrict__ inp, float* __restrict__ dnorm) {
#pragma clang fp contract(off)
    int p = blockIdx.x * 256 + threadIdx.x;
    int b = blockIdx.y;
    const float* col = inp + (size_t)b * Csz * HWsz + p;
    float acc = 0.f;
    for (int c = 0; c < Csz; c++) {
        float x  = col[(size_t)c * HWsz];
        float sq = x * x;
        acc = acc + sq;
    }
    dnorm[b * HWsz + p] = sqrtf(acc) + 1e-8f;
}

// ---------------------------------------------------------------------------
// K1b: knT[b][kk][c] = inpT[b][kidx[kk]][c] / dn  (IEEE f32 div, once)
// ---------------------------------------------------------------------------
__global__ void knprep_kernel(const float* __restrict__ inpT, const float* __restrict__ dnorm,
                              const int* __restrict__ kidx, float* __restrict__ knT) {
    int row  = blockIdx.x * 4 + (threadIdx.x >> 6);
    int lane = threadIdx.x & 63;
    int b    = blockIdx.y;
    int kid  = kidx[row];
    float dn = dnorm[b * HWsz + kid];
    const float* src = inpT + ((size_t)b * HWsz + kid) * Csz + lane * 4;
    float4 v = *(const float4*)src;
    float4 w = {v.x / dn, v.y / dn, v.z / dn, v.w / dn};
    *(float4*)(knT + ((size_t)b * Ksz + row) * Csz + lane * 4) = w;
}

// ---------------------------------------------------------------------------
// K2m: masked-pixel sim (64p x K tile, KSPL=8). Numerics identical.
// ---------------------------------------------------------------------------
__launch_bounds__(256, 2)
__global__ void masked_sim_kernel(const float* __restrict__ knT,
                                  const float* __restrict__ refm,
                                  const int* __restrict__ midx,
                                  float* __restrict__ pvmax, int* __restrict__ pind) {
#pragma clang fp contract(off)
    __shared__ float rf[64][MLDP];  // [c][p]
    __shared__ float kn[64][KLD];   // [c][kcol]

    int b   = blockIdx.x;
    int p0  = blockIdx.y * 64;
    int ks  = blockIdx.z;
    int k0  = ks * MKPER;
    int tid = threadIdx.x;

    int tr = tid >> 4;
    int tc = tid & 15;
    int kc = tc * 8 + ((tc >> 2) << 2);

    int skk  = tid >> 1;
    int sc4  = (tid & 1) * 32;
    int kcol = skk + ((skk >> 5) << 2);

    float best[4];
    int   bidx[4];
#pragma unroll
    for (int i = 0; i < 4; i++) { best[i] = -INFINITY; bidx[i] = 0x7fffffff; }

    for (int kt = 0; kt < MNKT; kt++) {
        int ktbase = k0 + kt * 128;
        const float* nrow = knT + ((size_t)b * Ksz + ktbase + skk) * Csz;

        f32x2 acc[4][4];
#pragma unroll
        for (int i = 0; i < 4; i++)
#pragma unroll
            for (int jj = 0; jj < 4; jj++) acc[i][jj] = (f32x2){0.f, 0.f};

        for (int cc = 0; cc < 4; cc++) {
            __syncthreads();
            {
                int pg  = (tid & 15) * 4;
                int pix = midx[p0 + pg];
#pragma unroll
                for (int i = 0; i < 4; i++) {
                    int c = i * 16 + (tid >> 4);
                    float4 v = *(const float4*)&refm[((size_t)b * Csz + cc * 64 + c) * HWsz + pix];
                    *(float4*)&rf[c][pg] = v;
                }
            }
            const float* src = nrow + cc * 64 + sc4;
#pragma unroll
            for (int i = 0; i < 8; i++) {
                float4 v = *(const float4*)(src + i * 4);
                int c = sc4 + i * 4;
                kn[c + 0][kcol] = v.x;
                kn[c + 1][kcol] = v.y;
                kn[c + 2][kcol] = v.z;
                kn[c + 3][kcol] = v.w;
            }
            __syncthreads();

#pragma unroll 2
            for (int c = 0; c < 64; c++) {
                float4 a0 = *(const float4*)&rf[c][tr * 4];
                float4 b0 = *(const float4*)&kn[c][kc];
                float4 b1 = *(const float4*)&kn[c][kc + 4];
                float av[4] = {a0.x, a0.y, a0.z, a0.w};
                f32x2 B[4] = {{b0.x, b0.y}, {b0.z, b0.w}, {b1.x, b1.y}, {b1.z, b1.w}};
#pragma unroll
                for (int i = 0; i < 4; i++) {
                    f32x2 av2 = {av[i], av[i]};
#pragma unroll
                    for (int jj = 0; jj < 4; jj++) {
                        f32x2 pr;
                        PK_MUL(pr, av2, B[jj]);
                        PK_ADD(acc[i][jj], pr);
                    }
                }
            }
        }
#pragma unroll
        for (int j = 0; j < 8; j++) {
            int k = ktbase + tc * 8 + j;
#pragma unroll
            for (int i = 0; i < 4; i++) {
                float v = (j & 1) ? acc[i][j >> 1].y : acc[i][j >> 1].x;
                if (v > best[i] || (v == best[i] && k < bidx[i])) { best[i] = v; bidx[i] = k; }
            }
        }
    }

    __syncthreads();
    float* sv = &rf[0][0];
    int*   si = (int*)&kn[0][0];
#pragma unroll
    for (int i = 0; i < 4; i++) {
        int p = tr * 4 + i;
        sv[p * 16 + tc] = best[i];
        si[p * 16 + tc] = bidx[i];
    }
    __syncthreads();
    if (tid < 64) {
        float bv = -INFINITY; int bi = 0x7fffffff;
        for (int t = 0; t < 16; t++) {
            float v = sv[tid * 16 + t];
            int   k = si[tid * 16 + t];
            if (v > bv || (v == bv && k < bi)) { bv = v; bi = k; }
        }
        int pix = midx[p0 + tid];
        pvmax[((size_t)ks * BZsz + b) * HWsz + pix] = bv;
        pind [((size_t)ks * BZsz + b) * HWsz + pix] = bi;
    }
}

// ---------------------------------------------------------------------------
// K2bm: combine masked splits (ks 0..7 ascending => global first-max)
// ---------------------------------------------------------------------------
__global__ void masked_combine_kernel(const float* __restrict__ pvmax, const int* __restrict__ pind,
                                      const int* __restrict__ midx,
                                      float* __restrict__ vmax, int* __restrict__ ind) {
    int i = blockIdx.x * 256 + threadIdx.x;   // 0..1023
    int b = blockIdx.y;
    int pix = midx[i];
    float bv = -INFINITY; int bi = 0x7fffffff;
    for (int ks = 0; ks < MKSPL; ks++) {
        float v = pvmax[((size_t)ks * BZsz + b) * HWsz + pix];
        int   k = pind [((size_t)ks * BZsz + b) * HWsz + pix];
        if (v > bv || (v == bv && k < bi)) { bv = v; bi = k; }
    }
    vmax[b * HWsz + pix] = bv;
    ind [b * HWsz + pix] = bi;
}

// ---------------------------------------------------------------------------
// K2b: combine known splits (ks 0..5)
// ---------------------------------------------------------------------------
__global__ void known_combine_kernel(const float* __restrict__ pvmax, const int* __restrict__ pind,
                                     const int* __restrict__ kidx,
                                     float* __restrict__ vmax, int* __restrict__ ind) {
    int i = blockIdx.x * 256 + threadIdx.x;   // 0..3071
    int b = blockIdx.y;
    int pix = kidx[i];
    float bv = -INFINITY; int bi = 0x7fffffff;
    for (int ks = 0; ks < KSPL; ks++) {
        float v = pvmax[((size_t)ks * BZsz + b) * HWsz + pix];
        int   k = pind [((size_t)ks * BZsz + b) * HWsz + pix];
        if (v > bv || (v == bv && k < bi)) { bv = v; bi = k; }
    }
    vmax[b * HWsz + pix] = bv;
    ind [b * HWsz + pix] = bi;
}

// ---------------------------------------------------------------------------
// K2c: scanprep
// ---------------------------------------------------------------------------
__global__ void scanprep_kernel(const float* __restrict__ inpT, const float* __restrict__ dnorm,
                                const int* __restrict__ ind, const int* __restrict__ midx,
                                const int* __restrict__ kidx,
                                float* __restrict__ uT, float* __restrict__ bkT) {
    int t    = blockIdx.x * 4 + (threadIdx.x >> 6);
    int lane = threadIdx.x & 63;
    int b    = blockIdx.y;
    int pp   = midx[t];
    float dn = dnorm[b * HWsz + pp];
    int bkid = kidx[ind[b * HWsz + pp]];
    const float* us = inpT + ((size_t)b * HWsz + pp) * Csz + lane * 4;
    const float* bs = inpT + ((size_t)b * HWsz + bkid) * Csz + lane * 4;
    float4 v = *(const float4*)us;
    float4 w = {v.x / dn, v.y / dn, v.z / dn, v.w / dn};
    *(float4*)(uT  + ((size_t)b * Msz + t) * Csz + lane * 4) = w;
    *(float4*)(bkT + ((size_t)b * Msz + t) * Csz + lane * 4) = *(const float4*)bs;
}

// ---------------------------------------------------------------------------
// K3h: HETEROGENEOUS kernel.
// blocks 0..3   = serial scan: REGISTER rolling double-buffer (R16 scheme —
//                 distance-1 named-float4 prefetch; load latency hides under
//                 the ~1100-cyc chain; no LDS roundtrip, no producer barriers)
//                 + setprio(3) on the lone scan wave (T5: dependency-bound
//                 wave sharing a SIMD with throughput sim waves).
// blocks 4..579 = known-pixel sim (128p tiles, KSPL=6).
// All numerics bit-identical to R16-19.
// ---------------------------------------------------------------------------

#define CH(LQ4, RA_N, RB_N, RA_C, RB_C) \
    "v_readlane_b32 " #RA_N ", %[va], " #LQ4 "\n\t" \
    "v_add_f32 %[dot], " #RA_C ", %[dot]\n\t" \
    "v_readlane_b32 " #RB_N ", %[vb], " #LQ4 "\n\t" \
    "v_add_f32 %[dot], " #RB_C ", %[dot]\n\t"

#define CH_BLOCK8(L0, L1, L2, L3, L4, L5, L6, L7) \
    CH(L0, s44, s52, s40, s48) \
    CH(L1, s45, s53, s41, s49) \
    CH(L2, s46, s54, s42, s50) \
    CH(L3, s47, s55, s43, s51) \
    CH(L4, s40, s48, s44, s52) \
    CH(L5, s41, s49, s45, s53) \
    CH(L6, s42, s50, s46, s54) \
    CH(L7, s43, s51, s47, s55)

__launch_bounds__(256, 2)
__global__ void hetero_kernel(const float* __restrict__ knT, const float* __restrict__ refm,
                              const int* __restrict__ kidx,
                              float* __restrict__ pvmax, int* __restrict__ pind,
                              const float* __restrict__ uT, const float* __restrict__ bkT,
                              const float* __restrict__ vmax, const int* __restrict__ midx,
                              float* __restrict__ outT) {
#pragma clang fp contract(off)
    __shared__ float smem[17408];   // 69632 B
    int gid = blockIdx.x;
    int tid = threadIdx.x;

    if (gid < BZsz) {
        // ------------------- scan branch (1 wave, reg dbuf, prio 3) --------
        float* L_vm = smem;
        int b = gid;
        for (int t = tid; t < Msz; t += 256) L_vm[t] = vmax[b * HWsz + midx[t]];
        __syncthreads();
        if (tid >= 64) return;
        __builtin_amdgcn_s_setprio(3);
        int lane = tid;

        const float* ub = uT  + (size_t)b * Msz * Csz + lane * 4;
        const float* bb = bkT + (size_t)b * Msz * Csz + lane * 4;
        float o0 = 0.f, o1 = 0.f, o2 = 0.f, o3 = 0.f;
        float4 Uc = *(const float4*)ub;
        float4 Bc = *(const float4*)bb;

        for (int t = 0; t < Msz; t++) {
            int tn = (t + 1) & (Msz - 1);       // branchless wrap
            float4 Un = *(const float4*)(ub + (size_t)tn * Csz);
            float4 Bn = *(const float4*)(bb + (size_t)tn * Csz);

            float pA = Uc.y * o1;
            float rA = __builtin_fmaf(Uc.x, o0, pA);
            float pB = Uc.w * o3;
            float rB = __builtin_fmaf(Uc.z, o2, pB);
            float dot = 0.f;
            asm volatile(
                "v_readlane_b32 s40, %[va], 0\n\t"
                "v_readlane_b32 s48, %[vb], 0\n\t"
                "v_readlane_b32 s41, %[va], 1\n\t"
                "v_readlane_b32 s49, %[vb], 1\n\t"
                "v_readlane_b32 s42, %[va], 2\n\t"
                "v_readlane_b32 s50, %[vb], 2\n\t"
                "v_readlane_b32 s43, %[va], 3\n\t"
                "v_readlane_b32 s51, %[vb], 3\n\t"
                CH_BLOCK8( 4,  5,  6,  7,  8,  9, 10, 11)
                CH_BLOCK8(12, 13, 14, 15, 16, 17, 18, 19)
                CH_BLOCK8(20, 21, 22, 23, 24, 25, 26, 27)
                CH_BLOCK8(28, 29, 30, 31, 32, 33, 34, 35)
                CH_BLOCK8(36, 37, 38, 39, 40, 41, 42, 43)
                CH_BLOCK8(44, 45, 46, 47, 48, 49, 50, 51)
                CH_BLOCK8(52, 53, 54, 55, 56, 57, 58, 59)
                CH(60, s44, s52, s40, s48)
                CH(61, s45, s53, s41, s49)
                CH(62, s46, s54, s42, s50)
                CH(63, s47, s55, s43, s51)
                "v_add_f32 %[dot], s44, %[dot]\n\t"
                "v_add_f32 %[dot], s52, %[dot]\n\t"
                "v_add_f32 %[dot], s45, %[dot]\n\t"
                "v_add_f32 %[dot], s53, %[dot]\n\t"
                "v_add_f32 %[dot], s46, %[dot]\n\t"
                "v_add_f32 %[dot], s54, %[dot]\n\t"
                "v_add_f32 %[dot], s47, %[dot]\n\t"
                "v_add_f32 %[dot], s55, %[dot]\n\t"
                : [dot] "+v"(dot)
                : [va] "v"(rA), [vb] "v"(rB)
                : "s40","s41","s42","s43","s44","s45","s46","s47",
                  "s48","s49","s50","s51","s52","s53","s54","s55");
            float at    = dot;
            float vm    = L_vm[t];
            float denom = at + vm;      // f32 add
            float anew  = at / denom;   // IEEE f32 div
            float aori  = vm / denom;   // IEEE f32 div
            float m0 = anew * o0, n0 = aori * Bc.x;
            float m1 = anew * o1, n1 = aori * Bc.y;
            float m2 = anew * o2, n2 = aori * Bc.z;
            float m3 = anew * o3, n3 = aori * Bc.w;
            o0 = m0 + n0; o1 = m1 + n1; o2 = m2 + n2; o3 = m3 + n3;
            float4 w = {o0, o1, o2, o3};
            *(float4*)&outT[((size_t)b * Msz + t) * Csz + lane * 4] = w;
            Uc = Un; Bc = Bn;   // vmcnt for Un/Bn lands here, post-chain
        }
        return;
    }

    // ------------------- known-pixel sim branch ---------------------------
    int g  = gid - BZsz;
    int ks = g % KSPL;
    int pt = (g / KSPL) % 24;
    int b  = g / (24 * KSPL);
    int p0 = pt * 128;
    int k0 = ks * KPER;

    float (*rf)[LDP] = (float(*)[LDP])smem;
    float (*kn)[KLD] = (float(*)[KLD])(smem + 64 * LDP);

    int tr = tid >> 4;
    int tc = tid & 15;
    int kc = tc * 8 + ((tc >> 2) << 2);

    int rowgrp = tid >> 5;
    int px4    = (tid & 31) * 4;
    int skk  = tid >> 1;
    int sc4  = (tid & 1) * 32;
    int kcol = skk + ((skk >> 5) << 2);

    float best[8];
    int   bidx[8];
#pragma unroll
    for (int i = 0; i < 8; i++) { best[i] = -INFINITY; bidx[i] = 0x7fffffff; }

    for (int kt = 0; kt < NKT; kt++) {
        int ktbase = k0 + kt * 128;
        const float* nrow = knT + ((size_t)b * Ksz + ktbase + skk) * Csz;

        f32x2 acc[8][4];
#pragma unroll
        for (int i = 0; i < 8; i++)
#pragma unroll
            for (int jj = 0; jj < 4; jj++) acc[i][jj] = (f32x2){0.f, 0.f};

        for (int cc = 0; cc < 4; cc++) {
            __syncthreads();
            {
                int pix = kidx[p0 + px4];
#pragma unroll
                for (int i = 0; i < 8; i++) {
                    int c = i * 8 + rowgrp;
                    float4 v = *(const float4*)&refm[((size_t)b * Csz + cc * 64 + c) * HWsz + pix];
                    *(float4*)&rf[c][px4] = v;
                }
            }
            const float* src = nrow + cc * 64 + sc4;
#pragma unroll
            for (int i = 0; i < 8; i++) {
                float4 v = *(const float4*)(src + i * 4);
                int c = sc4 + i * 4;
                kn[c + 0][kcol] = v.x;
                kn[c + 1][kcol] = v.y;
                kn[c + 2][kcol] = v.z;
                kn[c + 3][kcol] = v.w;
            }
            __syncthreads();

#pragma unroll 2
            for (int c = 0; c < 64; c++) {
                float4 a0 = *(const float4*)&rf[c][tr * 8];
                float4 a1 = *(const float4*)&rf[c][tr * 8 + 4];
                float4 b0 = *(const float4*)&kn[c][kc];
                float4 b1 = *(const float4*)&kn[c][kc + 4];
                float av[8] = {a0.x, a0.y, a0.z, a0.w, a1.x, a1.y, a1.z, a1.w};
                f32x2 B[4] = {{b0.x, b0.y}, {b0.z, b0.w}, {b1.x, b1.y}, {b1.z, b1.w}};
#pragma unroll
                for (int i = 0; i < 8; i++) {
                    f32x2 av2 = {av[i], av[i]};
#pragma unroll
                    for (int jj = 0; jj < 4; jj++) {
                        f32x2 pr;
                        PK_MUL(pr, av2, B[jj]);
                        PK_ADD(acc[i][jj], pr);
                    }
                }
            }
        }
#pragma unroll
        for (int j = 0; j < 8; j++) {
            int k = ktbase + tc * 8 + j;
#pragma unroll
            for (int i = 0; i < 8; i++) {
                float v = (j & 1) ? acc[i][j >> 1].y : acc[i][j >> 1].x;
                if (v > best[i] || (v == best[i] && k < bidx[i])) { best[i] = v; bidx[i] = k; }
            }
        }
    }

    __syncthreads();
    float* sv = &rf[0][0];
    int*   si = (int*)&kn[0][0];
#pragma unroll
    for (int i = 0; i < 8; i++) {
        int p = tr * 8 + i;
        sv[p * 16 + tc] = best[i];
        si[p * 16 + tc] = bidx[i];
    }
    __syncthreads();
    if (tid < 128) {
        float bv = -INFINITY; int bi = 0x7fffffff;
        for (int t = 0; t < 16; t++) {
            float v = sv[tid * 16 + t];
            int   k = si[tid * 16 + t];
            if (v > bv || (v == bv && k < bi)) { bv = v; bi = k; }
        }
        int pix = kidx[p0 + tid];
        pvmax[((size_t)ks * BZsz + b) * HWsz + pix] = bv;
        pind [((size_t)ks * BZsz + b) * HWsz + pix] = bi;
    }
}

// ---------------------------------------------------------------------------
// K4: mask position map
// ---------------------------------------------------------------------------
__global__ void maskpos_init(int* mp) { mp[blockIdx.x * 256 + threadIdx.x] = -1; }
__global__ void maskpos_set(const int* __restrict__ midx, int* mp) {
    int t = blockIdx.x * 256 + threadIdx.x;
    if (t < Msz) mp[midx[t]] = t;
}

// ---------------------------------------------------------------------------
// K5: assemble output [b][c][p]
// ---------------------------------------------------------------------------
#define FSTR 261
__launch_bounds__(256)
__global__ void finalize_kernel(const float* __restrict__ inpT, const float* __restrict__ outT,
                                const int* __restrict__ ind, const int* __restrict__ kidx,
                                const int* __restrict__ mp, float* __restrict__ out) {
    __shared__ float tile[64 * FSTR];
    int b   = blockIdx.x;
    int p0  = blockIdx.y * 64;
    int tid = threadIdx.x;
    int rl  = tid >> 6;
    int cc  = (tid & 63) * 4;
    for (int i = 0; i < 16; i++) {
        int r = rl + i * 4;
        int p = p0 + r;
        int m = mp[p];
        const float* src = (m >= 0) ? (outT + ((size_t)b * Msz + m) * Csz)
                                    : (inpT + ((size_t)b * HWsz + kidx[ind[b * HWsz + p]]) * Csz);
        float4 v = *(const float4*)(src + cc);
        tile[r * FSTR + cc + 0] = v.x;
        tile[r * FSTR + cc + 1] = v.y;
        tile[r * FSTR + cc + 2] = v.z;
        tile[r * FSTR + cc + 3] = v.w;
    }
    __syncthreads();
    int pp = tid & 63;
    int c0 = tid >> 6;
    for (int i = 0; i < 64; i++) {
        int c = c0 + i * 4;
        out[((size_t)b * Csz + c) * HWsz + p0 + pp] = tile[pp * FSTR + c];
    }
}

// ---------------------------------------------------------------------------
extern "C" void kernel_launch(void* const* d_in, const int* in_sizes, int n_in,
                              void* d_out, int out_size, void* d_ws, size_t ws_size,
                              hipStream_t stream) {
    const float* inp  = (const float*)d_in[0];
    const float* refm = (const float*)d_in[1];
    const int*   midx = (const int*)d_in[2];
    const int*   kidx = (const int*)d_in[3];
    float* out = (float*)d_out;

    char* ws = (char*)d_ws;
    float* inpT  = (float*)(ws);                  // 16 MB   (ends 16777216)
    float* outT  = (float*)(ws + 16777216);       // 4 MB    (ends 20971520)
    float* knT   = (float*)(ws + 20971520);       // 12 MB   (ends 33554432)
    float* uT    = (float*)(ws + 33554432);       // 4 MB    (ends 37748736)
    float* bkT   = (float*)(ws + 37748736);       // 4 MB    (ends 41943040)
    float* dnorm = (float*)(ws + 41943040);       // 64 KB   (ends 42008576)
    float* vmax  = (float*)(ws + 42008576);       // 64 KB   (ends 42074112)
    int*   ind   = (int*)  (ws + 42074112);       // 64 KB   (ends 42139648)
    int*   mp    = (int*)  (ws + 42139648);       // 16 KB   (ends 42156032)
    float* pvmax = (float*)(ws + 42156032);       // 512 KB  (ends 42680320)
    int*   pind  = (int*)  (ws + 42680320);       // 512 KB  (ends 43204608)

    hipLaunchKernelGGL(transpose_kernel, dim3(HWsz / 32, Csz / 32, BZsz), dim3(32, 8), 0, stream,
                       inp, inpT);
    hipLaunchKernelGGL(maskpos_init, dim3(HWsz / 256), dim3(256), 0, stream, mp);
    hipLaunchKernelGGL(maskpos_set, dim3((Msz + 255) / 256), dim3(256), 0, stream, midx, mp);
    hipLaunchKernelGGL(colnorm_kernel, dim3(HWsz / 256, BZsz), dim3(256), 0, stream, inp, dnorm);
    hipLaunchKernelGGL(knprep_kernel, dim3(Ksz / 4, BZsz), dim3(256), 0, stream,
                       inpT, dnorm, kidx, knT);
    hipLaunchKernelGGL(masked_sim_kernel, dim3(BZsz, 16, MKSPL), dim3(256), 0, stream,
                       knT, refm, midx, pvmax, pind);
    hipLaunchKernelGGL(masked_combine_kernel, dim3(4, BZsz), dim3(256), 0, stream,
                       pvmax, pind, midx, vmax, ind);
    hipLaunchKernelGGL(scanprep_kernel, dim3(Msz / 4, BZsz), dim3(256), 0, stream,
                       inpT, dnorm, ind, midx, kidx, uT, bkT);
    hipLaunchKernelGGL(hetero_kernel, dim3(BZsz + BZsz * 24 * KSPL), dim3(256), 0, stream,
                       knT, refm, kidx, pvmax, pind, uT, bkT, vmax, midx, outT);
    hipLaunchKernelGGL(known_combine_kernel, dim3(Ksz / 256, BZsz), dim3(256), 0, stream,
                       pvmax, pind, kidx, vmax, ind);
    hipLaunchKernelGGL(finalize_kernel, dim3(BZsz, HWsz / 64), dim3(256), 0, stream,
                       inpT, outT, ind, kidx, mp, out);
}

// Round 21
// 780.236 us; speedup vs baseline: 1.7730x; 1.2075x over previous
//
#include <hip/hip_runtime.h>
#include <hip/hip_bf16.h>
#include <math.h>

#define HWsz 4096
#define Csz  256
#define BZsz 4
#define Msz  1024
#define Ksz  3072
#define Knum 3072
// known-sim in hetero: 512-thr blocks, 256p x 128k tile, 24 k-splits
#define KSPL 24
#define LDP  264      // rf row: 256 + 8 pad
#define KLD  140      // kn row: 128 + 4-per-32 bank depad
// masked-sim (64p tiles): 16 tiles, KSPL=8
#define MKSPL 8
#define MKPER 384
#define MNKT  3
#define MLDP  68
#define MKLD  140

typedef float f32x2 __attribute__((ext_vector_type(2)));

#define PK_MUL(dst, s0, s1) asm("v_pk_mul_f32 %0, %1, %2" : "=v"(dst) : "v"(s0), "v"(s1))
#define PK_ADD(dst, s1)     asm("v_pk_add_f32 %0, %0, %1" : "+v"(dst) : "v"(s1))

// ---------------------------------------------------------------------------
// K0: transpose input [b][c][p] -> inpT [b][p][c]
// ---------------------------------------------------------------------------
__global__ void transpose_kernel(const float* __restrict__ in, float* __restrict__ outT) {
    __shared__ float tile[32][33];
    int b  = blockIdx.z;
    int p0 = blockIdx.x * 32;
    int c0 = blockIdx.y * 32;
    int tx = threadIdx.x;
    int ty = threadIdx.y;
#pragma unroll
    for (int i = 0; i < 4; i++) {
        int c = c0 + ty + i * 8;
        tile[ty + i * 8][tx] = in[((size_t)b * Csz + c) * HWsz + p0 + tx];
    }
    __syncthreads();
#pragma unroll
    for (int i = 0; i < 4; i++) {
        int p = p0 + ty + i * 8;
        outT[((size_t)b * HWsz + p) * Csz + c0 + tx] = tile[tx][ty + i * 8];
    }
}

// ---------------------------------------------------------------------------
// K1: norm replica (sequential f32 sum of f32 squares, sqrt, +1e-8f)
// ---------------------------------------------------------------------------
__global__ void colnorm_kernel(const float* __restrict__ inp, float* __restrict__ dnorm) {
#pragma clang fp contract(off)
    int p = blockIdx.x * 256 + threadIdx.x;
    int b = blockIdx.y;
    const float* col = inp + (size_t)b * Csz * HWsz + p;
    float acc = 0.f;
    for (int c = 0; c < Csz; c++) {
        float x  = col[(size_t)c * HWsz];
        float sq = x * x;
        acc = acc + sq;
    }
    dnorm[b * HWsz + p] = sqrtf(acc) + 1e-8f;
}

// ---------------------------------------------------------------------------
// K1b: knT[b][kk][c] = inpT[b][kidx[kk]][c] / dn  (IEEE f32 div, once)
// ---------------------------------------------------------------------------
__global__ void knprep_kernel(const float* __restrict__ inpT, const float* __restrict__ dnorm,
                              const int* __restrict__ kidx, float* __restrict__ knT) {
    int row  = blockIdx.x * 4 + (threadIdx.x >> 6);
    int lane = threadIdx.x & 63;
    int b    = blockIdx.y;
    int kid  = kidx[row];
    float dn = dnorm[b * HWsz + kid];
    const float* src = inpT + ((size_t)b * HWsz + kid) * Csz + lane * 4;
    float4 v = *(const float4*)src;
    float4 w = {v.x / dn, v.y / dn, v.z / dn, v.w / dn};
    *(float4*)(knT + ((size_t)b * Ksz + row) * Csz + lane * 4) = w;
}

// ---------------------------------------------------------------------------
// K2m: masked-pixel sim (64p x K tile, KSPL=8). Numerics identical.
// Writes t-indexed partials mpv/mpi.
// ---------------------------------------------------------------------------
__launch_bounds__(256, 2)
__global__ void masked_sim_kernel(const float* __restrict__ knT,
                                  const float* __restrict__ refm,
                                  const int* __restrict__ midx,
                                  float* __restrict__ mpv, int* __restrict__ mpi) {
#pragma clang fp contract(off)
    __shared__ float rf[64][MLDP];  // [c][p]
    __shared__ float kn[64][MKLD];  // [c][kcol]

    int b   = blockIdx.x;
    int p0  = blockIdx.y * 64;
    int ks  = blockIdx.z;
    int k0  = ks * MKPER;
    int tid = threadIdx.x;

    int tr = tid >> 4;
    int tc = tid & 15;
    int kc = tc * 8 + ((tc >> 2) << 2);

    int skk  = tid >> 1;
    int sc4  = (tid & 1) * 32;
    int kcol = skk + ((skk >> 5) << 2);

    float best[4];
    int   bidx[4];
#pragma unroll
    for (int i = 0; i < 4; i++) { best[i] = -INFINITY; bidx[i] = 0x7fffffff; }

    for (int kt = 0; kt < MNKT; kt++) {
        int ktbase = k0 + kt * 128;
        const float* nrow = knT + ((size_t)b * Ksz + ktbase + skk) * Csz;

        f32x2 acc[4][4];
#pragma unroll
        for (int i = 0; i < 4; i++)
#pragma unroll
            for (int jj = 0; jj < 4; jj++) acc[i][jj] = (f32x2){0.f, 0.f};

        for (int cc = 0; cc < 4; cc++) {
            __syncthreads();
            {
                int pg  = (tid & 15) * 4;
                int pix = midx[p0 + pg];
#pragma unroll
                for (int i = 0; i < 4; i++) {
                    int c = i * 16 + (tid >> 4);
                    float4 v = *(const float4*)&refm[((size_t)b * Csz + cc * 64 + c) * HWsz + pix];
                    *(float4*)&rf[c][pg] = v;
                }
            }
            const float* src = nrow + cc * 64 + sc4;
#pragma unroll
            for (int i = 0; i < 8; i++) {
                float4 v = *(const float4*)(src + i * 4);
                int c = sc4 + i * 4;
                kn[c + 0][kcol] = v.x;
                kn[c + 1][kcol] = v.y;
                kn[c + 2][kcol] = v.z;
                kn[c + 3][kcol] = v.w;
            }
            __syncthreads();

#pragma unroll 2
            for (int c = 0; c < 64; c++) {
                float4 a0 = *(const float4*)&rf[c][tr * 4];
                float4 b0 = *(const float4*)&kn[c][kc];
                float4 b1 = *(const float4*)&kn[c][kc + 4];
                float av[4] = {a0.x, a0.y, a0.z, a0.w};
                f32x2 B[4] = {{b0.x, b0.y}, {b0.z, b0.w}, {b1.x, b1.y}, {b1.z, b1.w}};
#pragma unroll
                for (int i = 0; i < 4; i++) {
                    f32x2 av2 = {av[i], av[i]};
#pragma unroll
                    for (int jj = 0; jj < 4; jj++) {
                        f32x2 pr;
                        PK_MUL(pr, av2, B[jj]);
                        PK_ADD(acc[i][jj], pr);
                    }
                }
            }
        }
#pragma unroll
        for (int j = 0; j < 8; j++) {
            int k = ktbase + tc * 8 + j;
#pragma unroll
            for (int i = 0; i < 4; i++) {
                float v = (j & 1) ? acc[i][j >> 1].y : acc[i][j >> 1].x;
                if (v > best[i] || (v == best[i] && k < bidx[i])) { best[i] = v; bidx[i] = k; }
            }
        }
    }

    __syncthreads();
    float* sv = &rf[0][0];
    int*   si = (int*)&kn[0][0];
#pragma unroll
    for (int i = 0; i < 4; i++) {
        int p = tr * 4 + i;
        sv[p * 16 + tc] = best[i];
        si[p * 16 + tc] = bidx[i];
    }
    __syncthreads();
    if (tid < 64) {
        float bv = -INFINITY; int bi = 0x7fffffff;
        for (int t = 0; t < 16; t++) {
            float v = sv[tid * 16 + t];
            int   k = si[tid * 16 + t];
            if (v > bv || (v == bv && k < bi)) { bv = v; bi = k; }
        }
        mpv[((size_t)ks * BZsz + b) * Msz + p0 + tid] = bv;
        mpi[((size_t)ks * BZsz + b) * Msz + p0 + tid] = bi;
    }
}

// ---------------------------------------------------------------------------
// K2bm: combine masked splits (ks 0..7 ascending => global first-max)
// ---------------------------------------------------------------------------
__global__ void masked_combine_kernel(const float* __restrict__ mpv, const int* __restrict__ mpi,
                                      const int* __restrict__ midx,
                                      float* __restrict__ vmax, int* __restrict__ ind) {
    int i = blockIdx.x * 256 + threadIdx.x;   // 0..1023
    int b = blockIdx.y;
    float bv = -INFINITY; int bi = 0x7fffffff;
    for (int ks = 0; ks < MKSPL; ks++) {
        float v = mpv[((size_t)ks * BZsz + b) * Msz + i];
        int   k = mpi[((size_t)ks * BZsz + b) * Msz + i];
        if (v > bv || (v == bv && k < bi)) { bv = v; bi = k; }
    }
    int pix = midx[i];
    vmax[b * HWsz + pix] = bv;
    ind [b * HWsz + pix] = bi;
}

// ---------------------------------------------------------------------------
// K2b: combine known splits (ks 0..23 ascending)
// ---------------------------------------------------------------------------
__global__ void known_combine_kernel(const float* __restrict__ kpv, const int* __restrict__ kpi,
                                     const int* __restrict__ kidx,
                                     float* __restrict__ vmax, int* __restrict__ ind) {
    int i = blockIdx.x * 256 + threadIdx.x;   // 0..3071
    int b = blockIdx.y;
    float bv = -INFINITY; int bi = 0x7fffffff;
    for (int ks = 0; ks < KSPL; ks++) {
        float v = kpv[((size_t)ks * BZsz + b) * Knum + i];
        int   k = kpi[((size_t)ks * BZsz + b) * Knum + i];
        if (v > bv || (v == bv && k < bi)) { bv = v; bi = k; }
    }
    int pix = kidx[i];
    vmax[b * HWsz + pix] = bv;
    ind [b * HWsz + pix] = bi;
}

// ---------------------------------------------------------------------------
// K2c: scanprep
// ---------------------------------------------------------------------------
__global__ void scanprep_kernel(const float* __restrict__ inpT, const float* __restrict__ dnorm,
                                const int* __restrict__ ind, const int* __restrict__ midx,
                                const int* __restrict__ kidx,
                                float* __restrict__ uT, float* __restrict__ bkT) {
    int t    = blockIdx.x * 4 + (threadIdx.x >> 6);
    int lane = threadIdx.x & 63;
    int b    = blockIdx.y;
    int pp   = midx[t];
    float dn = dnorm[b * HWsz + pp];
    int bkid = kidx[ind[b * HWsz + pp]];
    const float* us = inpT + ((size_t)b * HWsz + pp) * Csz + lane * 4;
    const float* bs = inpT + ((size_t)b * HWsz + bkid) * Csz + lane * 4;
    float4 v = *(const float4*)us;
    float4 w = {v.x / dn, v.y / dn, v.z / dn, v.w / dn};
    *(float4*)(uT  + ((size_t)b * Msz + t) * Csz + lane * 4) = w;
    *(float4*)(bkT + ((size_t)b * Msz + t) * Csz + lane * 4) = *(const float4*)bs;
}

// ---------------------------------------------------------------------------
// K3h: HETEROGENEOUS kernel, 512 threads, LDS 103KB -> 1 block/CU.
// blocks 0..3    = serial scan (reg rolling dbuf, R16 scheme) on a CU that
//                  hosts NOTHING else (LDS excludes a second block) -> runs
//                  at standalone speed (~440us), no co-residency interference.
// blocks 4..1155 = known-pixel sim, 256p x 128k tile per block, 8 waves/CU
//                  (2/SIMD -- same VALU occupancy as the old 2x256 scheme),
//                  1152 small blocks pack the remaining 252 CUs (makespan ~5
//                  blocks/CU).
// All numerics bit-identical to R16-20.
// ---------------------------------------------------------------------------

#define CH(LQ4, RA_N, RB_N, RA_C, RB_C) \
    "v_readlane_b32 " #RA_N ", %[va], " #LQ4 "\n\t" \
    "v_add_f32 %[dot], " #RA_C ", %[dot]\n\t" \
    "v_readlane_b32 " #RB_N ", %[vb], " #LQ4 "\n\t" \
    "v_add_f32 %[dot], " #RB_C ", %[dot]\n\t"

#define CH_BLOCK8(L0, L1, L2, L3, L4, L5, L6, L7) \
    CH(L0, s44, s52, s40, s48) \
    CH(L1, s45, s53, s41, s49) \
    CH(L2, s46, s54, s42, s50) \
    CH(L3, s47, s55, s43, s51) \
    CH(L4, s40, s48, s44, s52) \
    CH(L5, s41, s49, s45, s53) \
    CH(L6, s42, s50, s46, s54) \
    CH(L7, s43, s51, s47, s55)

__launch_bounds__(512, 1)
__global__ void hetero_kernel(const float* __restrict__ knT, const float* __restrict__ refm,
                              const int* __restrict__ kidx,
                              float* __restrict__ kpv, int* __restrict__ kpi,
                              const float* __restrict__ uT, const float* __restrict__ bkT,
                              const float* __restrict__ vmax, const int* __restrict__ midx,
                              float* __restrict__ outT) {
#pragma clang fp contract(off)
    __shared__ float smem[64 * LDP + 64 * KLD];   // 103,424 B -> 1 block/CU
    int gid = blockIdx.x;
    int tid = threadIdx.x;

    if (gid < BZsz) {
        // ------------------- scan branch (1 wave, dedicated CU) ------------
        float* L_vm = smem;
        int b = gid;
        for (int t = tid; t < Msz; t += 512) L_vm[t] = vmax[b * HWsz + midx[t]];
        __syncthreads();
        if (tid >= 64) return;
        __builtin_amdgcn_s_setprio(3);
        int lane = tid;

        const float* ub = uT  + (size_t)b * Msz * Csz + lane * 4;
        const float* bb = bkT + (size_t)b * Msz * Csz + lane * 4;
        float o0 = 0.f, o1 = 0.f, o2 = 0.f, o3 = 0.f;
        float4 Uc = *(const float4*)ub;
        float4 Bc = *(const float4*)bb;

        for (int t = 0; t < Msz; t++) {
            int tn = (t + 1) & (Msz - 1);       // branchless wrap
            float4 Un = *(const float4*)(ub + (size_t)tn * Csz);
            float4 Bn = *(const float4*)(bb + (size_t)tn * Csz);

            float pA = Uc.y * o1;
            float rA = __builtin_fmaf(Uc.x, o0, pA);
            float pB = Uc.w * o3;
            float rB = __builtin_fmaf(Uc.z, o2, pB);
            float dot = 0.f;
            asm volatile(
                "v_readlane_b32 s40, %[va], 0\n\t"
                "v_readlane_b32 s48, %[vb], 0\n\t"
                "v_readlane_b32 s41, %[va], 1\n\t"
                "v_readlane_b32 s49, %[vb], 1\n\t"
                "v_readlane_b32 s42, %[va], 2\n\t"
                "v_readlane_b32 s50, %[vb], 2\n\t"
                "v_readlane_b32 s43, %[va], 3\n\t"
                "v_readlane_b32 s51, %[vb], 3\n\t"
                CH_BLOCK8( 4,  5,  6,  7,  8,  9, 10, 11)
                CH_BLOCK8(12, 13, 14, 15, 16, 17, 18, 19)
                CH_BLOCK8(20, 21, 22, 23, 24, 25, 26, 27)
                CH_BLOCK8(28, 29, 30, 31, 32, 33, 34, 35)
                CH_BLOCK8(36, 37, 38, 39, 40, 41, 42, 43)
                CH_BLOCK8(44, 45, 46, 47, 48, 49, 50, 51)
                CH_BLOCK8(52, 53, 54, 55, 56, 57, 58, 59)
                CH(60, s44, s52, s40, s48)
                CH(61, s45, s53, s41, s49)
                CH(62, s46, s54, s42, s50)
                CH(63, s47, s55, s43, s51)
                "v_add_f32 %[dot], s44, %[dot]\n\t"
                "v_add_f32 %[dot], s52, %[dot]\n\t"
                "v_add_f32 %[dot], s45, %[dot]\n\t"
                "v_add_f32 %[dot], s53, %[dot]\n\t"
                "v_add_f32 %[dot], s46, %[dot]\n\t"
                "v_add_f32 %[dot], s54, %[dot]\n\t"
                "v_add_f32 %[dot], s47, %[dot]\n\t"
                "v_add_f32 %[dot], s55, %[dot]\n\t"
                : [dot] "+v"(dot)
                : [va] "v"(rA), [vb] "v"(rB)
                : "s40","s41","s42","s43","s44","s45","s46","s47",
                  "s48","s49","s50","s51","s52","s53","s54","s55");
            float at    = dot;
            float vm    = L_vm[t];
            float denom = at + vm;      // f32 add
            float anew  = at / denom;   // IEEE f32 div
            float aori  = vm / denom;   // IEEE f32 div
            float m0 = anew * o0, n0 = aori * Bc.x;
            float m1 = anew * o1, n1 = aori * Bc.y;
            float m2 = anew * o2, n2 = aori * Bc.z;
            float m3 = anew * o3, n3 = aori * Bc.w;
            o0 = m0 + n0; o1 = m1 + n1; o2 = m2 + n2; o3 = m3 + n3;
            float4 w = {o0, o1, o2, o3};
            *(float4*)&outT[((size_t)b * Msz + t) * Csz + lane * 4] = w;
            Uc = Un; Bc = Bn;   // vmcnt for Un/Bn lands here, post-chain
        }
        return;
    }

    // ------------------- known-pixel sim branch (512 thr) -----------------
    int g  = gid - BZsz;
    int ks = g % KSPL;
    int pt = (g / KSPL) % 12;
    int b  = g / (12 * KSPL);
    int p0 = pt * 256;              // known-index space
    int k0 = ks * 128;

    float (*rf)[LDP] = (float(*)[LDP])smem;
    float (*kn)[KLD] = (float(*)[KLD])(smem + 64 * LDP);

    int trp = tid >> 4;             // 0..31 : p-group (8 p each)
    int tc  = tid & 15;             // 0..15 : k-group (8 k each)
    int kc  = tc * 8 + ((tc >> 2) << 2);

    int rowgrp = tid >> 6;          // 0..7   (rf staging)
    int px4    = (tid & 63) * 4;    // 0..252 (rf staging col)
    int skk  = tid >> 2;            // 0..127 (kn staging row)
    int sc4  = (tid & 3) * 16;      // c offset 0/16/32/48
    int kcol = skk + ((skk >> 5) << 2);

    float best[8];
    int   bidx[8];
#pragma unroll
    for (int i = 0; i < 8; i++) { best[i] = -INFINITY; bidx[i] = 0x7fffffff; }

    const float* nrow = knT + ((size_t)b * Ksz + k0 + skk) * Csz;

    f32x2 acc[8][4];
#pragma unroll
    for (int i = 0; i < 8; i++)
#pragma unroll
        for (int jj = 0; jj < 4; jj++) acc[i][jj] = (f32x2){0.f, 0.f};

    for (int cc = 0; cc < 4; cc++) {
        __syncthreads();
        {
            int pix = kidx[p0 + px4];   // runs 4-aligned -> float4 ok
#pragma unroll
            for (int i = 0; i < 8; i++) {
                int c = i * 8 + rowgrp;
                float4 v = *(const float4*)&refm[((size_t)b * Csz + cc * 64 + c) * HWsz + pix];
                *(float4*)&rf[c][px4] = v;
            }
        }
        const float* src = nrow + cc * 64 + sc4;
#pragma unroll
        for (int i = 0; i < 4; i++) {
            float4 v = *(const float4*)(src + i * 4);
            int c = sc4 + i * 4;
            kn[c + 0][kcol] = v.x;
            kn[c + 1][kcol] = v.y;
            kn[c + 2][kcol] = v.z;
            kn[c + 3][kcol] = v.w;
        }
        __syncthreads();

#pragma unroll 2
        for (int c = 0; c < 64; c++) {
            float4 a0 = *(const float4*)&rf[c][trp * 8];
            float4 a1 = *(const float4*)&rf[c][trp * 8 + 4];
            float4 b0 = *(const float4*)&kn[c][kc];
            float4 b1 = *(const float4*)&kn[c][kc + 4];
            float av[8] = {a0.x, a0.y, a0.z, a0.w, a1.x, a1.y, a1.z, a1.w};
            f32x2 B[4] = {{b0.x, b0.y}, {b0.z, b0.w}, {b1.x, b1.y}, {b1.z, b1.w}};
#pragma unroll
            for (int i = 0; i < 8; i++) {
                f32x2 av2 = {av[i], av[i]};
#pragma unroll
                for (int jj = 0; jj < 4; jj++) {
                    f32x2 pr;
                    PK_MUL(pr, av2, B[jj]);
                    PK_ADD(acc[i][jj], pr);
                }
            }
        }
    }
#pragma unroll
    for (int j = 0; j < 8; j++) {
        int k = k0 + tc * 8 + j;
#pragma unroll
        for (int i = 0; i < 8; i++) {
            float v = (j & 1) ? acc[i][j >> 1].y : acc[i][j >> 1].x;
            if (v > best[i] || (v == best[i] && k < bidx[i])) { best[i] = v; bidx[i] = k; }
        }
    }

    __syncthreads();
    float* sv = &rf[0][0];          // 256p x 16tc floats (16KB)
    int*   si = (int*)&kn[0][0];
#pragma unroll
    for (int i = 0; i < 8; i++) {
        int p = trp * 8 + i;
        sv[p * 16 + tc] = best[i];
        si[p * 16 + tc] = bidx[i];
    }
    __syncthreads();
    if (tid < 256) {
        float bv = -INFINITY; int bi = 0x7fffffff;
        for (int t = 0; t < 16; t++) {
            float v = sv[tid * 16 + t];
            int   k = si[tid * 16 + t];
            if (v > bv || (v == bv && k < bi)) { bv = v; bi = k; }
        }
        kpv[((size_t)ks * BZsz + b) * Knum + p0 + tid] = bv;
        kpi[((size_t)ks * BZsz + b) * Knum + p0 + tid] = bi;
    }
}

// ---------------------------------------------------------------------------
// K4: mask position map
// ---------------------------------------------------------------------------
__global__ void maskpos_init(int* mp) { mp[blockIdx.x * 256 + threadIdx.x] = -1; }
__global__ void maskpos_set(const int* __restrict__ midx, int* mp) {
    int t = blockIdx.x * 256 + threadIdx.x;
    if (t < Msz) mp[midx[t]] = t;
}

// ---------------------------------------------------------------------------
// K5: assemble output [b][c][p]
// ---------------------------------------------------------------------------
#define FSTR 261
__launch_bounds__(256)
__global__ void finalize_kernel(const float* __restrict__ inpT, const float* __restrict__ outT,
                                const int* __restrict__ ind, const int* __restrict__ kidx,
                                const int* __restrict__ mp, float* __restrict__ out) {
    __shared__ float tile[64 * FSTR];
    int b   = blockIdx.x;
    int p0  = blockIdx.y * 64;
    int tid = threadIdx.x;
    int rl  = tid >> 6;
    int cc  = (tid & 63) * 4;
    for (int i = 0; i < 16; i++) {
        int r = rl + i * 4;
        int p = p0 + r;
        int m = mp[p];
        const float* src = (m >= 0) ? (outT + ((size_t)b * Msz + m) * Csz)
                                    : (inpT + ((size_t)b * HWsz + kidx[ind[b * HWsz + p]]) * Csz);
        float4 v = *(const float4*)(src + cc);
        tile[r * FSTR + cc + 0] = v.x;
        tile[r * FSTR + cc + 1] = v.y;
        tile[r * FSTR + cc + 2] = v.z;
        tile[r * FSTR + cc + 3] = v.w;
    }
    __syncthreads();
    int pp = tid & 63;
    int c0 = tid >> 6;
    for (int i = 0; i < 64; i++) {
        int c = c0 + i * 4;
        out[((size_t)b * Csz + c) * HWsz + p0 + pp] = tile[pp * FSTR + c];
    }
}

// ---------------------------------------------------------------------------
extern "C" void kernel_launch(void* const* d_in, const int* in_sizes, int n_in,
                              void* d_out, int out_size, void* d_ws, size_t ws_size,
                              hipStream_t stream) {
    const float* inp  = (const float*)d_in[0];
    const float* refm = (const float*)d_in[1];
    const int*   midx = (const int*)d_in[2];
    const int*   kidx = (const int*)d_in[3];
    float* out = (float*)d_out;

    char* ws = (char*)d_ws;
    float* inpT  = (float*)(ws);                  // 16 MB     (ends 16777216)
    float* outT  = (float*)(ws + 16777216);       // 4 MB      (ends 20971520)
    float* knT   = (float*)(ws + 20971520);       // 12 MB     (ends 33554432)
    float* uT    = (float*)(ws + 33554432);       // 4 MB      (ends 37748736)
    float* bkT   = (float*)(ws + 37748736);       // 4 MB      (ends 41943040)
    float* dnorm = (float*)(ws + 41943040);       // 64 KB     (ends 42008576)
    float* vmax  = (float*)(ws + 42008576);       // 64 KB     (ends 42074112)
    int*   ind   = (int*)  (ws + 42074112);       // 64 KB     (ends 42139648)
    int*   mp    = (int*)  (ws + 42139648);       // 16 KB     (ends 42156032)
    float* mpv   = (float*)(ws + 42156032);       // 128 KB    (ends 42287104)
    int*   mpi   = (int*)  (ws + 42287104);       // 128 KB    (ends 42418176)
    float* kpv   = (float*)(ws + 42418176);       // 1.125 MB  (ends 43597824)
    int*   kpi   = (int*)  (ws + 43597824);       // 1.125 MB  (ends 44777472)

    hipLaunchKernelGGL(transpose_kernel, dim3(HWsz / 32, Csz / 32, BZsz), dim3(32, 8), 0, stream,
                       inp, inpT);
    hipLaunchKernelGGL(maskpos_init, dim3(HWsz / 256), dim3(256), 0, stream, mp);
    hipLaunchKernelGGL(maskpos_set, dim3((Msz + 255) / 256), dim3(256), 0, stream, midx, mp);
    hipLaunchKernelGGL(colnorm_kernel, dim3(HWsz / 256, BZsz), dim3(256), 0, stream, inp, dnorm);
    hipLaunchKernelGGL(knprep_kernel, dim3(Ksz / 4, BZsz), dim3(256), 0, stream,
                       inpT, dnorm, kidx, knT);
    hipLaunchKernelGGL(masked_sim_kernel, dim3(BZsz, 16, MKSPL), dim3(256), 0, stream,
                       knT, refm, midx, mpv, mpi);
    hipLaunchKernelGGL(masked_combine_kernel, dim3(4, BZsz), dim3(256), 0, stream,
                       mpv, mpi, midx, vmax, ind);
    hipLaunchKernelGGL(scanprep_kernel, dim3(Msz / 4, BZsz), dim3(256), 0, stream,
                       inpT, dnorm, ind, midx, kidx, uT, bkT);
    hipLaunchKernelGGL(hetero_kernel, dim3(BZsz + BZsz * 12 * KSPL), dim3(512), 0, stream,
                       knT, refm, kidx, kpv, kpi, uT, bkT, vmax, midx, outT);
    hipLaunchKernelGGL(known_combine_kernel, dim3(Knum / 256, BZsz), dim3(256), 0, stream,
                       kpv, kpi, kidx, vmax, ind);
    hipLaunchKernelGGL(finalize_kernel, dim3(BZsz, HWsz / 64), dim3(256), 0, stream,
                       inpT, outT, ind, kidx, mp, out);
}